// Round 1
// baseline (1399.641 us; speedup 1.0000x reference)
//
#include <hip/hip_runtime.h>
#include <hip/hip_bf16.h>

#define NB   8
#define NC   192
#define NH   64
#define NW   64
#define NN   4096        // H*W
#define NCD  194         // C+2
#define NC4  48          // (C+2)/4
#define NKEEP 2048       // N*RATIO

typedef __attribute__((ext_vector_type(8))) short bf16x8;  // 8 bf16 (4 VGPRs)
typedef __attribute__((ext_vector_type(4))) float f32x4;
typedef __hip_bfloat16 bf16;

__device__ __forceinline__ float dsigmoid(float x){ return 1.f/(1.f+expf(-x)); }
__device__ __forceinline__ float dlrelu(float x){ return x>0.f ? x : 0.1f*x; }

// ---------------- K0: f = lrelu(LN(conv1x1(cond))), plus score ----------------
__global__ __launch_bounds__(64) void k_f_score(
    const float* __restrict__ x, const float* __restrict__ w_in, const float* __restrict__ b_in,
    const float* __restrict__ ln_w, const float* __restrict__ ln_b,
    const float* __restrict__ mw1, const float* __restrict__ mb1,
    const float* __restrict__ mw2, const float* __restrict__ mb2,
    float* __restrict__ f, float* __restrict__ score)
{
  int pix = blockIdx.x & (NN-1);
  int b   = blockIdx.x >> 12;
  int hh = pix >> 6, ww = pix & 63;
  __shared__ float cond[NCD];
  int t = threadIdx.x;
  for (int c = t; c < NCD; c += 64) {
    float v;
    if (c < NC)       v = x[((size_t)b*NC + c)*NN + pix];
    else if (c == NC) v = -1.f + (2.f/63.f)*ww;   // gx
    else              v = -1.f + (2.f/63.f)*hh;   // gy
    cond[c] = v;
  }
  __syncthreads();
  float y = 0.f;
  if (t < NC4) {
    const float* wr = w_in + t*NCD;
    float acc = b_in[t];
    #pragma unroll 2
    for (int c = 0; c < NCD; ++c) acc += wr[c]*cond[c];
    y = acc;
  }
  float s1 = y, s2 = y*y;
  for (int o=32;o;o>>=1){ s1 += __shfl_xor(s1,o); s2 += __shfl_xor(s2,o); }
  float mean = s1*(1.f/NC4);
  float var  = s2*(1.f/NC4) - mean*mean;
  float rstd = rsqrtf(var + 1e-6f);
  float fv = 0.f;
  if (t < NC4) {
    float z = ln_w[t]*((y-mean)*rstd) + ln_b[t];
    fv = dlrelu(z);
    f[((size_t)b*NC4 + t)*NN + pix] = fv;
  }
  float ts = fv;
  for (int o=32;o;o>>=1) ts += __shfl_xor(ts,o);
  if (t==0) {
    float tm = ts*(1.f/NC4);
    float sv = dlrelu(tm*mw1[0] + mb1[0]);
    float d  = sv*(mw2[0]-mw2[1]) + (mb2[0]-mb2[1]);
    score[b*NN + pix] = dsigmoid(d);   // softmax[...,0] == sigmoid(l0-l1)
  }
}

// ---------------- K1: per-batch top-2048 via bitonic sort -----------------
// key = (desc(score) << 32) | index  -> ascending sort == stable argsort(-score)
__global__ __launch_bounds__(1024) void k_topk(const float* __restrict__ score,
                                               int* __restrict__ idx1, int* __restrict__ flag)
{
  int b = blockIdx.x;
  __shared__ unsigned long long key[NN];
  int t = threadIdx.x;
  for (int i=t;i<NN;i+=1024){
    unsigned u = __float_as_uint(score[b*NN+i]);
    unsigned a = (u & 0x80000000u) ? ~u : (u | 0x80000000u); // ascending orderable
    unsigned d = ~a;                                          // descending
    key[i] = ((unsigned long long)d << 32) | (unsigned)i;
  }
  __syncthreads();
  for (int k=2;k<=NN;k<<=1){
    for (int j=k>>1;j>0;j>>=1){
      for (int i=t;i<NN;i+=1024){
        int ixj = i ^ j;
        if (ixj > i){
          unsigned long long a = key[i], c = key[ixj];
          bool up = ((i & k) == 0);
          if (up ? (a > c) : (a < c)){ key[i]=c; key[ixj]=a; }
        }
      }
      __syncthreads();
    }
  }
  for (int i=t;i<NN;i+=1024){
    int id = (int)(unsigned)(key[i] & 0xFFFFFFFFull);
    if (i < NKEEP) idx1[b*NKEEP+i] = id;
    flag[b*NN+id] = (i < NKEEP) ? 1 : 0;
  }
}

// ---------------- K2: offsets = tanh(conv1x1(lrelu(conv1x1(f))))*8 ----------
__global__ __launch_bounds__(256) void k_offsets(
    const float* __restrict__ f, const float* __restrict__ w1, const float* __restrict__ b1,
    const float* __restrict__ w2, const float* __restrict__ b2, float* __restrict__ offs)
{
  int gid = blockIdx.x*256 + threadIdx.x;
  int p = gid & (NN-1);
  int b = gid >> 12;
  const float* fb = f + (size_t)b*NC4*NN + p;
  float fl[NC4];
  #pragma unroll 8
  for (int c=0;c<NC4;++c) fl[c] = fb[(size_t)c*NN];
  float h1[24];
  for (int o=0;o<24;++o){
    const float* wr = w1 + o*NC4;
    float a = b1[o];
    #pragma unroll 8
    for (int c=0;c<NC4;++c) a += wr[c]*fl[c];
    h1[o] = dlrelu(a);
  }
  #pragma unroll
  for (int o=0;o<2;++o){
    const float* wr = w2 + o*24;
    float a = b2[o];
    #pragma unroll
    for (int c=0;c<24;++c) a += wr[c]*h1[c];
    offs[((size_t)b*2+o)*NN + p] = tanhf(a)*8.f;
  }
}

// ---------------- K3: f spatial mean, then ca = sigmoid(fc) -----------------
__global__ __launch_bounds__(256) void k_fmean(const float* __restrict__ f, float* __restrict__ fmean){
  int bc = blockIdx.x;
  const float* p = f + (size_t)bc*NN;
  float s = 0.f;
  for (int i=threadIdx.x;i<NN;i+=256) s += p[i];
  for (int o=32;o;o>>=1) s += __shfl_xor(s,o);
  __shared__ float r[4];
  if ((threadIdx.x&63)==0) r[threadIdx.x>>6] = s;
  __syncthreads();
  if (threadIdx.x==0) fmean[bc] = (r[0]+r[1]+r[2]+r[3])*(1.f/NN);
}

__global__ void k_ca(const float* __restrict__ fmean, const float* __restrict__ w,
                     const float* __restrict__ bias, float* __restrict__ ca){
  int b = blockIdx.x, o = threadIdx.x;
  const float* fm = fmean + b*NC4;
  float a = bias[o];
  #pragma unroll 8
  for (int c=0;c<NC4;++c) a += w[o*NC4+c]*fm[c];
  ca[b*NC+o] = dsigmoid(a);
}

// ---------------- K4: sa = sigmoid(conv3x3(f, 48->1)) -----------------------
__global__ __launch_bounds__(256) void k_sa(const float* __restrict__ f, const float* __restrict__ w,
                                            const float* __restrict__ bias, float* __restrict__ sa){
  int gid = blockIdx.x*256 + threadIdx.x;
  int p = gid & (NN-1);
  int b = gid >> 12;
  int hh=p>>6, ww=p&63;
  float acc = bias[0];
  for (int c=0;c<NC4;++c){
    const float* fp = f + ((size_t)b*NC4+c)*NN;
    const float* wc = w + c*9;
    #pragma unroll
    for (int dy=0;dy<3;++dy){ int yy=hh+dy-1; if(yy<0||yy>63) continue;
      #pragma unroll
      for (int dx=0;dx<3;++dx){ int xx=ww+dx-1; if(xx<0||xx>63) continue;
        acc += fp[yy*64+xx]*wc[dy*3+dx]; } }
  }
  sa[gid] = dsigmoid(acc);
}

// ---------------- conv1x1 192->192 over pixel images (fp32) -----------------
// out[b][o][p] = sum_c in[b][c][p]*w[o][c] + bias[o]; block (64,4): wave per o, 4 px/thread
__global__ __launch_bounds__(256) void k_conv1x1(const float* __restrict__ in, const float* __restrict__ w,
                                                 const float* __restrict__ bias, float* __restrict__ outp){
  int p0 = blockIdx.x*256 + threadIdx.x*4;
  int o  = blockIdx.y*4 + threadIdx.y;
  int b  = blockIdx.z;
  const float* ip = in + (size_t)b*NC*NN + p0;
  const float* wr = w + o*NC;
  float a0=0,a1=0,a2=0,a3=0;
  #pragma unroll 4
  for (int c=0;c<NC;++c){
    float4 xv = *(const float4*)(ip + (size_t)c*NN);
    float wv = wr[c];
    a0 += xv.x*wv; a1 += xv.y*wv; a2 += xv.z*wv; a3 += xv.w*wv;
  }
  float bv = bias[o];
  float4 rv; rv.x=a0+bv; rv.y=a1+bv; rv.z=a2+bv; rv.w=a3+bv;
  *(float4*)(outp + ((size_t)b*NC+o)*NN + p0) = rv;
}

// ---------------- warp params per selected token ----------------------------
__global__ __launch_bounds__(256) void k_warp_params(const int* __restrict__ idx1, const float* __restrict__ offs,
                                                     float4* __restrict__ wpar, int4* __restrict__ ipar){
  int gid = blockIdx.x*256 + threadIdx.x;  // B*KEEP
  int b = gid >> 11;
  int p = idx1[gid];
  int ph = p >> 6, pwx = p & 63;
  float fx = offs[((size_t)b*2+0)*NN + p];
  float fy = offs[((size_t)b*2+1)*NN + p];
  float sx = (float)pwx + fx, sy = (float)ph + fy;
  float x0f = floorf(sx), y0f = floorf(sy);
  float wx = sx - x0f, wy = sy - y0f;
  int x0 = (int)x0f, y0 = (int)y0f;
  bool vx0 = (x0f >= 0.f) && (x0f <= 63.f);
  bool vx1 = (x0f+1.f >= 0.f) && (x0f+1.f <= 63.f);
  bool vy0 = (y0f >= 0.f) && (y0f <= 63.f);
  bool vy1 = (y0f+1.f >= 0.f) && (y0f+1.f <= 63.f);
  int cx0 = min(max(x0,0),63), cx1 = min(max(x0+1,0),63);
  int cy0 = min(max(y0,0),63), cy1 = min(max(y0+1,0),63);
  float4 w4;
  w4.x = (vx0&&vy0) ? (1.f-wx)*(1.f-wy) : 0.f;
  w4.y = (vx1&&vy0) ? wx*(1.f-wy)       : 0.f;
  w4.z = (vx0&&vy1) ? (1.f-wx)*wy       : 0.f;
  w4.w = (vx1&&vy1) ? wx*wy             : 0.f;
  int4 i4;
  i4.x = cy0*64+cx0; i4.y = cy0*64+cx1; i4.z = cy1*64+cx0; i4.w = cy1*64+cx1;
  wpar[gid]=w4; ipar[gid]=i4;
}

// ---------------- gathers: xq (x at idx1), kg (x+warp at idx1), v1T ---------
__global__ __launch_bounds__(256) void k_gather_q(const float* __restrict__ x, const int* __restrict__ idx1,
                                                  float* __restrict__ xq){
  int gid = blockIdx.x*256 + threadIdx.x;  // B*C*KEEP
  int s = gid & (NKEEP-1);
  int bc = gid >> 11;
  int b = bc/NC;
  xq[gid] = x[(size_t)bc*NN + idx1[b*NKEEP+s]];
}

__global__ __launch_bounds__(256) void k_gather_k(const float* __restrict__ x, const int* __restrict__ idx1,
                                                  const float4* __restrict__ wpar, const int4* __restrict__ ipar,
                                                  float* __restrict__ kg){
  int gid = blockIdx.x*256 + threadIdx.x;
  int s = gid & (NKEEP-1);
  int bc = gid >> 11;
  int b = bc/NC;
  int bs = b*NKEEP + s;
  int p = idx1[bs];
  float4 w4 = wpar[bs]; int4 i4 = ipar[bs];
  const float* xr = x + (size_t)bc*NN;
  kg[gid] = xr[p] + w4.x*xr[i4.x] + w4.y*xr[i4.y] + w4.z*xr[i4.z] + w4.w*xr[i4.w];
}

__global__ __launch_bounds__(256) void k_gather_vT(const float* __restrict__ v, const int* __restrict__ idx1,
                                                   bf16* __restrict__ v1T){
  int gid = blockIdx.x*256 + threadIdx.x;
  int s = gid & (NKEEP-1);
  int bc = gid >> 11;
  int b = bc/NC;
  v1T[gid] = __float2bfloat16(v[(size_t)bc*NN + idx1[b*NKEEP+s]]);
}

// ---------------- GEMM for q1/k1: [b][c][s] fp32 -> [b][s][o] bf16 ----------
__global__ __launch_bounds__(256) void k_gemm_qk(const float* __restrict__ in, const float* __restrict__ w,
                                                 const float* __restrict__ bias, bf16* __restrict__ outp){
  int s0 = blockIdx.x*256 + threadIdx.x*4;
  int o  = blockIdx.y*4 + threadIdx.y;
  int b  = blockIdx.z;
  const float* ip = in + (size_t)b*NC*NKEEP + s0;
  const float* wr = w + o*NC;
  float a0=0,a1=0,a2=0,a3=0;
  #pragma unroll 4
  for (int c=0;c<NC;++c){
    float4 xv = *(const float4*)(ip + (size_t)c*NKEEP);
    float wv = wr[c];
    a0 += xv.x*wv; a1 += xv.y*wv; a2 += xv.z*wv; a3 += xv.w*wv;
  }
  float bv = bias[o];
  bf16* op = outp + ((size_t)b*NKEEP + s0)*NC + o;
  op[0]     = __float2bfloat16(a0+bv);
  op[NC]    = __float2bfloat16(a1+bv);
  op[2*NC]  = __float2bfloat16(a2+bv);
  op[3*NC]  = __float2bfloat16(a3+bv);
}

// ---------------- fill unselected: out_img = v*sa (in place in v) -----------
__global__ __launch_bounds__(256) void k_fill(const float* __restrict__ sa, const int* __restrict__ flag,
                                              float* __restrict__ vout){
  int gid = blockIdx.x*256 + threadIdx.x;  // B*C*N
  int p = gid & (NN-1);
  int bc = gid >> 12;
  int b = bc/NC;
  if (!flag[b*NN+p]) vout[gid] *= sa[b*NN+p];
}

// ---------------- flash attention over the 2048 selected tokens -------------
// block: 4 waves x 16 queries; stream keys in tiles of 32; bf16 MFMA, fp32 acc
__global__ __launch_bounds__(256) void k_attn(const bf16* __restrict__ q1, const bf16* __restrict__ k1,
                                              const bf16* __restrict__ v1T, const int* __restrict__ idx1,
                                              float* __restrict__ out_img)
{
  int b = blockIdx.y;
  int wv = threadIdx.x >> 6;
  int lane = threadIdx.x & 63;
  int g = lane >> 4, r = lane & 15;
  int q0 = blockIdx.x*64 + wv*16;

  const bf16* qb = q1 + (size_t)b*NKEEP*NC;
  const bf16* kb = k1 + (size_t)b*NKEEP*NC;
  const bf16* vb = v1T + (size_t)b*NC*NKEEP;

  // Q fragments: lane holds A[row=q0+r][k=32*ks+8*g+i]
  bf16x8 aq[6];
  #pragma unroll
  for (int ks=0;ks<6;++ks)
    aq[ks] = *(const bf16x8*)(qb + (size_t)(q0+r)*NC + 32*ks + 8*g);

  f32x4 acc[12];
  #pragma unroll
  for (int i=0;i<12;++i){ acc[i][0]=0.f; acc[i][1]=0.f; acc[i][2]=0.f; acc[i][3]=0.f; }
  float m[4]={-1e30f,-1e30f,-1e30f,-1e30f}, l[4]={0.f,0.f,0.f,0.f};

  __shared__ __align__(16) bf16 plds[4][16][40];   // per-wave P tile, padded rows
  bf16 (* __restrict__ pw)[40] = plds[wv];
  const float scale = 0.07216878364870323f;        // 192^-0.5

  for (int k0=0;k0<NKEEP;k0+=32) {
    f32x4 s0v, s1v;
    s0v[0]=s0v[1]=s0v[2]=s0v[3]=0.f;
    s1v[0]=s1v[1]=s1v[2]=s1v[3]=0.f;
    #pragma unroll
    for (int ks=0;ks<6;++ks) {
      bf16x8 bk0 = *(const bf16x8*)(kb + (size_t)(k0+r)*NC    + 32*ks + 8*g);
      bf16x8 bk1 = *(const bf16x8*)(kb + (size_t)(k0+16+r)*NC + 32*ks + 8*g);
      s0v = __builtin_amdgcn_mfma_f32_16x16x32_bf16(aq[ks], bk0, s0v, 0,0,0);
      s1v = __builtin_amdgcn_mfma_f32_16x16x32_bf16(aq[ks], bk1, s1v, 0,0,0);
    }
    // online softmax: lane holds S[q=4g+i][key=r or 16+r]
    float p0[4], p1[4], corr[4];
    #pragma unroll
    for (int i=0;i<4;++i) {
      float a0 = s0v[i]*scale, a1 = s1v[i]*scale;
      float mx = fmaxf(a0,a1);
      #pragma unroll
      for (int o=1;o<16;o<<=1) mx = fmaxf(mx, __shfl_xor(mx,o));
      float mn = fmaxf(m[i], mx);
      float c_ = expf(m[i]-mn);
      float e0 = expf(a0-mn), e1 = expf(a1-mn);
      float ls = e0+e1;
      #pragma unroll
      for (int o=1;o<16;o<<=1) ls += __shfl_xor(ls,o);
      l[i] = l[i]*c_ + ls;
      m[i] = mn; corr[i]=c_;
      p0[i]=e0; p1[i]=e1;
    }
    #pragma unroll
    for (int ct=0;ct<12;++ct){
      acc[ct][0]*=corr[0]; acc[ct][1]*=corr[1]; acc[ct][2]*=corr[2]; acc[ct][3]*=corr[3];
    }
    // P -> LDS (C-layout write), read back in A-layout
    #pragma unroll
    for (int i=0;i<4;++i) {
      pw[4*g+i][r]    = __float2bfloat16(p0[i]);
      pw[4*g+i][16+r] = __float2bfloat16(p1[i]);
    }
    __syncthreads();
    bf16x8 pa = *(const bf16x8*)(&pw[r][8*g]);
    #pragma unroll
    for (int ct=0;ct<12;++ct) {
      bf16x8 bvv = *(const bf16x8*)(vb + (size_t)(16*ct + r)*NKEEP + k0 + 8*g);
      acc[ct] = __builtin_amdgcn_mfma_f32_16x16x32_bf16(pa, bvv, acc[ct], 0,0,0);
    }
    __syncthreads();
  }
  float rl[4]; int pix[4];
  #pragma unroll
  for (int i=0;i<4;++i){ rl[i]=1.f/l[i]; pix[i]=idx1[b*NKEEP + q0 + 4*g + i]; }
  #pragma unroll
  for (int ct=0;ct<12;++ct)
    #pragma unroll
    for (int i=0;i<4;++i)
      out_img[((size_t)b*NC + 16*ct + r)*NN + pix[i]] = acc[ct][i]*rl[i];
}

// ---------------- depthwise 3x3 + gelu*ca + residual ------------------------
__global__ __launch_bounds__(256) void k_dwgelu(const float* __restrict__ vin, const float* __restrict__ ca,
                                                const float* __restrict__ cw, const float* __restrict__ cb,
                                                float* __restrict__ out2){
  int gid = blockIdx.x*256 + threadIdx.x;
  int p = gid & (NN-1);
  int bc = gid >> 12;
  int c = bc % NC, b = bc / NC;
  int hh = p>>6, ww = p&63;
  const float* ip = vin + (size_t)bc*NN;
  float a = cb[c];
  #pragma unroll
  for (int dy=0;dy<3;++dy){ int yy=hh+dy-1; if(yy<0||yy>63) continue;
    #pragma unroll
    for (int dx=0;dx<3;++dx){ int xx=ww+dx-1; if(xx<0||xx>63) continue;
      a += ip[yy*64+xx]*cw[c*9+dy*3+dx]; } }
  float gl = 0.5f*a*(1.f+tanhf(0.79788456080286536f*(a+0.044715f*a*a*a)));
  out2[gid] = gl*ca[b*NC+c] + ip[p];
}

// ============================================================================
extern "C" void kernel_launch(void* const* d_in, const int* in_sizes, int n_in,
                              void* d_out, int out_size, void* d_ws, size_t ws_size,
                              hipStream_t stream)
{
  const float* x       = (const float*)d_in[0];
  const float* p_in_w  = (const float*)d_in[1];
  const float* p_in_b  = (const float*)d_in[2];
  const float* p_ln_w  = (const float*)d_in[3];
  const float* p_ln_b  = (const float*)d_in[4];
  const float* p_off_w1= (const float*)d_in[5];
  const float* p_off_b1= (const float*)d_in[6];
  const float* p_off_w2= (const float*)d_in[7];
  const float* p_off_b2= (const float*)d_in[8];
  const float* p_ca_w  = (const float*)d_in[9];
  const float* p_ca_b  = (const float*)d_in[10];
  const float* p_sa_w  = (const float*)d_in[11];
  const float* p_sa_b  = (const float*)d_in[12];
  const float* p_mask_w1=(const float*)d_in[13];
  const float* p_mask_b1=(const float*)d_in[14];
  const float* p_mask_w2=(const float*)d_in[15];
  const float* p_mask_b2=(const float*)d_in[16];
  const float* v_w     = (const float*)d_in[17];
  const float* v_b     = (const float*)d_in[18];
  const float* q_w     = (const float*)d_in[19];
  const float* q_b     = (const float*)d_in[20];
  const float* k_w     = (const float*)d_in[21];
  const float* k_b     = (const float*)d_in[22];
  const float* cs_w    = (const float*)d_in[23];
  const float* cs_b    = (const float*)d_in[24];
  const float* out_w   = (const float*)d_in[25];
  const float* out_b   = (const float*)d_in[26];
  float* out = (float*)d_out;
  (void)in_sizes; (void)n_in; (void)out_size;

  char* wsp = (char*)d_ws;
  size_t off = 0;
  auto alloc = [&](size_t bytes)->char*{ char* p = wsp + off; off += (bytes + 255) & ~(size_t)255; return p; };
  float* f     = (float*)alloc((size_t)NB*NC4*NN*4);
  float* score = (float*)alloc((size_t)NB*NN*4);
  int*   idx1  = (int*)  alloc((size_t)NB*NKEEP*4);
  int*   flag  = (int*)  alloc((size_t)NB*NN*4);
  float* offs  = (float*)alloc((size_t)NB*2*NN*4);
  float* sa    = (float*)alloc((size_t)NB*NN*4);
  float* fmean = (float*)alloc((size_t)NB*NC4*4);
  float* ca    = (float*)alloc((size_t)NB*NC*4);
  float* vbuf  = (float*)alloc((size_t)NB*NC*NN*4);     // v, later out_img (in place)
  bf16*  q1bf  = (bf16*) alloc((size_t)NB*NKEEP*NC*2);
  bf16*  k1bf  = (bf16*) alloc((size_t)NB*NKEEP*NC*2);
  bf16*  v1T   = (bf16*) alloc((size_t)NB*NC*NKEEP*2);
  float4* wpar = (float4*)alloc((size_t)NB*NKEEP*16);
  int4*   ipar = (int4*) alloc((size_t)NB*NKEEP*16);
  float* out2  = (float*)alloc((size_t)NB*NC*NN*4);
  if (off > ws_size) return;                            // ws too small: fail loudly
  // gather scratch aliases out2 (dead until k_dwgelu)
  float* xq = out2;
  float* kg = out2 + (size_t)NB*NC*NKEEP;

  dim3 blk64x4(64,4);

  k_f_score<<<NB*NN, 64, 0, stream>>>(x, p_in_w, p_in_b, p_ln_w, p_ln_b,
      p_mask_w1, p_mask_b1, p_mask_w2, p_mask_b2, f, score);
  k_topk<<<NB, 1024, 0, stream>>>(score, idx1, flag);
  k_offsets<<<NB*NN/256, 256, 0, stream>>>(f, p_off_w1, p_off_b1, p_off_w2, p_off_b2, offs);
  k_fmean<<<NB*NC4, 256, 0, stream>>>(f, fmean);
  k_ca<<<NB, NC, 0, stream>>>(fmean, p_ca_w, p_ca_b, ca);
  k_sa<<<NB*NN/256, 256, 0, stream>>>(f, p_sa_w, p_sa_b, sa);
  k_conv1x1<<<dim3(NN/256, NC/4, NB), blk64x4, 0, stream>>>(x, v_w, v_b, vbuf);
  k_warp_params<<<NB*NKEEP/256, 256, 0, stream>>>(idx1, offs, wpar, ipar);
  k_gather_q<<<NB*NC*NKEEP/256, 256, 0, stream>>>(x, idx1, xq);
  k_gather_k<<<NB*NC*NKEEP/256, 256, 0, stream>>>(x, idx1, wpar, ipar, kg);
  k_gemm_qk<<<dim3(NKEEP/256, NC/4, NB), blk64x4, 0, stream>>>(xq, q_w, q_b, q1bf);
  k_gemm_qk<<<dim3(NKEEP/256, NC/4, NB), blk64x4, 0, stream>>>(kg, k_w, k_b, k1bf);
  k_gather_vT<<<NB*NC*NKEEP/256, 256, 0, stream>>>(vbuf, idx1, v1T);
  k_fill<<<NB*NC*NN/256, 256, 0, stream>>>(sa, flag, vbuf);
  k_attn<<<dim3(NKEEP/64, NB), 256, 0, stream>>>(q1bf, k1bf, v1T, idx1, vbuf);
  k_dwgelu<<<NB*NC*NN/256, 256, 0, stream>>>(vbuf, ca, cs_w, cs_b, out2);
  k_conv1x1<<<dim3(NN/256, NC/4, NB), blk64x4, 0, stream>>>(out2, out_w, out_b, out);
}

// Round 2
// 1173.731 us; speedup vs baseline: 1.1925x; 1.1925x over previous
//
#include <hip/hip_runtime.h>
#include <hip/hip_bf16.h>

#define NB   8
#define NC   192
#define NH   64
#define NW   64
#define NN   4096        // H*W
#define NCD  194         // C+2
#define NC4  48          // (C+2)/4
#define NKEEP 2048       // N*RATIO
#define NSPLIT 4         // attention K-splits
#define KPS   (NKEEP/NSPLIT)   // 512 keys per split

typedef __attribute__((ext_vector_type(8))) short bf16x8;  // 8 bf16 (4 VGPRs)
typedef __attribute__((ext_vector_type(4))) float f32x4;
typedef __hip_bfloat16 bf16;

__device__ __forceinline__ float dsigmoid(float x){ return 1.f/(1.f+__expf(-x)); }
__device__ __forceinline__ float dlrelu(float x){ return x>0.f ? x : 0.1f*x; }

// ---------------- K0: f = lrelu(LN(conv1x1(cond))), plus score ----------------
// pixel-per-thread; LN over channels is in-register (no shuffles); coalesced x.
__global__ __launch_bounds__(128) void k_f_score(
    const float* __restrict__ x, const float* __restrict__ w_in, const float* __restrict__ b_in,
    const float* __restrict__ ln_w, const float* __restrict__ ln_b,
    const float* __restrict__ mw1, const float* __restrict__ mb1,
    const float* __restrict__ mw2, const float* __restrict__ mb2,
    float* __restrict__ f, float* __restrict__ score)
{
  __shared__ float wT[NCD][NC4];   // transposed weights, 37.25 KB; reads are broadcast
  int t = threadIdx.x;
  for (int i=t; i<NCD*NC4; i+=128){ int o = i/NCD, c = i - o*NCD; wT[c][o] = w_in[i]; }
  __syncthreads();

  int gid = blockIdx.x*128 + t;
  int p = gid & (NN-1), b = gid >> 12;
  int hh = p>>6, ww = p&63;

  f32x4 a4[12];
  #pragma unroll
  for (int j=0;j<12;++j) a4[j] = *(const f32x4*)(b_in + 4*j);

  const float* xb = x + (size_t)b*NC*NN + p;
  for (int c=0;c<NC;++c){
    float xv = xb[(size_t)c*NN];
    #pragma unroll
    for (int j=0;j<12;++j){ f32x4 wv = *(const f32x4*)&wT[c][4*j]; a4[j] += wv*xv; }
  }
  { float gx = -1.f + (2.f/63.f)*(float)ww;
    #pragma unroll
    for (int j=0;j<12;++j){ f32x4 wv = *(const f32x4*)&wT[192][4*j]; a4[j] += wv*gx; }
    float gy = -1.f + (2.f/63.f)*(float)hh;
    #pragma unroll
    for (int j=0;j<12;++j){ f32x4 wv = *(const f32x4*)&wT[193][4*j]; a4[j] += wv*gy; }
  }
  float s1=0.f, s2=0.f;
  #pragma unroll
  for (int j=0;j<12;++j){
    #pragma unroll
    for (int k=0;k<4;++k){ float v=a4[j][k]; s1+=v; s2+=v*v; }
  }
  float mean = s1*(1.f/NC4);
  float var  = s2*(1.f/NC4) - mean*mean;
  float rstd = rsqrtf(var + 1e-6f);
  float tsum = 0.f;
  #pragma unroll
  for (int j=0;j<12;++j){
    f32x4 lw = *(const f32x4*)(ln_w + 4*j);
    f32x4 lb = *(const f32x4*)(ln_b + 4*j);
    #pragma unroll
    for (int k=0;k<4;++k){
      float z = lw[k]*((a4[j][k]-mean)*rstd) + lb[k];
      float fv = z>0.f ? z : 0.1f*z;
      tsum += fv;
      f[((size_t)b*NC4 + 4*j+k)*NN + p] = fv;
    }
  }
  float tm = tsum*(1.f/NC4);
  float sv = dlrelu(tm*mw1[0] + mb1[0]);
  float d  = sv*(mw2[0]-mw2[1]) + (mb2[0]-mb2[1]);
  score[b*NN + p] = dsigmoid(d);
}

// ---------------- K1: per-batch top-2048 via bitonic sort -----------------
__global__ __launch_bounds__(1024) void k_topk(const float* __restrict__ score,
                                               int* __restrict__ idx1, int* __restrict__ flag)
{
  int b = blockIdx.x;
  __shared__ unsigned long long key[NN];
  int t = threadIdx.x;
  for (int i=t;i<NN;i+=1024){
    unsigned u = __float_as_uint(score[b*NN+i]);
    unsigned a = (u & 0x80000000u) ? ~u : (u | 0x80000000u);
    unsigned d = ~a;
    key[i] = ((unsigned long long)d << 32) | (unsigned)i;
  }
  __syncthreads();
  for (int k=2;k<=NN;k<<=1){
    for (int j=k>>1;j>0;j>>=1){
      for (int i=t;i<NN;i+=1024){
        int ixj = i ^ j;
        if (ixj > i){
          unsigned long long a = key[i], c = key[ixj];
          bool up = ((i & k) == 0);
          if (up ? (a > c) : (a < c)){ key[i]=c; key[ixj]=a; }
        }
      }
      __syncthreads();
    }
  }
  for (int i=t;i<NN;i+=1024){
    int id = (int)(unsigned)(key[i] & 0xFFFFFFFFull);
    if (i < NKEEP) idx1[b*NKEEP+i] = id;
    flag[b*NN+id] = (i < NKEEP) ? 1 : 0;
  }
}

// ---------------- K2: offsets = tanh(conv1x1(lrelu(conv1x1(f))))*8 ----------
__global__ __launch_bounds__(256) void k_offsets(
    const float* __restrict__ f, const float* __restrict__ w1, const float* __restrict__ b1,
    const float* __restrict__ w2, const float* __restrict__ b2, float* __restrict__ offs)
{
  int gid = blockIdx.x*256 + threadIdx.x;
  int p = gid & (NN-1);
  int b = gid >> 12;
  const float* fb = f + (size_t)b*NC4*NN + p;
  float fl[NC4];
  #pragma unroll 8
  for (int c=0;c<NC4;++c) fl[c] = fb[(size_t)c*NN];
  float h1[24];
  for (int o=0;o<24;++o){
    const float* wr = w1 + o*NC4;
    float a = b1[o];
    #pragma unroll 8
    for (int c=0;c<NC4;++c) a += wr[c]*fl[c];
    h1[o] = dlrelu(a);
  }
  #pragma unroll
  for (int o=0;o<2;++o){
    const float* wr = w2 + o*24;
    float a = b2[o];
    #pragma unroll
    for (int c=0;c<24;++c) a += wr[c]*h1[c];
    offs[((size_t)b*2+o)*NN + p] = tanhf(a)*8.f;
  }
}

// ---------------- K3: f spatial mean, then ca = sigmoid(fc) -----------------
__global__ __launch_bounds__(256) void k_fmean(const float* __restrict__ f, float* __restrict__ fmean){
  int bc = blockIdx.x;
  const float* p = f + (size_t)bc*NN;
  float s = 0.f;
  for (int i=threadIdx.x;i<NN;i+=256) s += p[i];
  for (int o=32;o;o>>=1) s += __shfl_xor(s,o);
  __shared__ float r[4];
  if ((threadIdx.x&63)==0) r[threadIdx.x>>6] = s;
  __syncthreads();
  if (threadIdx.x==0) fmean[bc] = (r[0]+r[1]+r[2]+r[3])*(1.f/NN);
}

__global__ void k_ca(const float* __restrict__ fmean, const float* __restrict__ w,
                     const float* __restrict__ bias, float* __restrict__ ca){
  int b = blockIdx.x, o = threadIdx.x;
  const float* fm = fmean + b*NC4;
  float a = bias[o];
  #pragma unroll 8
  for (int c=0;c<NC4;++c) a += w[o*NC4+c]*fm[c];
  ca[b*NC+o] = dsigmoid(a);
}

// ---------------- K4: sa = sigmoid(conv3x3(f, 48->1)) -----------------------
__global__ __launch_bounds__(256) void k_sa(const float* __restrict__ f, const float* __restrict__ w,
                                            const float* __restrict__ bias, float* __restrict__ sa){
  int gid = blockIdx.x*256 + threadIdx.x;
  int p = gid & (NN-1);
  int b = gid >> 12;
  int hh=p>>6, ww=p&63;
  float acc = bias[0];
  for (int c=0;c<NC4;++c){
    const float* fp = f + ((size_t)b*NC4+c)*NN;
    const float* wc = w + c*9;
    #pragma unroll
    for (int dy=0;dy<3;++dy){ int yy=hh+dy-1; if(yy<0||yy>63) continue;
      #pragma unroll
      for (int dx=0;dx<3;++dx){ int xx=ww+dx-1; if(xx<0||xx>63) continue;
        acc += fp[yy*64+xx]*wc[dy*3+dx]; } }
  }
  sa[gid] = dsigmoid(acc);
}

// ---------------- conv1x1 192->192 over pixel images (fp32) -----------------
__global__ __launch_bounds__(256) void k_conv1x1(const float* __restrict__ in, const float* __restrict__ w,
                                                 const float* __restrict__ bias, float* __restrict__ outp){
  int p0 = blockIdx.x*256 + threadIdx.x*4;
  int o  = blockIdx.y*4 + threadIdx.y;
  int b  = blockIdx.z;
  const float* ip = in + (size_t)b*NC*NN + p0;
  const float* wr = w + o*NC;
  float a0=0,a1=0,a2=0,a3=0;
  #pragma unroll 4
  for (int c=0;c<NC;++c){
    float4 xv = *(const float4*)(ip + (size_t)c*NN);
    float wv = wr[c];
    a0 += xv.x*wv; a1 += xv.y*wv; a2 += xv.z*wv; a3 += xv.w*wv;
  }
  float bv = bias[o];
  float4 rv; rv.x=a0+bv; rv.y=a1+bv; rv.z=a2+bv; rv.w=a3+bv;
  *(float4*)(outp + ((size_t)b*NC+o)*NN + p0) = rv;
}

// ---------------- warp params per selected token ----------------------------
__global__ __launch_bounds__(256) void k_warp_params(const int* __restrict__ idx1, const float* __restrict__ offs,
                                                     float4* __restrict__ wpar, int4* __restrict__ ipar){
  int gid = blockIdx.x*256 + threadIdx.x;  // B*KEEP
  int b = gid >> 11;
  int p = idx1[gid];
  int ph = p >> 6, pwx = p & 63;
  float fx = offs[((size_t)b*2+0)*NN + p];
  float fy = offs[((size_t)b*2+1)*NN + p];
  float sx = (float)pwx + fx, sy = (float)ph + fy;
  float x0f = floorf(sx), y0f = floorf(sy);
  float wx = sx - x0f, wy = sy - y0f;
  int x0 = (int)x0f, y0 = (int)y0f;
  bool vx0 = (x0f >= 0.f) && (x0f <= 63.f);
  bool vx1 = (x0f+1.f >= 0.f) && (x0f+1.f <= 63.f);
  bool vy0 = (y0f >= 0.f) && (y0f <= 63.f);
  bool vy1 = (y0f+1.f >= 0.f) && (y0f+1.f <= 63.f);
  int cx0 = min(max(x0,0),63), cx1 = min(max(x0+1,0),63);
  int cy0 = min(max(y0,0),63), cy1 = min(max(y0+1,0),63);
  float4 w4;
  w4.x = (vx0&&vy0) ? (1.f-wx)*(1.f-wy) : 0.f;
  w4.y = (vx1&&vy0) ? wx*(1.f-wy)       : 0.f;
  w4.z = (vx0&&vy1) ? (1.f-wx)*wy       : 0.f;
  w4.w = (vx1&&vy1) ? wx*wy             : 0.f;
  int4 i4;
  i4.x = cy0*64+cx0; i4.y = cy0*64+cx1; i4.z = cy1*64+cx0; i4.w = cy1*64+cx1;
  wpar[gid]=w4; ipar[gid]=i4;
}

// ---------------- gathers: xq (x at idx1), kg (x+warp at idx1), v1T ---------
__global__ __launch_bounds__(256) void k_gather_q(const float* __restrict__ x, const int* __restrict__ idx1,
                                                  float* __restrict__ xq){
  int gid = blockIdx.x*256 + threadIdx.x;  // B*C*KEEP
  int s = gid & (NKEEP-1);
  int bc = gid >> 11;
  int b = bc/NC;
  xq[gid] = x[(size_t)bc*NN + idx1[b*NKEEP+s]];
}

__global__ __launch_bounds__(256) void k_gather_k(const float* __restrict__ x, const int* __restrict__ idx1,
                                                  const float4* __restrict__ wpar, const int4* __restrict__ ipar,
                                                  float* __restrict__ kg){
  int gid = blockIdx.x*256 + threadIdx.x;
  int s = gid & (NKEEP-1);
  int bc = gid >> 11;
  int b = bc/NC;
  int bs = b*NKEEP + s;
  int p = idx1[bs];
  float4 w4 = wpar[bs]; int4 i4 = ipar[bs];
  const float* xr = x + (size_t)bc*NN;
  kg[gid] = xr[p] + w4.x*xr[i4.x] + w4.y*xr[i4.y] + w4.z*xr[i4.z] + w4.w*xr[i4.w];
}

__global__ __launch_bounds__(256) void k_gather_vT(const float* __restrict__ v, const int* __restrict__ idx1,
                                                   bf16* __restrict__ v1T){
  int gid = blockIdx.x*256 + threadIdx.x;
  int s = gid & (NKEEP-1);
  int bc = gid >> 11;
  int b = bc/NC;
  v1T[gid] = __float2bfloat16(v[(size_t)bc*NN + idx1[b*NKEEP+s]]);
}

// ---------------- GEMM for q1/k1: [b][c][s] fp32 -> [b][s][o] bf16 ----------
__global__ __launch_bounds__(256) void k_gemm_qk(const float* __restrict__ in, const float* __restrict__ w,
                                                 const float* __restrict__ bias, bf16* __restrict__ outp){
  int s0 = blockIdx.x*256 + threadIdx.x*4;
  int o  = blockIdx.y*4 + threadIdx.y;
  int b  = blockIdx.z;
  const float* ip = in + (size_t)b*NC*NKEEP + s0;
  const float* wr = w + o*NC;
  float a0=0,a1=0,a2=0,a3=0;
  #pragma unroll 4
  for (int c=0;c<NC;++c){
    float4 xv = *(const float4*)(ip + (size_t)c*NKEEP);
    float wv = wr[c];
    a0 += xv.x*wv; a1 += xv.y*wv; a2 += xv.z*wv; a3 += xv.w*wv;
  }
  float bv = bias[o];
  bf16* op = outp + ((size_t)b*NKEEP + s0)*NC + o;
  op[0]     = __float2bfloat16(a0+bv);
  op[NC]    = __float2bfloat16(a1+bv);
  op[2*NC]  = __float2bfloat16(a2+bv);
  op[3*NC]  = __float2bfloat16(a3+bv);
}

// ---------------- fill unselected: out_img = v*sa (in place in v) -----------
__global__ __launch_bounds__(256) void k_fill(const float* __restrict__ sa, const int* __restrict__ flag,
                                              float* __restrict__ vout){
  int gid = blockIdx.x*256 + threadIdx.x;  // B*C*N
  int p = gid & (NN-1);
  int bc = gid >> 12;
  int b = bc/NC;
  if (!flag[b*NN+p]) vout[gid] *= sa[b*NN+p];
}

// ---------------- flash attention, K-split x4, barrier-free -----------------
// grid (32, B, NSPLIT); block 256 = 4 waves x 16 queries; 32-key tiles.
// Writes unnormalized partials (bf16) + per-row m,l (f32); k_merge combines.
__global__ __launch_bounds__(256) void k_attn(const bf16* __restrict__ q1, const bf16* __restrict__ k1,
                                              const bf16* __restrict__ v1T,
                                              bf16* __restrict__ pacc, float* __restrict__ pm, float* __restrict__ pl)
{
  int b = blockIdx.y, qb = blockIdx.x, sp = blockIdx.z;
  int wv = threadIdx.x >> 6;
  int lane = threadIdx.x & 63;
  int g = lane >> 4, r = lane & 15;
  int q0 = qb*64 + wv*16;

  const bf16* qbp = q1 + (size_t)b*NKEEP*NC;
  const bf16* kbp = k1 + (size_t)b*NKEEP*NC;
  const bf16* vbp = v1T + (size_t)b*NC*NKEEP;

  bf16x8 aq[6];
  #pragma unroll
  for (int ks=0;ks<6;++ks)
    aq[ks] = *(const bf16x8*)(qbp + (size_t)(q0+r)*NC + 32*ks + 8*g);

  f32x4 acc[12];
  #pragma unroll
  for (int i=0;i<12;++i){ acc[i][0]=0.f; acc[i][1]=0.f; acc[i][2]=0.f; acc[i][3]=0.f; }
  float m[4]={-1e30f,-1e30f,-1e30f,-1e30f}, l[4]={0.f,0.f,0.f,0.f};

  __shared__ __align__(16) bf16 plds[4][16][40];   // per-wave P tile (no cross-wave use)
  bf16 (* __restrict__ pw)[40] = plds[wv];
  const float scale = 0.07216878364870323f;        // 192^-0.5
  const int kbase = sp*KPS;

  for (int t16=0;t16<KPS/32;++t16) {
    int k0 = kbase + t16*32;
    f32x4 s0v, s1v;
    s0v[0]=s0v[1]=s0v[2]=s0v[3]=0.f;
    s1v[0]=s1v[1]=s1v[2]=s1v[3]=0.f;
    const bf16* kr0 = kbp + (size_t)(k0+r)*NC + 8*g;
    #pragma unroll
    for (int ks=0;ks<6;++ks) {
      bf16x8 bk0 = *(const bf16x8*)(kr0 + 32*ks);
      bf16x8 bk1 = *(const bf16x8*)(kr0 + 16*NC + 32*ks);
      s0v = __builtin_amdgcn_mfma_f32_16x16x32_bf16(aq[ks], bk0, s0v, 0,0,0);
      s1v = __builtin_amdgcn_mfma_f32_16x16x32_bf16(aq[ks], bk1, s1v, 0,0,0);
    }
    float a0[4], a1[4], mx[4];
    bool need = false;
    #pragma unroll
    for (int i=0;i<4;++i) {
      a0[i] = s0v[i]*scale; a1[i] = s1v[i]*scale;
      float mm = fmaxf(a0[i],a1[i]);
      #pragma unroll
      for (int o=1;o<16;o<<=1) mm = fmaxf(mm, __shfl_xor(mm,o));
      mx[i] = mm;
      need = need || (mm > m[i] + 8.f);
    }
    if (__any(need)) {           // T13 defer-max: rescale only when max grew
      float c_[4];
      #pragma unroll
      for (int i=0;i<4;++i){ float mn=fmaxf(m[i],mx[i]); c_[i]=__expf(m[i]-mn); m[i]=mn; l[i]*=c_[i]; }
      #pragma unroll
      for (int ct=0;ct<12;++ct){
        acc[ct][0]*=c_[0]; acc[ct][1]*=c_[1]; acc[ct][2]*=c_[2]; acc[ct][3]*=c_[3];
      }
    }
    #pragma unroll
    for (int i=0;i<4;++i) {
      float e0 = __expf(a0[i]-m[i]), e1 = __expf(a1[i]-m[i]);
      float ls = e0+e1;
      #pragma unroll
      for (int o=1;o<16;o<<=1) ls += __shfl_xor(ls,o);
      l[i] += ls;
      pw[4*g+i][r]    = __float2bfloat16(e0);
      pw[4*g+i][16+r] = __float2bfloat16(e1);
    }
    // wave-synchronous LDS transpose (per-wave buffer; compiler inserts lgkmcnt)
    bf16x8 pa = *(const bf16x8*)(&pw[r][8*g]);
    const bf16* vr = vbp + (size_t)r*NKEEP + k0 + 8*g;
    #pragma unroll
    for (int ct=0;ct<12;++ct) {
      bf16x8 bvv = *(const bf16x8*)(vr + (size_t)(16*ct)*NKEEP);
      acc[ct] = __builtin_amdgcn_mfma_f32_16x16x32_bf16(pa, bvv, acc[ct], 0,0,0);
    }
  }
  size_t pbase = (((size_t)(b*32+qb)*NSPLIT + sp)*64);
  #pragma unroll
  for (int i=0;i<4;++i){
    if (r==0){ pm[pbase + wv*16 + 4*g + i] = m[i]; pl[pbase + wv*16 + 4*g + i] = l[i]; }
  }
  #pragma unroll
  for (int ct=0;ct<12;++ct)
    #pragma unroll
    for (int i=0;i<4;++i)
      pacc[(pbase + wv*16 + 4*g + i)*NC + 16*ct + r] = __float2bfloat16(acc[ct][i]);
}

// ---------------- merge the NSPLIT attention partials + scatter -------------
__global__ __launch_bounds__(256) void k_merge(const bf16* __restrict__ pacc, const float* __restrict__ pm,
                                               const float* __restrict__ pl, const int* __restrict__ idx1,
                                               float* __restrict__ out_img)
{
  int gid = blockIdx.x*256 + threadIdx.x;   // B*KEEP*NC, c fastest
  int c = gid % NC;
  int bs = gid / NC;
  int s = bs & (NKEEP-1);
  int b = bs >> 11;
  int qb = s >> 6, ql = s & 63;
  size_t base = ((size_t)(b*32+qb)*NSPLIT)*64 + ql;
  float m0=pm[base], m1=pm[base+64], m2=pm[base+128], m3=pm[base+192];
  float M = fmaxf(fmaxf(m0,m1),fmaxf(m2,m3));
  float w0=__expf(m0-M), w1=__expf(m1-M), w2=__expf(m2-M), w3=__expf(m3-M);
  float l = w0*pl[base] + w1*pl[base+64] + w2*pl[base+128] + w3*pl[base+192];
  size_t pb = base*NC + c;
  float v = w0*__bfloat162float(pacc[pb])
          + w1*__bfloat162float(pacc[pb + (size_t)64*NC])
          + w2*__bfloat162float(pacc[pb + (size_t)128*NC])
          + w3*__bfloat162float(pacc[pb + (size_t)192*NC]);
  out_img[((size_t)b*NC + c)*NN + idx1[b*NKEEP + s]] = v / l;
}

// ---------------- depthwise 3x3 + gelu*ca + residual ------------------------
__global__ __launch_bounds__(256) void k_dwgelu(const float* __restrict__ vin, const float* __restrict__ ca,
                                                const float* __restrict__ cw, const float* __restrict__ cb,
                                                float* __restrict__ out2){
  int gid = blockIdx.x*256 + threadIdx.x;
  int p = gid & (NN-1);
  int bc = gid >> 12;
  int c = bc % NC, b = bc / NC;
  int hh = p>>6, ww = p&63;
  const float* ip = vin + (size_t)bc*NN;
  float a = cb[c];
  #pragma unroll
  for (int dy=0;dy<3;++dy){ int yy=hh+dy-1; if(yy<0||yy>63) continue;
    #pragma unroll
    for (int dx=0;dx<3;++dx){ int xx=ww+dx-1; if(xx<0||xx>63) continue;
      a += ip[yy*64+xx]*cw[c*9+dy*3+dx]; } }
  float gl = 0.5f*a*(1.f+tanhf(0.79788456080286536f*(a+0.044715f*a*a*a)));
  out2[gid] = gl*ca[b*NC+c] + ip[p];
}

// ============================================================================
extern "C" void kernel_launch(void* const* d_in, const int* in_sizes, int n_in,
                              void* d_out, int out_size, void* d_ws, size_t ws_size,
                              hipStream_t stream)
{
  const float* x       = (const float*)d_in[0];
  const float* p_in_w  = (const float*)d_in[1];
  const float* p_in_b  = (const float*)d_in[2];
  const float* p_ln_w  = (const float*)d_in[3];
  const float* p_ln_b  = (const float*)d_in[4];
  const float* p_off_w1= (const float*)d_in[5];
  const float* p_off_b1= (const float*)d_in[6];
  const float* p_off_w2= (const float*)d_in[7];
  const float* p_off_b2= (const float*)d_in[8];
  const float* p_ca_w  = (const float*)d_in[9];
  const float* p_ca_b  = (const float*)d_in[10];
  const float* p_sa_w  = (const float*)d_in[11];
  const float* p_sa_b  = (const float*)d_in[12];
  const float* p_mask_w1=(const float*)d_in[13];
  const float* p_mask_b1=(const float*)d_in[14];
  const float* p_mask_w2=(const float*)d_in[15];
  const float* p_mask_b2=(const float*)d_in[16];
  const float* v_w     = (const float*)d_in[17];
  const float* v_b     = (const float*)d_in[18];
  const float* q_w     = (const float*)d_in[19];
  const float* q_b     = (const float*)d_in[20];
  const float* k_w     = (const float*)d_in[21];
  const float* k_b     = (const float*)d_in[22];
  const float* cs_w    = (const float*)d_in[23];
  const float* cs_b    = (const float*)d_in[24];
  const float* out_w   = (const float*)d_in[25];
  const float* out_b   = (const float*)d_in[26];
  float* out = (float*)d_out;
  (void)in_sizes; (void)n_in; (void)out_size;

  char* wsp = (char*)d_ws;
  size_t off = 0;
  auto alloc = [&](size_t bytes)->char*{ char* p = wsp + off; off += (bytes + 255) & ~(size_t)255; return p; };
  float* f     = (float*)alloc((size_t)NB*NC4*NN*4);
  float* score = (float*)alloc((size_t)NB*NN*4);
  int*   idx1  = (int*)  alloc((size_t)NB*NKEEP*4);
  int*   flag  = (int*)  alloc((size_t)NB*NN*4);
  float* offs  = (float*)alloc((size_t)NB*2*NN*4);
  float* sa    = (float*)alloc((size_t)NB*NN*4);
  float* fmean = (float*)alloc((size_t)NB*NC4*4);
  float* ca    = (float*)alloc((size_t)NB*NC*4);
  float* vbuf  = (float*)alloc((size_t)NB*NC*NN*4);     // v, later out_img (in place)
  bf16*  q1bf  = (bf16*) alloc((size_t)NB*NKEEP*NC*2);
  bf16*  k1bf  = (bf16*) alloc((size_t)NB*NKEEP*NC*2);
  bf16*  v1T   = (bf16*) alloc((size_t)NB*NC*NKEEP*2);
  float4* wpar = (float4*)alloc((size_t)NB*NKEEP*16);
  int4*   ipar = (int4*) alloc((size_t)NB*NKEEP*16);
  float* out2  = (float*)alloc((size_t)NB*NC*NN*4);
  float* pm    = (float*)alloc((size_t)NB*32*NSPLIT*64*4);
  float* pl    = (float*)alloc((size_t)NB*32*NSPLIT*64*4);
  if (off > ws_size) return;
  // aliases inside out2 (all dead before dwgelu writes out2):
  //   xq/kg fill it during gather+gemm; pacc (bf16, 25.2 MB) reuses the whole
  //   region after gemm_qk has consumed xq/kg.
  float* xq = out2;
  float* kg = out2 + (size_t)NB*NC*NKEEP;
  bf16*  pacc = (bf16*)out2;   // B*32*NSPLIT*64*NC bf16 = 25.2 MB

  dim3 blk64x4(64,4);

  k_f_score<<<NB*NN/128, 128, 0, stream>>>(x, p_in_w, p_in_b, p_ln_w, p_ln_b,
      p_mask_w1, p_mask_b1, p_mask_w2, p_mask_b2, f, score);
  k_topk<<<NB, 1024, 0, stream>>>(score, idx1, flag);
  k_offsets<<<NB*NN/256, 256, 0, stream>>>(f, p_off_w1, p_off_b1, p_off_w2, p_off_b2, offs);
  k_fmean<<<NB*NC4, 256, 0, stream>>>(f, fmean);
  k_ca<<<NB, NC, 0, stream>>>(fmean, p_ca_w, p_ca_b, ca);
  k_sa<<<NB*NN/256, 256, 0, stream>>>(f, p_sa_w, p_sa_b, sa);
  k_conv1x1<<<dim3(NN/256, NC/4, NB), blk64x4, 0, stream>>>(x, v_w, v_b, vbuf);
  k_warp_params<<<NB*NKEEP/256, 256, 0, stream>>>(idx1, offs, wpar, ipar);
  k_gather_q<<<NB*NC*NKEEP/256, 256, 0, stream>>>(x, idx1, xq);
  k_gather_k<<<NB*NC*NKEEP/256, 256, 0, stream>>>(x, idx1, wpar, ipar, kg);
  k_gemm_qk<<<dim3(NKEEP/256, NC/4, NB), blk64x4, 0, stream>>>(xq, q_w, q_b, q1bf);
  k_gemm_qk<<<dim3(NKEEP/256, NC/4, NB), blk64x4, 0, stream>>>(kg, k_w, k_b, k1bf);
  k_gather_vT<<<NB*NC*NKEEP/256, 256, 0, stream>>>(vbuf, idx1, v1T);
  k_fill<<<NB*NC*NN/256, 256, 0, stream>>>(sa, flag, vbuf);
  k_attn<<<dim3(NKEEP/64, NB, NSPLIT), 256, 0, stream>>>(q1bf, k1bf, v1T, pacc, pm, pl);
  k_merge<<<NB*NKEEP*NC/256, 256, 0, stream>>>(pacc, pm, pl, idx1, vbuf);
  k_dwgelu<<<NB*NC*NN/256, 256, 0, stream>>>(vbuf, ca, cs_w, cs_b, out2);
  k_conv1x1<<<dim3(NN/256, NC/4, NB), blk64x4, 0, stream>>>(out2, out_w, out_b, out);
}

// Round 3
// 1169.328 us; speedup vs baseline: 1.1970x; 1.0038x over previous
//
#include <hip/hip_runtime.h>
#include <hip/hip_bf16.h>

#define NB   8
#define NC   192
#define NH   64
#define NW   64
#define NN   4096        // H*W
#define NCD  194         // C+2
#define NC4  48          // (C+2)/4
#define NKEEP 2048       // N*RATIO
#define NSPLIT 4         // attention K-splits
#define KPS   (NKEEP/NSPLIT)   // 512 keys per split

typedef __attribute__((ext_vector_type(8))) short bf16x8;  // 8 bf16 (4 VGPRs)
typedef __attribute__((ext_vector_type(4))) float f32x4;
typedef __hip_bfloat16 bf16;

__device__ __forceinline__ float dsigmoid(float x){ return 1.f/(1.f+__expf(-x)); }
__device__ __forceinline__ float dlrelu(float x){ return x>0.f ? x : 0.1f*x; }

// ---------------- K0: f = lrelu(LN(conv1x1(cond))), plus score ----------------
__global__ __launch_bounds__(128) void k_f_score(
    const float* __restrict__ x, const float* __restrict__ w_in, const float* __restrict__ b_in,
    const float* __restrict__ ln_w, const float* __restrict__ ln_b,
    const float* __restrict__ mw1, const float* __restrict__ mb1,
    const float* __restrict__ mw2, const float* __restrict__ mb2,
    float* __restrict__ f, float* __restrict__ score)
{
  __shared__ float wT[NCD][NC4];   // transposed weights; reads are broadcast
  int t = threadIdx.x;
  for (int i=t; i<NCD*NC4; i+=128){ int o = i/NCD, c = i - o*NCD; wT[c][o] = w_in[i]; }
  __syncthreads();

  int gid = blockIdx.x*128 + t;
  int p = gid & (NN-1), b = gid >> 12;
  int hh = p>>6, ww = p&63;

  f32x4 a4[12];
  #pragma unroll
  for (int j=0;j<12;++j) a4[j] = *(const f32x4*)(b_in + 4*j);

  const float* xb = x + (size_t)b*NC*NN + p;
  for (int c=0;c<NC;++c){
    float xv = xb[(size_t)c*NN];
    #pragma unroll
    for (int j=0;j<12;++j){ f32x4 wv = *(const f32x4*)&wT[c][4*j]; a4[j] += wv*xv; }
  }
  { float gx = -1.f + (2.f/63.f)*(float)ww;
    #pragma unroll
    for (int j=0;j<12;++j){ f32x4 wv = *(const f32x4*)&wT[192][4*j]; a4[j] += wv*gx; }
    float gy = -1.f + (2.f/63.f)*(float)hh;
    #pragma unroll
    for (int j=0;j<12;++j){ f32x4 wv = *(const f32x4*)&wT[193][4*j]; a4[j] += wv*gy; }
  }
  float s1=0.f, s2=0.f;
  #pragma unroll
  for (int j=0;j<12;++j){
    #pragma unroll
    for (int k=0;k<4;++k){ float v=a4[j][k]; s1+=v; s2+=v*v; }
  }
  float mean = s1*(1.f/NC4);
  float var  = s2*(1.f/NC4) - mean*mean;
  float rstd = rsqrtf(var + 1e-6f);
  float tsum = 0.f;
  #pragma unroll
  for (int j=0;j<12;++j){
    f32x4 lw = *(const f32x4*)(ln_w + 4*j);
    f32x4 lb = *(const f32x4*)(ln_b + 4*j);
    #pragma unroll
    for (int k=0;k<4;++k){
      float z = lw[k]*((a4[j][k]-mean)*rstd) + lb[k];
      float fv = z>0.f ? z : 0.1f*z;
      tsum += fv;
      f[((size_t)b*NC4 + 4*j+k)*NN + p] = fv;
    }
  }
  float tm = tsum*(1.f/NC4);
  float sv = dlrelu(tm*mw1[0] + mb1[0]);
  float d  = sv*(mw2[0]-mw2[1]) + (mb2[0]-mb2[1]);
  score[b*NN + p] = dsigmoid(d);
}

// ---------------- K1: per-batch top-2048 via bitonic sort -----------------
__global__ __launch_bounds__(1024) void k_topk(const float* __restrict__ score,
                                               int* __restrict__ idx1, int* __restrict__ flag)
{
  int b = blockIdx.x;
  __shared__ unsigned long long key[NN];
  int t = threadIdx.x;
  for (int i=t;i<NN;i+=1024){
    unsigned u = __float_as_uint(score[b*NN+i]);
    unsigned a = (u & 0x80000000u) ? ~u : (u | 0x80000000u);
    unsigned d = ~a;
    key[i] = ((unsigned long long)d << 32) | (unsigned)i;
  }
  __syncthreads();
  for (int k=2;k<=NN;k<<=1){
    for (int j=k>>1;j>0;j>>=1){
      for (int i=t;i<NN;i+=1024){
        int ixj = i ^ j;
        if (ixj > i){
          unsigned long long a = key[i], c = key[ixj];
          bool up = ((i & k) == 0);
          if (up ? (a > c) : (a < c)){ key[i]=c; key[ixj]=a; }
        }
      }
      __syncthreads();
    }
  }
  for (int i=t;i<NN;i+=1024){
    int id = (int)(unsigned)(key[i] & 0xFFFFFFFFull);
    if (i < NKEEP) idx1[b*NKEEP+i] = id;
    flag[b*NN+id] = (i < NKEEP) ? 1 : 0;
  }
}

// ---------------- K2: offsets = tanh(conv1x1(lrelu(conv1x1(f))))*8 ----------
__global__ __launch_bounds__(256) void k_offsets(
    const float* __restrict__ f, const float* __restrict__ w1, const float* __restrict__ b1,
    const float* __restrict__ w2, const float* __restrict__ b2, float* __restrict__ offs)
{
  int gid = blockIdx.x*256 + threadIdx.x;
  int p = gid & (NN-1);
  int b = gid >> 12;
  const float* fb = f + (size_t)b*NC4*NN + p;
  float fl[NC4];
  #pragma unroll 8
  for (int c=0;c<NC4;++c) fl[c] = fb[(size_t)c*NN];
  float h1[24];
  for (int o=0;o<24;++o){
    const float* wr = w1 + o*NC4;
    float a = b1[o];
    #pragma unroll 8
    for (int c=0;c<NC4;++c) a += wr[c]*fl[c];
    h1[o] = dlrelu(a);
  }
  #pragma unroll
  for (int o=0;o<2;++o){
    const float* wr = w2 + o*24;
    float a = b2[o];
    #pragma unroll
    for (int c=0;c<24;++c) a += wr[c]*h1[c];
    offs[((size_t)b*2+o)*NN + p] = tanhf(a)*8.f;
  }
}

// ---------------- K3: f spatial mean, then ca = sigmoid(fc) -----------------
__global__ __launch_bounds__(256) void k_fmean(const float* __restrict__ f, float* __restrict__ fmean){
  int bc = blockIdx.x;
  const float* p = f + (size_t)bc*NN;
  float s = 0.f;
  for (int i=threadIdx.x;i<NN;i+=256) s += p[i];
  for (int o=32;o;o>>=1) s += __shfl_xor(s,o);
  __shared__ float r[4];
  if ((threadIdx.x&63)==0) r[threadIdx.x>>6] = s;
  __syncthreads();
  if (threadIdx.x==0) fmean[bc] = (r[0]+r[1]+r[2]+r[3])*(1.f/NN);
}

__global__ void k_ca(const float* __restrict__ fmean, const float* __restrict__ w,
                     const float* __restrict__ bias, float* __restrict__ ca){
  int b = blockIdx.x, o = threadIdx.x;
  const float* fm = fmean + b*NC4;
  float a = bias[o];
  #pragma unroll 8
  for (int c=0;c<NC4;++c) a += w[o*NC4+c]*fm[c];
  ca[b*NC+o] = dsigmoid(a);
}

// ---------------- K4: sa = sigmoid(conv3x3(f, 48->1)) -----------------------
__global__ __launch_bounds__(256) void k_sa(const float* __restrict__ f, const float* __restrict__ w,
                                            const float* __restrict__ bias, float* __restrict__ sa){
  int gid = blockIdx.x*256 + threadIdx.x;
  int p = gid & (NN-1);
  int b = gid >> 12;
  int hh=p>>6, ww=p&63;
  float acc = bias[0];
  for (int c=0;c<NC4;++c){
    const float* fp = f + ((size_t)b*NC4+c)*NN;
    const float* wc = w + c*9;
    #pragma unroll
    for (int dy=0;dy<3;++dy){ int yy=hh+dy-1; if(yy<0||yy>63) continue;
      #pragma unroll
      for (int dx=0;dx<3;++dx){ int xx=ww+dx-1; if(xx<0||xx>63) continue;
        acc += fp[yy*64+xx]*wc[dy*3+dx]; } }
  }
  sa[gid] = dsigmoid(acc);
}

// ---------------- conv1x1 192->192 over pixel images (fp32) -----------------
__global__ __launch_bounds__(256) void k_conv1x1(const float* __restrict__ in, const float* __restrict__ w,
                                                 const float* __restrict__ bias, float* __restrict__ outp){
  int p0 = blockIdx.x*256 + threadIdx.x*4;
  int o  = blockIdx.y*4 + threadIdx.y;
  int b  = blockIdx.z;
  const float* ip = in + (size_t)b*NC*NN + p0;
  const float* wr = w + o*NC;
  float a0=0,a1=0,a2=0,a3=0;
  #pragma unroll 4
  for (int c=0;c<NC;++c){
    float4 xv = *(const float4*)(ip + (size_t)c*NN);
    float wv = wr[c];
    a0 += xv.x*wv; a1 += xv.y*wv; a2 += xv.z*wv; a3 += xv.w*wv;
  }
  float bv = bias[o];
  float4 rv; rv.x=a0+bv; rv.y=a1+bv; rv.z=a2+bv; rv.w=a3+bv;
  *(float4*)(outp + ((size_t)b*NC+o)*NN + p0) = rv;
}

// ---------------- warp params per selected token ----------------------------
__global__ __launch_bounds__(256) void k_warp_params(const int* __restrict__ idx1, const float* __restrict__ offs,
                                                     float4* __restrict__ wpar, int4* __restrict__ ipar){
  int gid = blockIdx.x*256 + threadIdx.x;  // B*KEEP
  int b = gid >> 11;
  int p = idx1[gid];
  int ph = p >> 6, pwx = p & 63;
  float fx = offs[((size_t)b*2+0)*NN + p];
  float fy = offs[((size_t)b*2+1)*NN + p];
  float sx = (float)pwx + fx, sy = (float)ph + fy;
  float x0f = floorf(sx), y0f = floorf(sy);
  float wx = sx - x0f, wy = sy - y0f;
  int x0 = (int)x0f, y0 = (int)y0f;
  bool vx0 = (x0f >= 0.f) && (x0f <= 63.f);
  bool vx1 = (x0f+1.f >= 0.f) && (x0f+1.f <= 63.f);
  bool vy0 = (y0f >= 0.f) && (y0f <= 63.f);
  bool vy1 = (y0f+1.f >= 0.f) && (y0f+1.f <= 63.f);
  int cx0 = min(max(x0,0),63), cx1 = min(max(x0+1,0),63);
  int cy0 = min(max(y0,0),63), cy1 = min(max(y0+1,0),63);
  float4 w4;
  w4.x = (vx0&&vy0) ? (1.f-wx)*(1.f-wy) : 0.f;
  w4.y = (vx1&&vy0) ? wx*(1.f-wy)       : 0.f;
  w4.z = (vx0&&vy1) ? (1.f-wx)*wy       : 0.f;
  w4.w = (vx1&&vy1) ? wx*wy             : 0.f;
  int4 i4;
  i4.x = cy0*64+cx0; i4.y = cy0*64+cx1; i4.z = cy1*64+cx0; i4.w = cy1*64+cx1;
  wpar[gid]=w4; ipar[gid]=i4;
}

// ---------------- gathers: xq (x at idx1), kg (x+warp at idx1), v1T ---------
__global__ __launch_bounds__(256) void k_gather_q(const float* __restrict__ x, const int* __restrict__ idx1,
                                                  float* __restrict__ xq){
  int gid = blockIdx.x*256 + threadIdx.x;  // B*C*KEEP
  int s = gid & (NKEEP-1);
  int bc = gid >> 11;
  int b = bc/NC;
  xq[gid] = x[(size_t)bc*NN + idx1[b*NKEEP+s]];
}

__global__ __launch_bounds__(256) void k_gather_k(const float* __restrict__ x, const int* __restrict__ idx1,
                                                  const float4* __restrict__ wpar, const int4* __restrict__ ipar,
                                                  float* __restrict__ kg){
  int gid = blockIdx.x*256 + threadIdx.x;
  int s = gid & (NKEEP-1);
  int bc = gid >> 11;
  int b = bc/NC;
  int bs = b*NKEEP + s;
  int p = idx1[bs];
  float4 w4 = wpar[bs]; int4 i4 = ipar[bs];
  const float* xr = x + (size_t)bc*NN;
  kg[gid] = xr[p] + w4.x*xr[i4.x] + w4.y*xr[i4.y] + w4.z*xr[i4.z] + w4.w*xr[i4.w];
}

__global__ __launch_bounds__(256) void k_gather_vT(const float* __restrict__ v, const int* __restrict__ idx1,
                                                   bf16* __restrict__ v1T){
  int gid = blockIdx.x*256 + threadIdx.x;
  int s = gid & (NKEEP-1);
  int bc = gid >> 11;
  int b = bc/NC;
  v1T[gid] = __float2bfloat16(v[(size_t)bc*NN + idx1[b*NKEEP+s]]);
}

// ---------------- GEMM for q1/k1: [b][c][s] fp32 -> [b][s][o] bf16 ----------
__global__ __launch_bounds__(256) void k_gemm_qk(const float* __restrict__ in, const float* __restrict__ w,
                                                 const float* __restrict__ bias, bf16* __restrict__ outp){
  int s0 = blockIdx.x*256 + threadIdx.x*4;
  int o  = blockIdx.y*4 + threadIdx.y;
  int b  = blockIdx.z;
  const float* ip = in + (size_t)b*NC*NKEEP + s0;
  const float* wr = w + o*NC;
  float a0=0,a1=0,a2=0,a3=0;
  #pragma unroll 4
  for (int c=0;c<NC;++c){
    float4 xv = *(const float4*)(ip + (size_t)c*NKEEP);
    float wv = wr[c];
    a0 += xv.x*wv; a1 += xv.y*wv; a2 += xv.z*wv; a3 += xv.w*wv;
  }
  float bv = bias[o];
  bf16* op = outp + ((size_t)b*NKEEP + s0)*NC + o;
  op[0]     = __float2bfloat16(a0+bv);
  op[NC]    = __float2bfloat16(a1+bv);
  op[2*NC]  = __float2bfloat16(a2+bv);
  op[3*NC]  = __float2bfloat16(a3+bv);
}

// ---------------- fill unselected: out_img = v*sa (in place in v) -----------
__global__ __launch_bounds__(256) void k_fill(const float* __restrict__ sa, const int* __restrict__ flag,
                                              float* __restrict__ vout){
  int gid = blockIdx.x*256 + threadIdx.x;  // B*C*N
  int p = gid & (NN-1);
  int bc = gid >> 12;
  int b = bc/NC;
  if (!flag[b*NN+p]) vout[gid] *= sa[b*NN+p];
}

// ---------------- flash attention, K-split x4, no-max softmax ---------------
// exp(s - 20) uniformly (constant shift cancels in v/l); no cross-lane work in
// the loop: l accumulates lane-locally, reduced once at the end. Partials are
// plain sums across splits -> merge has no exp.
__global__ __launch_bounds__(256) void k_attn(const bf16* __restrict__ q1, const bf16* __restrict__ k1,
                                              const bf16* __restrict__ v1T,
                                              bf16* __restrict__ pacc, float* __restrict__ pl)
{
  int b = blockIdx.y, qb = blockIdx.x, sp = blockIdx.z;
  int wv = threadIdx.x >> 6;
  int lane = threadIdx.x & 63;
  int g = lane >> 4, r = lane & 15;
  int q0 = qb*64 + wv*16;

  const bf16* qbp = q1 + (size_t)b*NKEEP*NC;
  const bf16* kbp = k1 + (size_t)b*NKEEP*NC;
  const bf16* vbp = v1T + (size_t)b*NC*NKEEP;

  bf16x8 aq[6];
  #pragma unroll
  for (int ks=0;ks<6;++ks)
    aq[ks] = *(const bf16x8*)(qbp + (size_t)(q0+r)*NC + 32*ks + 8*g);

  f32x4 acc[12];
  #pragma unroll
  for (int i=0;i<12;++i){ acc[i][0]=0.f; acc[i][1]=0.f; acc[i][2]=0.f; acc[i][3]=0.f; }
  float l[4]={0.f,0.f,0.f,0.f};

  __shared__ __align__(16) bf16 plds[4][16][40];   // per-wave P tile (wave-synchronous)
  bf16 (* __restrict__ pw)[40] = plds[wv];
  const float scale = 0.07216878364870323f;        // 192^-0.5
  const float shift = 20.f;                        // uniform; cancels in v/l
  const int kbase = sp*KPS;

  for (int t16=0;t16<KPS/32;++t16) {
    int k0 = kbase + t16*32;
    f32x4 s0v, s1v;
    s0v[0]=s0v[1]=s0v[2]=s0v[3]=0.f;
    s1v[0]=s1v[1]=s1v[2]=s1v[3]=0.f;
    const bf16* kr0 = kbp + (size_t)(k0+r)*NC + 8*g;
    #pragma unroll
    for (int ks=0;ks<6;++ks) {
      bf16x8 bk0 = *(const bf16x8*)(kr0 + 32*ks);
      bf16x8 bk1 = *(const bf16x8*)(kr0 + 16*NC + 32*ks);
      s0v = __builtin_amdgcn_mfma_f32_16x16x32_bf16(aq[ks], bk0, s0v, 0,0,0);
      s1v = __builtin_amdgcn_mfma_f32_16x16x32_bf16(aq[ks], bk1, s1v, 0,0,0);
    }
    #pragma unroll
    for (int i=0;i<4;++i) {
      float e0 = __expf(s0v[i]*scale - shift);
      float e1 = __expf(s1v[i]*scale - shift);
      l[i] += e0 + e1;
      pw[4*g+i][r]    = __float2bfloat16(e0);
      pw[4*g+i][16+r] = __float2bfloat16(e1);
    }
    bf16x8 pa = *(const bf16x8*)(&pw[r][8*g]);
    const bf16* vr = vbp + (size_t)r*NKEEP + k0 + 8*g;
    #pragma unroll
    for (int ct=0;ct<12;++ct) {
      bf16x8 bvv = *(const bf16x8*)(vr + (size_t)(16*ct)*NKEEP);
      acc[ct] = __builtin_amdgcn_mfma_f32_16x16x32_bf16(pa, bvv, acc[ct], 0,0,0);
    }
  }
  // reduce l over the 16 lanes sharing each query row (same g)
  #pragma unroll
  for (int i=0;i<4;++i){
    #pragma unroll
    for (int o=1;o<16;o<<=1) l[i] += __shfl_xor(l[i],o);
  }
  size_t pbase = (((size_t)(b*32+qb)*NSPLIT + sp)*64);
  if (r==0){
    #pragma unroll
    for (int i=0;i<4;++i) pl[pbase + wv*16 + 4*g + i] = l[i];
  }
  #pragma unroll
  for (int ct=0;ct<12;++ct)
    #pragma unroll
    for (int i=0;i<4;++i)
      pacc[(pbase + wv*16 + 4*g + i)*NC + 16*ct + r] = __float2bfloat16(acc[ct][i]);
}

// ---------------- merge the NSPLIT attention partials + scatter -------------
__global__ __launch_bounds__(256) void k_merge(const bf16* __restrict__ pacc,
                                               const float* __restrict__ pl, const int* __restrict__ idx1,
                                               float* __restrict__ out_img)
{
  int gid = blockIdx.x*256 + threadIdx.x;   // B*KEEP*NC, c fastest
  int c = gid % NC;
  int bs = gid / NC;
  int s = bs & (NKEEP-1);
  int b = bs >> 11;
  int qb = s >> 6, ql = s & 63;
  size_t base = ((size_t)(b*32+qb)*NSPLIT)*64 + ql;
  float l = pl[base] + pl[base+64] + pl[base+128] + pl[base+192];
  size_t pb = base*NC + c;
  float v = __bfloat162float(pacc[pb])
          + __bfloat162float(pacc[pb + (size_t)64*NC])
          + __bfloat162float(pacc[pb + (size_t)128*NC])
          + __bfloat162float(pacc[pb + (size_t)192*NC]);
  out_img[((size_t)b*NC + c)*NN + idx1[b*NKEEP + s]] = v / l;
}

// ---------------- depthwise 3x3 + gelu*ca + residual ------------------------
__global__ __launch_bounds__(256) void k_dwgelu(const float* __restrict__ vin, const float* __restrict__ ca,
                                                const float* __restrict__ cw, const float* __restrict__ cb,
                                                float* __restrict__ out2){
  int gid = blockIdx.x*256 + threadIdx.x;
  int p = gid & (NN-1);
  int bc = gid >> 12;
  int c = bc % NC, b = bc / NC;
  int hh = p>>6, ww = p&63;
  const float* ip = vin + (size_t)bc*NN;
  float a = cb[c];
  #pragma unroll
  for (int dy=0;dy<3;++dy){ int yy=hh+dy-1; if(yy<0||yy>63) continue;
    #pragma unroll
    for (int dx=0;dx<3;++dx){ int xx=ww+dx-1; if(xx<0||xx>63) continue;
      a += ip[yy*64+xx]*cw[c*9+dy*3+dx]; } }
  float gl = 0.5f*a*(1.f+tanhf(0.79788456080286536f*(a+0.044715f*a*a*a)));
  out2[gid] = gl*ca[b*NC+c] + ip[p];
}

// ============================================================================
extern "C" void kernel_launch(void* const* d_in, const int* in_sizes, int n_in,
                              void* d_out, int out_size, void* d_ws, size_t ws_size,
                              hipStream_t stream)
{
  const float* x       = (const float*)d_in[0];
  const float* p_in_w  = (const float*)d_in[1];
  const float* p_in_b  = (const float*)d_in[2];
  const float* p_ln_w  = (const float*)d_in[3];
  const float* p_ln_b  = (const float*)d_in[4];
  const float* p_off_w1= (const float*)d_in[5];
  const float* p_off_b1= (const float*)d_in[6];
  const float* p_off_w2= (const float*)d_in[7];
  const float* p_off_b2= (const float*)d_in[8];
  const float* p_ca_w  = (const float*)d_in[9];
  const float* p_ca_b  = (const float*)d_in[10];
  const float* p_sa_w  = (const float*)d_in[11];
  const float* p_sa_b  = (const float*)d_in[12];
  const float* p_mask_w1=(const float*)d_in[13];
  const float* p_mask_b1=(const float*)d_in[14];
  const float* p_mask_w2=(const float*)d_in[15];
  const float* p_mask_b2=(const float*)d_in[16];
  const float* v_w     = (const float*)d_in[17];
  const float* v_b     = (const float*)d_in[18];
  const float* q_w     = (const float*)d_in[19];
  const float* q_b     = (const float*)d_in[20];
  const float* k_w     = (const float*)d_in[21];
  const float* k_b     = (const float*)d_in[22];
  const float* cs_w    = (const float*)d_in[23];
  const float* cs_b    = (const float*)d_in[24];
  const float* out_w   = (const float*)d_in[25];
  const float* out_b   = (const float*)d_in[26];
  float* out = (float*)d_out;
  (void)in_sizes; (void)n_in; (void)out_size;

  char* wsp = (char*)d_ws;
  size_t off = 0;
  auto alloc = [&](size_t bytes)->char*{ char* p = wsp + off; off += (bytes + 255) & ~(size_t)255; return p; };
  float* f     = (float*)alloc((size_t)NB*NC4*NN*4);
  float* score = (float*)alloc((size_t)NB*NN*4);
  int*   idx1  = (int*)  alloc((size_t)NB*NKEEP*4);
  int*   flag  = (int*)  alloc((size_t)NB*NN*4);
  float* offs  = (float*)alloc((size_t)NB*2*NN*4);
  float* sa    = (float*)alloc((size_t)NB*NN*4);
  float* fmean = (float*)alloc((size_t)NB*NC4*4);
  float* ca    = (float*)alloc((size_t)NB*NC*4);
  float* vbuf  = (float*)alloc((size_t)NB*NC*NN*4);     // v, later out_img (in place)
  bf16*  q1bf  = (bf16*) alloc((size_t)NB*NKEEP*NC*2);
  bf16*  k1bf  = (bf16*) alloc((size_t)NB*NKEEP*NC*2);
  bf16*  v1T   = (bf16*) alloc((size_t)NB*NC*NKEEP*2);
  float4* wpar = (float4*)alloc((size_t)NB*NKEEP*16);
  int4*   ipar = (int4*) alloc((size_t)NB*NKEEP*16);
  float* out2  = (float*)alloc((size_t)NB*NC*NN*4);
  float* pl    = (float*)alloc((size_t)NB*32*NSPLIT*64*4);
  if (off > ws_size) return;
  // aliases inside out2 (all dead before dwgelu writes out2):
  float* xq = out2;
  float* kg = out2 + (size_t)NB*NC*NKEEP;
  bf16*  pacc = (bf16*)out2;   // B*KEEP*NSPLIT*NC bf16 = 25.2 MB

  dim3 blk64x4(64,4);

  k_f_score<<<NB*NN/128, 128, 0, stream>>>(x, p_in_w, p_in_b, p_ln_w, p_ln_b,
      p_mask_w1, p_mask_b1, p_mask_w2, p_mask_b2, f, score);
  k_topk<<<NB, 1024, 0, stream>>>(score, idx1, flag);
  k_offsets<<<NB*NN/256, 256, 0, stream>>>(f, p_off_w1, p_off_b1, p_off_w2, p_off_b2, offs);
  k_fmean<<<NB*NC4, 256, 0, stream>>>(f, fmean);
  k_ca<<<NB, NC, 0, stream>>>(fmean, p_ca_w, p_ca_b, ca);
  k_sa<<<NB*NN/256, 256, 0, stream>>>(f, p_sa_w, p_sa_b, sa);
  k_conv1x1<<<dim3(NN/256, NC/4, NB), blk64x4, 0, stream>>>(x, v_w, v_b, vbuf);
  k_warp_params<<<NB*NKEEP/256, 256, 0, stream>>>(idx1, offs, wpar, ipar);
  k_gather_q<<<NB*NC*NKEEP/256, 256, 0, stream>>>(x, idx1, xq);
  k_gather_k<<<NB*NC*NKEEP/256, 256, 0, stream>>>(x, idx1, wpar, ipar, kg);
  k_gemm_qk<<<dim3(NKEEP/256, NC/4, NB), blk64x4, 0, stream>>>(xq, q_w, q_b, q1bf);
  k_gemm_qk<<<dim3(NKEEP/256, NC/4, NB), blk64x4, 0, stream>>>(kg, k_w, k_b, k1bf);
  k_gather_vT<<<NB*NC*NKEEP/256, 256, 0, stream>>>(vbuf, idx1, v1T);
  k_fill<<<NB*NC*NN/256, 256, 0, stream>>>(sa, flag, vbuf);
  k_attn<<<dim3(NKEEP/64, NB, NSPLIT), 256, 0, stream>>>(q1bf, k1bf, v1T, pacc, pl);
  k_merge<<<NB*NKEEP*NC/256, 256, 0, stream>>>(pacc, pl, idx1, vbuf);
  k_dwgelu<<<NB*NC*NN/256, 256, 0, stream>>>(vbuf, ca, cs_w, cs_b, out2);
  k_conv1x1<<<dim3(NN/256, NC/4, NB), blk64x4, 0, stream>>>(out2, out_w, out_b, out);
}

// Round 4
// 1043.555 us; speedup vs baseline: 1.3412x; 1.1205x over previous
//
#include <hip/hip_runtime.h>
#include <hip/hip_bf16.h>

#define NB   8
#define NC   192
#define NH   64
#define NW   64
#define NN   4096        // H*W
#define NCD  194         // C+2
#define NC4  48          // (C+2)/4
#define NKEEP 2048       // N*RATIO
#define NSPLIT 4         // attention K-splits
#define KPS   (NKEEP/NSPLIT)   // 512 keys per split
#define NT    (KPS/32)         // 16 key-tiles per split

typedef __attribute__((ext_vector_type(8))) short bf16x8;  // 8 bf16 (4 VGPRs)
typedef __attribute__((ext_vector_type(4))) float f32x4;
typedef __hip_bfloat16 bf16;

__device__ __forceinline__ float dsigmoid(float x){ return 1.f/(1.f+__expf(-x)); }
__device__ __forceinline__ float dlrelu(float x){ return x>0.f ? x : 0.1f*x; }

// ---------------- K0: f = lrelu(LN(conv1x1(cond))), plus score ----------------
__global__ __launch_bounds__(128) void k_f_score(
    const float* __restrict__ x, const float* __restrict__ w_in, const float* __restrict__ b_in,
    const float* __restrict__ ln_w, const float* __restrict__ ln_b,
    const float* __restrict__ mw1, const float* __restrict__ mb1,
    const float* __restrict__ mw2, const float* __restrict__ mb2,
    float* __restrict__ f, float* __restrict__ score)
{
  __shared__ float wT[NCD][NC4];   // transposed weights; reads are broadcast
  int t = threadIdx.x;
  for (int i=t; i<NCD*NC4; i+=128){ int o = i/NCD, c = i - o*NCD; wT[c][o] = w_in[i]; }
  __syncthreads();

  int gid = blockIdx.x*128 + t;
  int p = gid & (NN-1), b = gid >> 12;
  int hh = p>>6, ww = p&63;

  f32x4 a4[12];
  #pragma unroll
  for (int j=0;j<12;++j) a4[j] = *(const f32x4*)(b_in + 4*j);

  const float* xb = x + (size_t)b*NC*NN + p;
  for (int c=0;c<NC;++c){
    float xv = xb[(size_t)c*NN];
    #pragma unroll
    for (int j=0;j<12;++j){ f32x4 wv = *(const f32x4*)&wT[c][4*j]; a4[j] += wv*xv; }
  }
  { float gx = -1.f + (2.f/63.f)*(float)ww;
    #pragma unroll
    for (int j=0;j<12;++j){ f32x4 wv = *(const f32x4*)&wT[192][4*j]; a4[j] += wv*gx; }
    float gy = -1.f + (2.f/63.f)*(float)hh;
    #pragma unroll
    for (int j=0;j<12;++j){ f32x4 wv = *(const f32x4*)&wT[193][4*j]; a4[j] += wv*gy; }
  }
  float s1=0.f, s2=0.f;
  #pragma unroll
  for (int j=0;j<12;++j){
    #pragma unroll
    for (int k=0;k<4;++k){ float v=a4[j][k]; s1+=v; s2+=v*v; }
  }
  float mean = s1*(1.f/NC4);
  float var  = s2*(1.f/NC4) - mean*mean;
  float rstd = rsqrtf(var + 1e-6f);
  float tsum = 0.f;
  #pragma unroll
  for (int j=0;j<12;++j){
    f32x4 lw = *(const f32x4*)(ln_w + 4*j);
    f32x4 lb = *(const f32x4*)(ln_b + 4*j);
    #pragma unroll
    for (int k=0;k<4;++k){
      float z = lw[k]*((a4[j][k]-mean)*rstd) + lb[k];
      float fv = z>0.f ? z : 0.1f*z;
      tsum += fv;
      f[((size_t)b*NC4 + 4*j+k)*NN + p] = fv;
    }
  }
  float tm = tsum*(1.f/NC4);
  float sv = dlrelu(tm*mw1[0] + mb1[0]);
  float d  = sv*(mw2[0]-mw2[1]) + (mb2[0]-mb2[1]);
  score[b*NN + p] = dsigmoid(d);
}

// ---------------- K1: per-batch top-2048 via bitonic sort -----------------
__global__ __launch_bounds__(1024) void k_topk(const float* __restrict__ score,
                                               int* __restrict__ idx1, int* __restrict__ flag)
{
  int b = blockIdx.x;
  __shared__ unsigned long long key[NN];
  int t = threadIdx.x;
  for (int i=t;i<NN;i+=1024){
    unsigned u = __float_as_uint(score[b*NN+i]);
    unsigned a = (u & 0x80000000u) ? ~u : (u | 0x80000000u);
    unsigned d = ~a;
    key[i] = ((unsigned long long)d << 32) | (unsigned)i;
  }
  __syncthreads();
  for (int k=2;k<=NN;k<<=1){
    for (int j=k>>1;j>0;j>>=1){
      for (int i=t;i<NN;i+=1024){
        int ixj = i ^ j;
        if (ixj > i){
          unsigned long long a = key[i], c = key[ixj];
          bool up = ((i & k) == 0);
          if (up ? (a > c) : (a < c)){ key[i]=c; key[ixj]=a; }
        }
      }
      __syncthreads();
    }
  }
  for (int i=t;i<NN;i+=1024){
    int id = (int)(unsigned)(key[i] & 0xFFFFFFFFull);
    if (i < NKEEP) idx1[b*NKEEP+i] = id;
    flag[b*NN+id] = (i < NKEEP) ? 1 : 0;
  }
}

// ---------------- K2: offsets = tanh(conv1x1(lrelu(conv1x1(f))))*8 ----------
__global__ __launch_bounds__(256) void k_offsets(
    const float* __restrict__ f, const float* __restrict__ w1, const float* __restrict__ b1,
    const float* __restrict__ w2, const float* __restrict__ b2, float* __restrict__ offs)
{
  int gid = blockIdx.x*256 + threadIdx.x;
  int p = gid & (NN-1);
  int b = gid >> 12;
  const float* fb = f + (size_t)b*NC4*NN + p;
  float fl[NC4];
  #pragma unroll 8
  for (int c=0;c<NC4;++c) fl[c] = fb[(size_t)c*NN];
  float h1[24];
  for (int o=0;o<24;++o){
    const float* wr = w1 + o*NC4;
    float a = b1[o];
    #pragma unroll 8
    for (int c=0;c<NC4;++c) a += wr[c]*fl[c];
    h1[o] = dlrelu(a);
  }
  #pragma unroll
  for (int o=0;o<2;++o){
    const float* wr = w2 + o*24;
    float a = b2[o];
    #pragma unroll
    for (int c=0;c<24;++c) a += wr[c]*h1[c];
    offs[((size_t)b*2+o)*NN + p] = tanhf(a)*8.f;
  }
}

// ---------------- K3: f spatial mean, then ca = sigmoid(fc) -----------------
__global__ __launch_bounds__(256) void k_fmean(const float* __restrict__ f, float* __restrict__ fmean){
  int bc = blockIdx.x;
  const float* p = f + (size_t)bc*NN;
  float s = 0.f;
  for (int i=threadIdx.x;i<NN;i+=256) s += p[i];
  for (int o=32;o;o>>=1) s += __shfl_xor(s,o);
  __shared__ float r[4];
  if ((threadIdx.x&63)==0) r[threadIdx.x>>6] = s;
  __syncthreads();
  if (threadIdx.x==0) fmean[bc] = (r[0]+r[1]+r[2]+r[3])*(1.f/NN);
}

__global__ void k_ca(const float* __restrict__ fmean, const float* __restrict__ w,
                     const float* __restrict__ bias, float* __restrict__ ca){
  int b = blockIdx.x, o = threadIdx.x;
  const float* fm = fmean + b*NC4;
  float a = bias[o];
  #pragma unroll 8
  for (int c=0;c<NC4;++c) a += w[o*NC4+c]*fm[c];
  ca[b*NC+o] = dsigmoid(a);
}

// ---------------- K4: sa = sigmoid(conv3x3(f, 48->1)) -----------------------
__global__ __launch_bounds__(256) void k_sa(const float* __restrict__ f, const float* __restrict__ w,
                                            const float* __restrict__ bias, float* __restrict__ sa){
  int gid = blockIdx.x*256 + threadIdx.x;
  int p = gid & (NN-1);
  int b = gid >> 12;
  int hh=p>>6, ww=p&63;
  float acc = bias[0];
  for (int c=0;c<NC4;++c){
    const float* fp = f + ((size_t)b*NC4+c)*NN;
    const float* wc = w + c*9;
    #pragma unroll
    for (int dy=0;dy<3;++dy){ int yy=hh+dy-1; if(yy<0||yy>63) continue;
      #pragma unroll
      for (int dx=0;dx<3;++dx){ int xx=ww+dx-1; if(xx<0||xx>63) continue;
        acc += fp[yy*64+xx]*wc[dy*3+dx]; } }
  }
  sa[gid] = dsigmoid(acc);
}

// ---------------- conv1x1 192->192 over pixel images (fp32) -----------------
__global__ __launch_bounds__(256) void k_conv1x1(const float* __restrict__ in, const float* __restrict__ w,
                                                 const float* __restrict__ bias, float* __restrict__ outp){
  int p0 = blockIdx.x*256 + threadIdx.x*4;
  int o  = blockIdx.y*4 + threadIdx.y;
  int b  = blockIdx.z;
  const float* ip = in + (size_t)b*NC*NN + p0;
  const float* wr = w + o*NC;
  float a0=0,a1=0,a2=0,a3=0;
  #pragma unroll 4
  for (int c=0;c<NC;++c){
    float4 xv = *(const float4*)(ip + (size_t)c*NN);
    float wv = wr[c];
    a0 += xv.x*wv; a1 += xv.y*wv; a2 += xv.z*wv; a3 += xv.w*wv;
  }
  float bv = bias[o];
  float4 rv; rv.x=a0+bv; rv.y=a1+bv; rv.z=a2+bv; rv.w=a3+bv;
  *(float4*)(outp + ((size_t)b*NC+o)*NN + p0) = rv;
}

// ---------------- warp params per selected token ----------------------------
__global__ __launch_bounds__(256) void k_warp_params(const int* __restrict__ idx1, const float* __restrict__ offs,
                                                     float4* __restrict__ wpar, int4* __restrict__ ipar){
  int gid = blockIdx.x*256 + threadIdx.x;  // B*KEEP
  int b = gid >> 11;
  int p = idx1[gid];
  int ph = p >> 6, pwx = p & 63;
  float fx = offs[((size_t)b*2+0)*NN + p];
  float fy = offs[((size_t)b*2+1)*NN + p];
  float sx = (float)pwx + fx, sy = (float)ph + fy;
  float x0f = floorf(sx), y0f = floorf(sy);
  float wx = sx - x0f, wy = sy - y0f;
  int x0 = (int)x0f, y0 = (int)y0f;
  bool vx0 = (x0f >= 0.f) && (x0f <= 63.f);
  bool vx1 = (x0f+1.f >= 0.f) && (x0f+1.f <= 63.f);
  bool vy0 = (y0f >= 0.f) && (y0f <= 63.f);
  bool vy1 = (y0f+1.f >= 0.f) && (y0f+1.f <= 63.f);
  int cx0 = min(max(x0,0),63), cx1 = min(max(x0+1,0),63);
  int cy0 = min(max(y0,0),63), cy1 = min(max(y0+1,0),63);
  float4 w4;
  w4.x = (vx0&&vy0) ? (1.f-wx)*(1.f-wy) : 0.f;
  w4.y = (vx1&&vy0) ? wx*(1.f-wy)       : 0.f;
  w4.z = (vx0&&vy1) ? (1.f-wx)*wy       : 0.f;
  w4.w = (vx1&&vy1) ? wx*wy             : 0.f;
  int4 i4;
  i4.x = cy0*64+cx0; i4.y = cy0*64+cx1; i4.z = cy1*64+cx0; i4.w = cy1*64+cx1;
  wpar[gid]=w4; ipar[gid]=i4;
}

// ---------------- gathers: xq (x at idx1), kg (x+warp at idx1), v1T ---------
__global__ __launch_bounds__(256) void k_gather_q(const float* __restrict__ x, const int* __restrict__ idx1,
                                                  float* __restrict__ xq){
  int gid = blockIdx.x*256 + threadIdx.x;  // B*C*KEEP
  int s = gid & (NKEEP-1);
  int bc = gid >> 11;
  int b = bc/NC;
  xq[gid] = x[(size_t)bc*NN + idx1[b*NKEEP+s]];
}

__global__ __launch_bounds__(256) void k_gather_k(const float* __restrict__ x, const int* __restrict__ idx1,
                                                  const float4* __restrict__ wpar, const int4* __restrict__ ipar,
                                                  float* __restrict__ kg){
  int gid = blockIdx.x*256 + threadIdx.x;
  int s = gid & (NKEEP-1);
  int bc = gid >> 11;
  int b = bc/NC;
  int bs = b*NKEEP + s;
  int p = idx1[bs];
  float4 w4 = wpar[bs]; int4 i4 = ipar[bs];
  const float* xr = x + (size_t)bc*NN;
  kg[gid] = xr[p] + w4.x*xr[i4.x] + w4.y*xr[i4.y] + w4.z*xr[i4.z] + w4.w*xr[i4.w];
}

__global__ __launch_bounds__(256) void k_gather_vT(const float* __restrict__ v, const int* __restrict__ idx1,
                                                   bf16* __restrict__ v1T){
  int gid = blockIdx.x*256 + threadIdx.x;
  int s = gid & (NKEEP-1);
  int bc = gid >> 11;
  int b = bc/NC;
  v1T[gid] = __float2bfloat16(v[(size_t)bc*NN + idx1[b*NKEEP+s]]);
}

// ---------------- GEMM for q1/k1: [b][c][s] fp32 -> [b][s][o] bf16 ----------
__global__ __launch_bounds__(256) void k_gemm_qk(const float* __restrict__ in, const float* __restrict__ w,
                                                 const float* __restrict__ bias, bf16* __restrict__ outp){
  int s0 = blockIdx.x*256 + threadIdx.x*4;
  int o  = blockIdx.y*4 + threadIdx.y;
  int b  = blockIdx.z;
  const float* ip = in + (size_t)b*NC*NKEEP + s0;
  const float* wr = w + o*NC;
  float a0=0,a1=0,a2=0,a3=0;
  #pragma unroll 4
  for (int c=0;c<NC;++c){
    float4 xv = *(const float4*)(ip + (size_t)c*NKEEP);
    float wv = wr[c];
    a0 += xv.x*wv; a1 += xv.y*wv; a2 += xv.z*wv; a3 += xv.w*wv;
  }
  float bv = bias[o];
  bf16* op = outp + ((size_t)b*NKEEP + s0)*NC + o;
  op[0]     = __float2bfloat16(a0+bv);
  op[NC]    = __float2bfloat16(a1+bv);
  op[2*NC]  = __float2bfloat16(a2+bv);
  op[3*NC]  = __float2bfloat16(a3+bv);
}

// ---------------- fill unselected: out_img = v*sa (in place in v) -----------
__global__ __launch_bounds__(256) void k_fill(const float* __restrict__ sa, const int* __restrict__ flag,
                                              float* __restrict__ vout){
  int gid = blockIdx.x*256 + threadIdx.x;  // B*C*N
  int p = gid & (NN-1);
  int bc = gid >> 12;
  int b = bc/NC;
  if (!flag[b*NN+p]) vout[gid] *= sa[b*NN+p];
}

// ---------------- flash attention: LDS-staged K/V, K-split x4 ---------------
// Block = 4 waves x 16 queries over a 512-key split, 32-key tiles.
// K tile [32][384B] staged swizzled (byte ^= (row&7)<<4) via pre-swizzled
// global source + linear global_load_lds dest; V tile [192][64B] linear
// (reads are a contiguous 1024B/wave cover -> conflict-free).
// K single-buffer, V double-buffer; stage(t+1) issued after barrier-1,
// overlapped by PV(t).
__global__ __launch_bounds__(256) void k_attn(const bf16* __restrict__ q1, const bf16* __restrict__ k1,
                                              const bf16* __restrict__ v1T,
                                              bf16* __restrict__ pacc, float* __restrict__ pl)
{
  int b = blockIdx.y, qb = blockIdx.x, sp = blockIdx.z;
  int tid = threadIdx.x;
  int wv = tid >> 6;
  int lane = tid & 63;
  int g = lane >> 4, r = lane & 15;
  int q0 = qb*64 + wv*16;

  const bf16* qbp = q1 + (size_t)b*NKEEP*NC;
  const char* kgb = (const char*)(k1 + (size_t)b*NKEEP*NC);
  const char* vgb = (const char*)(v1T + (size_t)b*NC*NKEEP);

  __shared__ __align__(1024) char kl[12288];        // K tile, swizzled rows
  __shared__ __align__(1024) char vl[2][12288];     // V tile, double-buffered
  __shared__ __align__(16) bf16 plds[4][16][40];    // per-wave P transpose
  bf16 (* __restrict__ pw)[40] = plds[wv];
  char* klc = kl;

  // per-lane staging source offsets (bytes); this wave stages chunks wv*3..wv*3+2
  int ksrc[3], vsrc[3];
  #pragma unroll
  for (int i=0;i<3;++i){
    int j = wv*3 + i;
    int o = j*1024 + lane*16;
    int rr = o/384, cb = o - rr*384;
    ksrc[i] = rr*384 + (cb ^ ((rr&7)<<4));   // + k0*384 at stage time
    int ch = o>>6, kb2 = o&63;
    vsrc[i] = ch*(NKEEP*2) + kb2;            // + k0*2 at stage time
  }

  const int kbase = sp*KPS;
  auto stage = [&](int k0, int vb){
    char* vlc = vl[vb];
    #pragma unroll
    for (int i=0;i<3;++i){
      int j = wv*3 + i;
      __builtin_amdgcn_global_load_lds(
        (const __attribute__((address_space(1))) void*)(kgb + (size_t)k0*384 + ksrc[i]),
        (__attribute__((address_space(3))) void*)(klc + j*1024), 16, 0, 0);
      __builtin_amdgcn_global_load_lds(
        (const __attribute__((address_space(1))) void*)(vgb + (size_t)k0*2 + vsrc[i]),
        (__attribute__((address_space(3))) void*)(vlc + j*1024), 16, 0, 0);
    }
  };

  // Q fragments: lane holds A[row=q0+r][k=32*ks+8*g+i]
  bf16x8 aq[6];
  #pragma unroll
  for (int ks=0;ks<6;++ks)
    aq[ks] = *(const bf16x8*)(qbp + (size_t)(q0+r)*NC + 32*ks + 8*g);

  f32x4 acc[12];
  #pragma unroll
  for (int i=0;i<12;++i){ acc[i][0]=0.f; acc[i][1]=0.f; acc[i][2]=0.f; acc[i][3]=0.f; }
  float l[4]={0.f,0.f,0.f,0.f};

  const float scale = 0.07216878364870323f;        // 192^-0.5
  const float shift = 20.f;                        // uniform; cancels in v/l
  const int swz = (r&7)<<4;

  stage(kbase, 0);
  __syncthreads();

  int vb = 0;
  for (int t16=0;t16<NT;++t16) {
    // ---- QK^T from kl ----
    f32x4 s0v, s1v;
    s0v[0]=s0v[1]=s0v[2]=s0v[3]=0.f;
    s1v[0]=s1v[1]=s1v[2]=s1v[3]=0.f;
    #pragma unroll
    for (int ks=0;ks<6;++ks) {
      int co = (ks*64 + g*16) ^ swz;
      bf16x8 bk0 = *(const bf16x8*)(klc + r*384 + co);
      bf16x8 bk1 = *(const bf16x8*)(klc + (16+r)*384 + co);
      s0v = __builtin_amdgcn_mfma_f32_16x16x32_bf16(aq[ks], bk0, s0v, 0,0,0);
      s1v = __builtin_amdgcn_mfma_f32_16x16x32_bf16(aq[ks], bk1, s1v, 0,0,0);
    }
    // ---- exp (no-max; uniform shift cancels) + P to per-wave LDS ----
    #pragma unroll
    for (int i=0;i<4;++i) {
      float e0 = __expf(s0v[i]*scale - shift);
      float e1 = __expf(s1v[i]*scale - shift);
      l[i] += e0 + e1;
      pw[4*g+i][r]    = __float2bfloat16(e0);
      pw[4*g+i][16+r] = __float2bfloat16(e1);
    }
    bf16x8 pa = *(const bf16x8*)(&pw[r][8*g]);

    __syncthreads();                       // all waves done reading kl
    if (t16+1 < NT) stage(kbase + (t16+1)*32, vb^1);   // issue next K/V

    // ---- PV from vl[vb] (overlaps staging latency) ----
    const char* vlc = vl[vb];
    #pragma unroll
    for (int ct=0;ct<12;++ct) {
      bf16x8 bvv = *(const bf16x8*)(vlc + (16*ct + r)*64 + g*16);
      acc[ct] = __builtin_amdgcn_mfma_f32_16x16x32_bf16(pa, bvv, acc[ct], 0,0,0);
    }
    __syncthreads();                       // drain staging; vl[vb] free
    vb ^= 1;
  }

  // reduce l over the 16 lanes sharing each query row (same g)
  #pragma unroll
  for (int i=0;i<4;++i){
    #pragma unroll
    for (int o=1;o<16;o<<=1) l[i] += __shfl_xor(l[i],o);
  }
  size_t pbase = (((size_t)(b*32+qb)*NSPLIT + sp)*64);
  if (r==0){
    #pragma unroll
    for (int i=0;i<4;++i) pl[pbase + wv*16 + 4*g + i] = l[i];
  }
  #pragma unroll
  for (int ct=0;ct<12;++ct)
    #pragma unroll
    for (int i=0;i<4;++i)
      pacc[(pbase + wv*16 + 4*g + i)*NC + 16*ct + r] = __float2bfloat16(acc[ct][i]);
}

// ---------------- merge the NSPLIT attention partials + scatter -------------
__global__ __launch_bounds__(256) void k_merge(const bf16* __restrict__ pacc,
                                               const float* __restrict__ pl, const int* __restrict__ idx1,
                                               float* __restrict__ out_img)
{
  int gid = blockIdx.x*256 + threadIdx.x;   // B*KEEP*NC, c fastest
  int c = gid % NC;
  int bs = gid / NC;
  int s = bs & (NKEEP-1);
  int b = bs >> 11;
  int qb = s >> 6, ql = s & 63;
  size_t base = ((size_t)(b*32+qb)*NSPLIT)*64 + ql;
  float l = pl[base] + pl[base+64] + pl[base+128] + pl[base+192];
  size_t pb = base*NC + c;
  float v = __bfloat162float(pacc[pb])
          + __bfloat162float(pacc[pb + (size_t)64*NC])
          + __bfloat162float(pacc[pb + (size_t)128*NC])
          + __bfloat162float(pacc[pb + (size_t)192*NC]);
  out_img[((size_t)b*NC + c)*NN + idx1[b*NKEEP + s]] = v / l;
}

// ---------------- depthwise 3x3 + gelu*ca + residual ------------------------
__global__ __launch_bounds__(256) void k_dwgelu(const float* __restrict__ vin, const float* __restrict__ ca,
                                                const float* __restrict__ cw, const float* __restrict__ cb,
                                                float* __restrict__ out2){
  int gid = blockIdx.x*256 + threadIdx.x;
  int p = gid & (NN-1);
  int bc = gid >> 12;
  int c = bc % NC, b = bc / NC;
  int hh = p>>6, ww = p&63;
  const float* ip = vin + (size_t)bc*NN;
  float a = cb[c];
  #pragma unroll
  for (int dy=0;dy<3;++dy){ int yy=hh+dy-1; if(yy<0||yy>63) continue;
    #pragma unroll
    for (int dx=0;dx<3;++dx){ int xx=ww+dx-1; if(xx<0||xx>63) continue;
      a += ip[yy*64+xx]*cw[c*9+dy*3+dx]; } }
  float gl = 0.5f*a*(1.f+tanhf(0.79788456080286536f*(a+0.044715f*a*a*a)));
  out2[gid] = gl*ca[b*NC+c] + ip[p];
}

// ============================================================================
extern "C" void kernel_launch(void* const* d_in, const int* in_sizes, int n_in,
                              void* d_out, int out_size, void* d_ws, size_t ws_size,
                              hipStream_t stream)
{
  const float* x       = (const float*)d_in[0];
  const float* p_in_w  = (const float*)d_in[1];
  const float* p_in_b  = (const float*)d_in[2];
  const float* p_ln_w  = (const float*)d_in[3];
  const float* p_ln_b  = (const float*)d_in[4];
  const float* p_off_w1= (const float*)d_in[5];
  const float* p_off_b1= (const float*)d_in[6];
  const float* p_off_w2= (const float*)d_in[7];
  const float* p_off_b2= (const float*)d_in[8];
  const float* p_ca_w  = (const float*)d_in[9];
  const float* p_ca_b  = (const float*)d_in[10];
  const float* p_sa_w  = (const float*)d_in[11];
  const float* p_sa_b  = (const float*)d_in[12];
  const float* p_mask_w1=(const float*)d_in[13];
  const float* p_mask_b1=(const float*)d_in[14];
  const float* p_mask_w2=(const float*)d_in[15];
  const float* p_mask_b2=(const float*)d_in[16];
  const float* v_w     = (const float*)d_in[17];
  const float* v_b     = (const float*)d_in[18];
  const float* q_w     = (const float*)d_in[19];
  const float* q_b     = (const float*)d_in[20];
  const float* k_w     = (const float*)d_in[21];
  const float* k_b     = (const float*)d_in[22];
  const float* cs_w    = (const float*)d_in[23];
  const float* cs_b    = (const float*)d_in[24];
  const float* out_w   = (const float*)d_in[25];
  const float* out_b   = (const float*)d_in[26];
  float* out = (float*)d_out;
  (void)in_sizes; (void)n_in; (void)out_size;

  char* wsp = (char*)d_ws;
  size_t off = 0;
  auto alloc = [&](size_t bytes)->char*{ char* p = wsp + off; off += (bytes + 255) & ~(size_t)255; return p; };
  float* f     = (float*)alloc((size_t)NB*NC4*NN*4);
  float* score = (float*)alloc((size_t)NB*NN*4);
  int*   idx1  = (int*)  alloc((size_t)NB*NKEEP*4);
  int*   flag  = (int*)  alloc((size_t)NB*NN*4);
  float* offs  = (float*)alloc((size_t)NB*2*NN*4);
  float* sa    = (float*)alloc((size_t)NB*NN*4);
  float* fmean = (float*)alloc((size_t)NB*NC4*4);
  float* ca    = (float*)alloc((size_t)NB*NC*4);
  float* vbuf  = (float*)alloc((size_t)NB*NC*NN*4);     // v, later out_img (in place)
  bf16*  q1bf  = (bf16*) alloc((size_t)NB*NKEEP*NC*2);
  bf16*  k1bf  = (bf16*) alloc((size_t)NB*NKEEP*NC*2);
  bf16*  v1T   = (bf16*) alloc((size_t)NB*NC*NKEEP*2);
  float4* wpar = (float4*)alloc((size_t)NB*NKEEP*16);
  int4*   ipar = (int4*) alloc((size_t)NB*NKEEP*16);
  float* out2  = (float*)alloc((size_t)NB*NC*NN*4);
  float* pl    = (float*)alloc((size_t)NB*32*NSPLIT*64*4);
  if (off > ws_size) return;
  // aliases inside out2 (all dead before dwgelu writes out2):
  float* xq = out2;
  float* kg = out2 + (size_t)NB*NC*NKEEP;
  bf16*  pacc = (bf16*)out2;   // B*KEEP*NSPLIT*NC bf16 = 25.2 MB

  dim3 blk64x4(64,4);

  k_f_score<<<NB*NN/128, 128, 0, stream>>>(x, p_in_w, p_in_b, p_ln_w, p_ln_b,
      p_mask_w1, p_mask_b1, p_mask_w2, p_mask_b2, f, score);
  k_topk<<<NB, 1024, 0, stream>>>(score, idx1, flag);
  k_offsets<<<NB*NN/256, 256, 0, stream>>>(f, p_off_w1, p_off_b1, p_off_w2, p_off_b2, offs);
  k_fmean<<<NB*NC4, 256, 0, stream>>>(f, fmean);
  k_ca<<<NB, NC, 0, stream>>>(fmean, p_ca_w, p_ca_b, ca);
  k_sa<<<NB*NN/256, 256, 0, stream>>>(f, p_sa_w, p_sa_b, sa);
  k_conv1x1<<<dim3(NN/256, NC/4, NB), blk64x4, 0, stream>>>(x, v_w, v_b, vbuf);
  k_warp_params<<<NB*NKEEP/256, 256, 0, stream>>>(idx1, offs, wpar, ipar);
  k_gather_q<<<NB*NC*NKEEP/256, 256, 0, stream>>>(x, idx1, xq);
  k_gather_k<<<NB*NC*NKEEP/256, 256, 0, stream>>>(x, idx1, wpar, ipar, kg);
  k_gemm_qk<<<dim3(NKEEP/256, NC/4, NB), blk64x4, 0, stream>>>(xq, q_w, q_b, q1bf);
  k_gemm_qk<<<dim3(NKEEP/256, NC/4, NB), blk64x4, 0, stream>>>(kg, k_w, k_b, k1bf);
  k_gather_vT<<<NB*NC*NKEEP/256, 256, 0, stream>>>(vbuf, idx1, v1T);
  k_fill<<<NB*NC*NN/256, 256, 0, stream>>>(sa, flag, vbuf);
  k_attn<<<dim3(NKEEP/64, NB, NSPLIT), 256, 0, stream>>>(q1bf, k1bf, v1T, pacc, pl);
  k_merge<<<NB*NKEEP*NC/256, 256, 0, stream>>>(pacc, pl, idx1, vbuf);
  k_dwgelu<<<NB*NC*NN/256, 256, 0, stream>>>(vbuf, ca, cs_w, cs_b, out2);
  k_conv1x1<<<dim3(NN/256, NC/4, NB), blk64x4, 0, stream>>>(out2, out_w, out_b, out);
}

// Round 6
// 552.524 us; speedup vs baseline: 2.5332x; 1.8887x over previous
//
#include <hip/hip_runtime.h>
#include <hip/hip_bf16.h>

#define NB   8
#define NC   192
#define NH   64
#define NW   64
#define NN   4096        // H*W
#define NCD  194         // C+2
#define NC4  48          // (C+2)/4
#define NKEEP 2048       // N*RATIO
#define NSPLIT 4         // attention K-splits
#define KPS   (NKEEP/NSPLIT)   // 512 keys per split
#define NT    (KPS/32)         // 16 key-tiles per split

typedef __attribute__((ext_vector_type(8))) short bf16x8;  // 8 bf16 (4 VGPRs)
typedef __attribute__((ext_vector_type(4))) float f32x4;
typedef __hip_bfloat16 bf16;

__device__ __forceinline__ float dsigmoid(float x){ return 1.f/(1.f+__expf(-x)); }
__device__ __forceinline__ float dlrelu(float x){ return x>0.f ? x : 0.1f*x; }
__device__ __forceinline__ float b2f(short s){ return __uint_as_float(((unsigned)(unsigned short)s)<<16); }

// ---------------- K0: f = lrelu(LN(conv1x1(cond))), plus score ----------------
__global__ __launch_bounds__(128) void k_f_score(
    const float* __restrict__ x, const float* __restrict__ w_in, const float* __restrict__ b_in,
    const float* __restrict__ ln_w, const float* __restrict__ ln_b,
    const float* __restrict__ mw1, const float* __restrict__ mb1,
    const float* __restrict__ mw2, const float* __restrict__ mb2,
    float* __restrict__ f, float* __restrict__ score)
{
  __shared__ float wT[NCD][NC4];   // transposed weights; reads are broadcast
  int t = threadIdx.x;
  for (int i=t; i<NCD*NC4; i+=128){ int o = i/NCD, c = i - o*NCD; wT[c][o] = w_in[i]; }
  __syncthreads();

  int gid = blockIdx.x*128 + t;
  int p = gid & (NN-1), b = gid >> 12;
  int hh = p>>6, ww = p&63;

  f32x4 a4[12];
  #pragma unroll
  for (int j=0;j<12;++j) a4[j] = *(const f32x4*)(b_in + 4*j);

  const float* xb = x + (size_t)b*NC*NN + p;
  for (int c=0;c<NC;++c){
    float xv = xb[(size_t)c*NN];
    #pragma unroll
    for (int j=0;j<12;++j){ f32x4 wv = *(const f32x4*)&wT[c][4*j]; a4[j] += wv*xv; }
  }
  { float gx = -1.f + (2.f/63.f)*(float)ww;
    #pragma unroll
    for (int j=0;j<12;++j){ f32x4 wv = *(const f32x4*)&wT[192][4*j]; a4[j] += wv*gx; }
    float gy = -1.f + (2.f/63.f)*(float)hh;
    #pragma unroll
    for (int j=0;j<12;++j){ f32x4 wv = *(const f32x4*)&wT[193][4*j]; a4[j] += wv*gy; }
  }
  float s1=0.f, s2=0.f;
  #pragma unroll
  for (int j=0;j<12;++j){
    #pragma unroll
    for (int k=0;k<4;++k){ float v=a4[j][k]; s1+=v; s2+=v*v; }
  }
  float mean = s1*(1.f/NC4);
  float var  = s2*(1.f/NC4) - mean*mean;
  float rstd = rsqrtf(var + 1e-6f);
  float tsum = 0.f;
  #pragma unroll
  for (int j=0;j<12;++j){
    f32x4 lw = *(const f32x4*)(ln_w + 4*j);
    f32x4 lb = *(const f32x4*)(ln_b + 4*j);
    #pragma unroll
    for (int k=0;k<4;++k){
      float z = lw[k]*((a4[j][k]-mean)*rstd) + lb[k];
      float fv = z>0.f ? z : 0.1f*z;
      tsum += fv;
      f[((size_t)b*NC4 + 4*j+k)*NN + p] = fv;
    }
  }
  float tm = tsum*(1.f/NC4);
  float sv = dlrelu(tm*mw1[0] + mb1[0]);
  float d  = sv*(mw2[0]-mw2[1]) + (mb2[0]-mb2[1]);
  score[b*NN + p] = dsigmoid(d);
}

// ---------------- K1: per-batch top-2048 via bitonic sort -----------------
__global__ __launch_bounds__(1024) void k_topk(const float* __restrict__ score,
                                               int* __restrict__ idx1, int* __restrict__ flag)
{
  int b = blockIdx.x;
  __shared__ unsigned long long key[NN];
  int t = threadIdx.x;
  for (int i=t;i<NN;i+=1024){
    unsigned u = __float_as_uint(score[b*NN+i]);
    unsigned a = (u & 0x80000000u) ? ~u : (u | 0x80000000u);
    unsigned d = ~a;
    key[i] = ((unsigned long long)d << 32) | (unsigned)i;
  }
  __syncthreads();
  for (int k=2;k<=NN;k<<=1){
    for (int j=k>>1;j>0;j>>=1){
      for (int i=t;i<NN;i+=1024){
        int ixj = i ^ j;
        if (ixj > i){
          unsigned long long a = key[i], c = key[ixj];
          bool up = ((i & k) == 0);
          if (up ? (a > c) : (a < c)){ key[i]=c; key[ixj]=a; }
        }
      }
      __syncthreads();
    }
  }
  for (int i=t;i<NN;i+=1024){
    int id = (int)(unsigned)(key[i] & 0xFFFFFFFFull);
    if (i < NKEEP) idx1[b*NKEEP+i] = id;
    flag[b*NN+id] = (i < NKEEP) ? 1 : 0;
  }
}

// ---------------- K2: offsets = tanh(conv1x1(lrelu(conv1x1(f))))*8 ----------
__global__ __launch_bounds__(256) void k_offsets(
    const float* __restrict__ f, const float* __restrict__ w1, const float* __restrict__ b1,
    const float* __restrict__ w2, const float* __restrict__ b2, float* __restrict__ offs)
{
  int gid = blockIdx.x*256 + threadIdx.x;
  int p = gid & (NN-1);
  int b = gid >> 12;
  const float* fb = f + (size_t)b*NC4*NN + p;
  float fl[NC4];
  #pragma unroll 8
  for (int c=0;c<NC4;++c) fl[c] = fb[(size_t)c*NN];
  float h1[24];
  for (int o=0;o<24;++o){
    const float* wr = w1 + o*NC4;
    float a = b1[o];
    #pragma unroll 8
    for (int c=0;c<NC4;++c) a += wr[c]*fl[c];
    h1[o] = dlrelu(a);
  }
  #pragma unroll
  for (int o=0;o<2;++o){
    const float* wr = w2 + o*24;
    float a = b2[o];
    #pragma unroll
    for (int c=0;c<24;++c) a += wr[c]*h1[c];
    offs[((size_t)b*2+o)*NN + p] = tanhf(a)*8.f;
  }
}

// ---------------- K3: f spatial mean, then ca = sigmoid(fc) -----------------
__global__ __launch_bounds__(256) void k_fmean(const float* __restrict__ f, float* __restrict__ fmean){
  int bc = blockIdx.x;
  const float* p = f + (size_t)bc*NN;
  float s = 0.f;
  for (int i=threadIdx.x;i<NN;i+=256) s += p[i];
  for (int o=32;o;o>>=1) s += __shfl_xor(s,o);
  __shared__ float r[4];
  if ((threadIdx.x&63)==0) r[threadIdx.x>>6] = s;
  __syncthreads();
  if (threadIdx.x==0) fmean[bc] = (r[0]+r[1]+r[2]+r[3])*(1.f/NN);
}

__global__ void k_ca(const float* __restrict__ fmean, const float* __restrict__ w,
                     const float* __restrict__ bias, float* __restrict__ ca){
  int b = blockIdx.x, o = threadIdx.x;
  const float* fm = fmean + b*NC4;
  float a = bias[o];
  #pragma unroll 8
  for (int c=0;c<NC4;++c) a += w[o*NC4+c]*fm[c];
  ca[b*NC+o] = dsigmoid(a);
}

// ---------------- K4: sa = sigmoid(conv3x3(f, 48->1)) -----------------------
__global__ __launch_bounds__(256) void k_sa(const float* __restrict__ f, const float* __restrict__ w,
                                            const float* __restrict__ bias, float* __restrict__ sa){
  int gid = blockIdx.x*256 + threadIdx.x;
  int p = gid & (NN-1);
  int b = gid >> 12;
  int hh=p>>6, ww=p&63;
  float acc = bias[0];
  for (int c=0;c<NC4;++c){
    const float* fp = f + ((size_t)b*NC4+c)*NN;
    const float* wc = w + c*9;
    #pragma unroll
    for (int dy=0;dy<3;++dy){ int yy=hh+dy-1; if(yy<0||yy>63) continue;
      #pragma unroll
      for (int dx=0;dx<3;++dx){ int xx=ww+dx-1; if(xx<0||xx>63) continue;
        acc += fp[yy*64+xx]*wc[dy*3+dx]; } }
  }
  sa[gid] = dsigmoid(acc);
}

// ---------------- weights fp32 -> bf16 (4 matrices of 192x192) --------------
__global__ __launch_bounds__(256) void k_w2bf(const float* __restrict__ a, const float* __restrict__ b,
                                              const float* __restrict__ c, const float* __restrict__ d,
                                              bf16* __restrict__ oa, bf16* __restrict__ ob,
                                              bf16* __restrict__ oc, bf16* __restrict__ od){
  int i = blockIdx.x*256 + threadIdx.x;
  if (i < NC*NC){
    oa[i] = __float2bfloat16(a[i]);
    ob[i] = __float2bfloat16(b[i]);
    oc[i] = __float2bfloat16(c[i]);
    od[i] = __float2bfloat16(d[i]);
  }
}

// ---------------- transpose [b][c][p] fp32 -> [b][p][c] bf16 ----------------
__global__ __launch_bounds__(256) void k_transpose(const float* __restrict__ in, bf16* __restrict__ outT){
  int b = blockIdx.z;
  int c0 = blockIdx.y*32, p0 = blockIdx.x*32;
  __shared__ float tile[32][33];
  int col = threadIdx.x & 31, row8 = threadIdx.x >> 5;
  #pragma unroll
  for (int ph=0;ph<4;++ph){
    int c = c0 + ph*8 + row8;
    tile[ph*8+row8][col] = in[((size_t)b*NC + c)*NN + p0 + col];
  }
  __syncthreads();
  #pragma unroll
  for (int ph=0;ph<4;++ph){
    int p = p0 + ph*8 + row8;
    outT[((size_t)b*NN + p)*NC + c0 + col] = __float2bfloat16(tile[col][ph*8+row8]);
  }
}

// ---------------- conv1x1 via MFMA: out[b][o][p] = inT[b][p][:]·w[o][:] -----
// block 4 waves; wave wv owns o in [48wv, 48wv+48); 64-px chunk (4 tiles)
__global__ __launch_bounds__(256) void k_conv_mfma(const bf16* __restrict__ inT, const bf16* __restrict__ wb,
                                                   const float* __restrict__ bias, float* __restrict__ outp){
  int b = blockIdx.y;
  int px0 = blockIdx.x*64;
  int wv = threadIdx.x>>6, lane = threadIdx.x&63, g = lane>>4, r = lane&15;
  int o0 = wv*48;
  bf16x8 bw[3][6];
  #pragma unroll
  for (int jo=0;jo<3;++jo)
    #pragma unroll
    for (int ks=0;ks<6;++ks)
      bw[jo][ks] = *(const bf16x8*)(wb + (size_t)(o0+jo*16+r)*NC + ks*32 + 8*g);
  float bv[3];
  #pragma unroll
  for (int jo=0;jo<3;++jo) bv[jo] = bias[o0+jo*16+r];

  const bf16* ib = inT + (size_t)b*NN*NC;
  #pragma unroll
  for (int t=0;t<4;++t){
    int px = px0 + t*16;
    bf16x8 a[6];
    #pragma unroll
    for (int ks=0;ks<6;++ks) a[ks] = *(const bf16x8*)(ib + (size_t)(px+r)*NC + ks*32 + 8*g);
    f32x4 acc[3];
    #pragma unroll
    for (int jo=0;jo<3;++jo){ acc[jo][0]=0.f; acc[jo][1]=0.f; acc[jo][2]=0.f; acc[jo][3]=0.f; }
    #pragma unroll
    for (int ks=0;ks<6;++ks)
      #pragma unroll
      for (int jo=0;jo<3;++jo)
        acc[jo] = __builtin_amdgcn_mfma_f32_16x16x32_bf16(a[ks], bw[jo][ks], acc[jo], 0,0,0);
    #pragma unroll
    for (int jo=0;jo<3;++jo){
      float4 rv; rv.x=acc[jo][0]+bv[jo]; rv.y=acc[jo][1]+bv[jo]; rv.z=acc[jo][2]+bv[jo]; rv.w=acc[jo][3]+bv[jo];
      *(float4*)(outp + ((size_t)b*NC + o0+jo*16+r)*NN + px + 4*g) = rv;
    }
  }
}

// ---------------- token GEMM via MFMA: out[b][s][o] bf16 --------------------
// block 4 waves; wave owns 48 o; 32-token chunk (2 tiles)
__global__ __launch_bounds__(256) void k_gemm_mfma(const bf16* __restrict__ in, const bf16* __restrict__ wb,
                                                   const float* __restrict__ bias, bf16* __restrict__ outp){
  int b = blockIdx.y;
  int s0 = blockIdx.x*32;
  int wv = threadIdx.x>>6, lane = threadIdx.x&63, g = lane>>4, r = lane&15;
  int o0 = wv*48;
  bf16x8 bw[3][6];
  #pragma unroll
  for (int jo=0;jo<3;++jo)
    #pragma unroll
    for (int ks=0;ks<6;++ks)
      bw[jo][ks] = *(const bf16x8*)(wb + (size_t)(o0+jo*16+r)*NC + ks*32 + 8*g);
  float bv[3];
  #pragma unroll
  for (int jo=0;jo<3;++jo) bv[jo] = bias[o0+jo*16+r];

  const bf16* ib = in + (size_t)b*NKEEP*NC;
  bf16* ob = outp + (size_t)b*NKEEP*NC;
  #pragma unroll
  for (int t=0;t<2;++t){
    int s = s0 + t*16;
    bf16x8 a[6];
    #pragma unroll
    for (int ks=0;ks<6;++ks) a[ks] = *(const bf16x8*)(ib + (size_t)(s+r)*NC + ks*32 + 8*g);
    f32x4 acc[3];
    #pragma unroll
    for (int jo=0;jo<3;++jo){ acc[jo][0]=0.f; acc[jo][1]=0.f; acc[jo][2]=0.f; acc[jo][3]=0.f; }
    #pragma unroll
    for (int ks=0;ks<6;++ks)
      #pragma unroll
      for (int jo=0;jo<3;++jo)
        acc[jo] = __builtin_amdgcn_mfma_f32_16x16x32_bf16(a[ks], bw[jo][ks], acc[jo], 0,0,0);
    #pragma unroll
    for (int jo=0;jo<3;++jo)
      #pragma unroll
      for (int i=0;i<4;++i)
        ob[(size_t)(s+4*g+i)*NC + o0+jo*16+r] = __float2bfloat16(acc[jo][i]+bv[jo]);
  }
}

// ---------------- warp params per selected token ----------------------------
__global__ __launch_bounds__(256) void k_warp_params(const int* __restrict__ idx1, const float* __restrict__ offs,
                                                     float4* __restrict__ wpar, int4* __restrict__ ipar){
  int gid = blockIdx.x*256 + threadIdx.x;  // B*KEEP
  int b = gid >> 11;
  int p = idx1[gid];
  int ph = p >> 6, pwx = p & 63;
  float fx = offs[((size_t)b*2+0)*NN + p];
  float fy = offs[((size_t)b*2+1)*NN + p];
  float sx = (float)pwx + fx, sy = (float)ph + fy;
  float x0f = floorf(sx), y0f = floorf(sy);
  float wx = sx - x0f, wy = sy - y0f;
  int x0 = (int)x0f, y0 = (int)y0f;
  bool vx0 = (x0f >= 0.f) && (x0f <= 63.f);
  bool vx1 = (x0f+1.f >= 0.f) && (x0f+1.f <= 63.f);
  bool vy0 = (y0f >= 0.f) && (y0f <= 63.f);
  bool vy1 = (y0f+1.f >= 0.f) && (y0f+1.f <= 63.f);
  int cx0 = min(max(x0,0),63), cx1 = min(max(x0+1,0),63);
  int cy0 = min(max(y0,0),63), cy1 = min(max(y0+1,0),63);
  float4 w4;
  w4.x = (vx0&&vy0) ? (1.f-wx)*(1.f-wy) : 0.f;
  w4.y = (vx1&&vy0) ? wx*(1.f-wy)       : 0.f;
  w4.z = (vx0&&vy1) ? (1.f-wx)*wy       : 0.f;
  w4.w = (vx1&&vy1) ? wx*wy             : 0.f;
  int4 i4;
  i4.x = cy0*64+cx0; i4.y = cy0*64+cx1; i4.z = cy1*64+cx0; i4.w = cy1*64+cx1;
  wpar[gid]=w4; ipar[gid]=i4;
}

// ---------------- gathers from xT (token rows, vectorized) ------------------
__global__ __launch_bounds__(256) void k_gather_qT(const bf16* __restrict__ xT, const int* __restrict__ idx1,
                                                   bf16* __restrict__ qin){
  int gid = blockIdx.x*256 + threadIdx.x;   // B*KEEP*24
  int j = gid % 24;
  int bs = gid / 24;
  int b = bs >> 11;
  int p = idx1[bs];
  *(bf16x8*)(qin + (size_t)bs*NC + j*8) = *(const bf16x8*)(xT + ((size_t)b*NN + p)*NC + j*8);
}

__global__ __launch_bounds__(256) void k_gather_kT(const bf16* __restrict__ xT, const int* __restrict__ idx1,
                                                   const float4* __restrict__ wpar, const int4* __restrict__ ipar,
                                                   bf16* __restrict__ kin){
  int gid = blockIdx.x*256 + threadIdx.x;   // B*KEEP*24
  int j = gid % 24;
  int bs = gid / 24;
  int b = bs >> 11;
  int p = idx1[bs];
  float4 w4 = wpar[bs]; int4 i4 = ipar[bs];
  const bf16* xb = xT + (size_t)b*NN*NC + j*8;
  bf16x8 v0 = *(const bf16x8*)(xb + (size_t)p*NC);
  bf16x8 v1 = *(const bf16x8*)(xb + (size_t)i4.x*NC);
  bf16x8 v2 = *(const bf16x8*)(xb + (size_t)i4.y*NC);
  bf16x8 v3 = *(const bf16x8*)(xb + (size_t)i4.z*NC);
  bf16x8 v4 = *(const bf16x8*)(xb + (size_t)i4.w*NC);
  bf16x8 o;
  #pragma unroll
  for (int k=0;k<8;++k){
    float vv = b2f(v0[k]) + w4.x*b2f(v1[k]) + w4.y*b2f(v2[k]) + w4.z*b2f(v3[k]) + w4.w*b2f(v4[k]);
    bf16 h = __float2bfloat16(vv);
    o[k] = *(short*)&h;
  }
  *(bf16x8*)(kin + (size_t)bs*NC + j*8) = o;
}

__global__ __launch_bounds__(256) void k_gather_vT(const float* __restrict__ v, const int* __restrict__ idx1,
                                                   bf16* __restrict__ v1T){
  int gid = blockIdx.x*256 + threadIdx.x;
  int s = gid & (NKEEP-1);
  int bc = gid >> 11;
  int b = bc/NC;
  v1T[gid] = __float2bfloat16(v[(size_t)bc*NN + idx1[b*NKEEP+s]]);
}

// ---------------- fill unselected: out_img = v*sa (in place in v) -----------
__global__ __launch_bounds__(256) void k_fill(const float* __restrict__ sa, const int* __restrict__ flag,
                                              float* __restrict__ vout){
  int gid = blockIdx.x*256 + threadIdx.x;  // B*C*N
  int p = gid & (NN-1);
  int bc = gid >> 12;
  int b = bc/NC;
  if (!flag[b*NN+p]) vout[gid] *= sa[b*NN+p];
}

// ---------------- flash attention: LDS-staged K/V, K-split x4 ---------------
__global__ __launch_bounds__(256) void k_attn(const bf16* __restrict__ q1, const bf16* __restrict__ k1,
                                              const bf16* __restrict__ v1T,
                                              bf16* __restrict__ pacc, float* __restrict__ pl)
{
  int b = blockIdx.y, qb = blockIdx.x, sp = blockIdx.z;
  int tid = threadIdx.x;
  int wv = tid >> 6;
  int lane = tid & 63;
  int g = lane >> 4, r = lane & 15;
  int q0 = qb*64 + wv*16;

  const bf16* qbp = q1 + (size_t)b*NKEEP*NC;
  const char* kgb = (const char*)(k1 + (size_t)b*NKEEP*NC);
  const char* vgb = (const char*)(v1T + (size_t)b*NC*NKEEP);

  __shared__ __align__(1024) char kl[12288];        // K tile, swizzled rows
  __shared__ __align__(1024) char vl[2][12288];     // V tile, double-buffered
  __shared__ __align__(16) bf16 plds[4][16][40];    // per-wave P transpose
  bf16 (* __restrict__ pw)[40] = plds[wv];
  char* klc = kl;

  int ksrc[3], vsrc[3];
  #pragma unroll
  for (int i=0;i<3;++i){
    int j = wv*3 + i;
    int o = j*1024 + lane*16;
    int rr = o/384, cb = o - rr*384;
    ksrc[i] = rr*384 + (cb ^ ((rr&7)<<4));
    int ch = o>>6, kb2 = o&63;
    vsrc[i] = ch*(NKEEP*2) + kb2;
  }

  const int kbase = sp*KPS;
  auto stage = [&](int k0, int vb){
    char* vlc = vl[vb];
    #pragma unroll
    for (int i=0;i<3;++i){
      int j = wv*3 + i;
      __builtin_amdgcn_global_load_lds(
        (const __attribute__((address_space(1))) void*)(kgb + (size_t)k0*384 + ksrc[i]),
        (__attribute__((address_space(3))) void*)(klc + j*1024), 16, 0, 0);
      __builtin_amdgcn_global_load_lds(
        (const __attribute__((address_space(1))) void*)(vgb + (size_t)k0*2 + vsrc[i]),
        (__attribute__((address_space(3))) void*)(vlc + j*1024), 16, 0, 0);
    }
  };

  bf16x8 aq[6];
  #pragma unroll
  for (int ks=0;ks<6;++ks)
    aq[ks] = *(const bf16x8*)(qbp + (size_t)(q0+r)*NC + 32*ks + 8*g);

  f32x4 acc[12];
  #pragma unroll
  for (int i=0;i<12;++i){ acc[i][0]=0.f; acc[i][1]=0.f; acc[i][2]=0.f; acc[i][3]=0.f; }
  float l[4]={0.f,0.f,0.f,0.f};

  const float scale = 0.07216878364870323f;        // 192^-0.5
  const float shift = 20.f;                        // uniform; cancels in v/l
  const int swz = (r&7)<<4;

  stage(kbase, 0);
  __syncthreads();

  int vb = 0;
  for (int t16=0;t16<NT;++t16) {
    f32x4 s0v, s1v;
    s0v[0]=s0v[1]=s0v[2]=s0v[3]=0.f;
    s1v[0]=s1v[1]=s1v[2]=s1v[3]=0.f;
    #pragma unroll
    for (int ks=0;ks<6;++ks) {
      int co = (ks*64 + g*16) ^ swz;
      bf16x8 bk0 = *(const bf16x8*)(klc + r*384 + co);
      bf16x8 bk1 = *(const bf16x8*)(klc + (16+r)*384 + co);
      s0v = __builtin_amdgcn_mfma_f32_16x16x32_bf16(aq[ks], bk0, s0v, 0,0,0);
      s1v = __builtin_amdgcn_mfma_f32_16x16x32_bf16(aq[ks], bk1, s1v, 0,0,0);
    }
    #pragma unroll
    for (int i=0;i<4;++i) {
      float e0 = __expf(s0v[i]*scale - shift);
      float e1 = __expf(s1v[i]*scale - shift);
      l[i] += e0 + e1;
      pw[4*g+i][r]    = __float2bfloat16(e0);
      pw[4*g+i][16+r] = __float2bfloat16(e1);
    }
    bf16x8 pa = *(const bf16x8*)(&pw[r][8*g]);

    __syncthreads();
    if (t16+1 < NT) stage(kbase + (t16+1)*32, vb^1);

    const char* vlc = vl[vb];
    #pragma unroll
    for (int ct=0;ct<12;++ct) {
      bf16x8 bvv = *(const bf16x8*)(vlc + (16*ct + r)*64 + g*16);
      acc[ct] = __builtin_amdgcn_mfma_f32_16x16x32_bf16(pa, bvv, acc[ct], 0,0,0);
    }
    __syncthreads();
    vb ^= 1;
  }

  #pragma unroll
  for (int i=0;i<4;++i){
    #pragma unroll
    for (int o=1;o<16;o<<=1) l[i] += __shfl_xor(l[i],o);
  }
  size_t pbase = (((size_t)(b*32+qb)*NSPLIT + sp)*64);
  if (r==0){
    #pragma unroll
    for (int i=0;i<4;++i) pl[pbase + wv*16 + 4*g + i] = l[i];
  }
  #pragma unroll
  for (int ct=0;ct<12;++ct)
    #pragma unroll
    for (int i=0;i<4;++i)
      pacc[(pbase + wv*16 + 4*g + i)*NC + 16*ct + r] = __float2bfloat16(acc[ct][i]);
}

// ---------------- merge the NSPLIT attention partials + scatter -------------
__global__ __launch_bounds__(256) void k_merge(const bf16* __restrict__ pacc,
                                               const float* __restrict__ pl, const int* __restrict__ idx1,
                                               float* __restrict__ out_img)
{
  int gid = blockIdx.x*256 + threadIdx.x;   // B*KEEP*NC, c fastest
  int c = gid % NC;
  int bs = gid / NC;
  int s = bs & (NKEEP-1);
  int b = bs >> 11;
  int qb = s >> 6, ql = s & 63;
  size_t base = ((size_t)(b*32+qb)*NSPLIT)*64 + ql;
  float l = pl[base] + pl[base+64] + pl[base+128] + pl[base+192];
  size_t pb = base*NC + c;
  float v = __bfloat162float(pacc[pb])
          + __bfloat162float(pacc[pb + (size_t)64*NC])
          + __bfloat162float(pacc[pb + (size_t)128*NC])
          + __bfloat162float(pacc[pb + (size_t)192*NC]);
  out_img[((size_t)b*NC + c)*NN + idx1[b*NKEEP + s]] = v / l;
}

// ---------------- depthwise 3x3 + gelu*ca + residual ------------------------
__global__ __launch_bounds__(256) void k_dwgelu(const float* __restrict__ vin, const float* __restrict__ ca,
                                                const float* __restrict__ cw, const float* __restrict__ cb,
                                                float* __restrict__ out2){
  int gid = blockIdx.x*256 + threadIdx.x;
  int p = gid & (NN-1);
  int bc = gid >> 12;
  int c = bc % NC, b = bc / NC;
  int hh = p>>6, ww = p&63;
  const float* ip = vin + (size_t)bc*NN;
  float a = cb[c];
  #pragma unroll
  for (int dy=0;dy<3;++dy){ int yy=hh+dy-1; if(yy<0||yy>63) continue;
    #pragma unroll
    for (int dx=0;dx<3;++dx){ int xx=ww+dx-1; if(xx<0||xx>63) continue;
      a += ip[yy*64+xx]*cw[c*9+dy*3+dx]; } }
  float gl = 0.5f*a*(1.f+tanhf(0.79788456080286536f*(a+0.044715f*a*a*a)));
  out2[gid] = gl*ca[b*NC+c] + ip[p];
}

// ============================================================================
extern "C" void kernel_launch(void* const* d_in, const int* in_sizes, int n_in,
                              void* d_out, int out_size, void* d_ws, size_t ws_size,
                              hipStream_t stream)
{
  const float* x       = (const float*)d_in[0];
  const float* p_in_w  = (const float*)d_in[1];
  const float* p_in_b  = (const float*)d_in[2];
  const float* p_ln_w  = (const float*)d_in[3];
  const float* p_ln_b  = (const float*)d_in[4];
  const float* p_off_w1= (const float*)d_in[5];
  const float* p_off_b1= (const float*)d_in[6];
  const float* p_off_w2= (const float*)d_in[7];
  const float* p_off_b2= (const float*)d_in[8];
  const float* p_ca_w  = (const float*)d_in[9];
  const float* p_ca_b  = (const float*)d_in[10];
  const float* p_sa_w  = (const float*)d_in[11];
  const float* p_sa_b  = (const float*)d_in[12];
  const float* p_mask_w1=(const float*)d_in[13];
  const float* p_mask_b1=(const float*)d_in[14];
  const float* p_mask_w2=(const float*)d_in[15];
  const float* p_mask_b2=(const float*)d_in[16];
  const float* v_w     = (const float*)d_in[17];
  const float* v_b     = (const float*)d_in[18];
  const float* q_w     = (const float*)d_in[19];
  const float* q_b     = (const float*)d_in[20];
  const float* k_w     = (const float*)d_in[21];
  const float* k_b     = (const float*)d_in[22];
  const float* cs_w    = (const float*)d_in[23];
  const float* cs_b    = (const float*)d_in[24];
  const float* out_w   = (const float*)d_in[25];
  const float* out_b   = (const float*)d_in[26];
  float* out = (float*)d_out;
  (void)in_sizes; (void)n_in; (void)out_size;

  char* wsp = (char*)d_ws;
  size_t off = 0;
  auto alloc = [&](size_t bytes)->char*{ char* p = wsp + off; off += (bytes + 255) & ~(size_t)255; return p; };
  float* f     = (float*)alloc((size_t)NB*NC4*NN*4);
  float* score = (float*)alloc((size_t)NB*NN*4);
  int*   idx1  = (int*)  alloc((size_t)NB*NKEEP*4);
  int*   flag  = (int*)  alloc((size_t)NB*NN*4);
  float* offs  = (float*)alloc((size_t)NB*2*NN*4);
  float* sa    = (float*)alloc((size_t)NB*NN*4);
  float* fmean = (float*)alloc((size_t)NB*NC4*4);
  float* ca    = (float*)alloc((size_t)NB*NC*4);
  float* vbuf  = (float*)alloc((size_t)NB*NC*NN*4);     // v, later out_img (in place)
  bf16*  q1bf  = (bf16*) alloc((size_t)NB*NKEEP*NC*2);
  bf16*  k1bf  = (bf16*) alloc((size_t)NB*NKEEP*NC*2);
  bf16*  v1T   = (bf16*) alloc((size_t)NB*NC*NKEEP*2);
  float4* wpar = (float4*)alloc((size_t)NB*NKEEP*16);
  int4*   ipar = (int4*) alloc((size_t)NB*NKEEP*16);
  float* out2  = (float*)alloc((size_t)NB*NC*NN*4);
  float* pl    = (float*)alloc((size_t)NB*32*NSPLIT*64*4);
  bf16*  xT    = (bf16*) alloc((size_t)NB*NN*NC*2);     // x tokens; later out2T
  bf16*  wqb   = (bf16*) alloc((size_t)NC*NC*2);
  bf16*  wkb   = (bf16*) alloc((size_t)NC*NC*2);
  bf16*  wvb   = (bf16*) alloc((size_t)NC*NC*2);
  bf16*  wob   = (bf16*) alloc((size_t)NC*NC*2);
  if (off > ws_size) return;
  // aliases inside out2 (sequentially dead):
  //   qin/kin (gathers+gemms) -> pacc (attn+merge) -> out2 fp32 (dwgelu+transpose)
  bf16* qin  = (bf16*)out2;
  bf16* kin  = qin + (size_t)NB*NKEEP*NC;
  bf16* pacc = (bf16*)out2;
  bf16* out2T = xT;   // xT dead after gather_kT

  k_w2bf<<<(NC*NC+255)/256, 256, 0, stream>>>(q_w, k_w, v_w, out_w, wqb, wkb, wvb, wob);
  k_transpose<<<dim3(NN/32, NC/32, NB), 256, 0, stream>>>(x, xT);
  k_f_score<<<NB*NN/128, 128, 0, stream>>>(x, p_in_w, p_in_b, p_ln_w, p_ln_b,
      p_mask_w1, p_mask_b1, p_mask_w2, p_mask_b2, f, score);
  k_topk<<<NB, 1024, 0, stream>>>(score, idx1, flag);
  k_offsets<<<NB*NN/256, 256, 0, stream>>>(f, p_off_w1, p_off_b1, p_off_w2, p_off_b2, offs);
  k_fmean<<<NB*NC4, 256, 0, stream>>>(f, fmean);
  k_ca<<<NB, NC, 0, stream>>>(fmean, p_ca_w, p_ca_b, ca);
  k_sa<<<NB*NN/256, 256, 0, stream>>>(f, p_sa_w, p_sa_b, sa);
  k_conv_mfma<<<dim3(NN/64, NB), 256, 0, stream>>>(xT, wvb, v_b, vbuf);
  k_warp_params<<<NB*NKEEP/256, 256, 0, stream>>>(idx1, offs, wpar, ipar);
  k_gather_qT<<<NB*NKEEP*24/256, 256, 0, stream>>>(xT, idx1, qin);
  k_gather_kT<<<NB*NKEEP*24/256, 256, 0, stream>>>(xT, idx1, wpar, ipar, kin);
  k_gemm_mfma<<<dim3(NKEEP/32, NB), 256, 0, stream>>>(qin, wqb, q_b, q1bf);
  k_gemm_mfma<<<dim3(NKEEP/32, NB), 256, 0, stream>>>(kin, wkb, k_b, k1bf);
  k_gather_vT<<<NB*NC*NKEEP/256, 256, 0, stream>>>(vbuf, idx1, v1T);
  k_fill<<<NB*NC*NN/256, 256, 0, stream>>>(sa, flag, vbuf);
  k_attn<<<dim3(NKEEP/64, NB, NSPLIT), 256, 0, stream>>>(q1bf, k1bf, v1T, pacc, pl);
  k_merge<<<NB*NKEEP*NC/256, 256, 0, stream>>>(pacc, pl, idx1, vbuf);
  k_dwgelu<<<NB*NC*NN/256, 256, 0, stream>>>(vbuf, ca, cs_w, cs_b, out2);
  k_transpose<<<dim3(NN/32, NC/32, NB), 256, 0, stream>>>(out2, out2T);
  k_conv_mfma<<<dim3(NN/64, NB), 256, 0, stream>>>(out2T, wob, out_b, out);
}

// Round 7
// 485.126 us; speedup vs baseline: 2.8851x; 1.1389x over previous
//
#include <hip/hip_runtime.h>
#include <hip/hip_bf16.h>

#define NB   8
#define NC   192
#define NH   64
#define NW   64
#define NN   4096        // H*W
#define NCD  194         // C+2
#define NC4  48          // (C+2)/4
#define NKEEP 2048       // N*RATIO
#define NSPLIT 4         // attention K-splits
#define KPS   (NKEEP/NSPLIT)   // 512 keys per split
#define NT    (KPS/32)         // 16 key-tiles per split

typedef __attribute__((ext_vector_type(8))) short bf16x8;  // 8 bf16 (4 VGPRs)
typedef __attribute__((ext_vector_type(4))) float f32x4;
typedef __hip_bfloat16 bf16;

__device__ __forceinline__ float dsigmoid(float x){ return 1.f/(1.f+__expf(-x)); }
__device__ __forceinline__ float dlrelu(float x){ return x>0.f ? x : 0.1f*x; }
__device__ __forceinline__ float b2f(short s){ return __uint_as_float(((unsigned)(unsigned short)s)<<16); }

// ---------------- K0: f = lrelu(LN(conv1x1(cond))), plus score ----------------
__global__ __launch_bounds__(128) void k_f_score(
    const float* __restrict__ x, const float* __restrict__ w_in, const float* __restrict__ b_in,
    const float* __restrict__ ln_w, const float* __restrict__ ln_b,
    const float* __restrict__ mw1, const float* __restrict__ mb1,
    const float* __restrict__ mw2, const float* __restrict__ mb2,
    float* __restrict__ f, float* __restrict__ score)
{
  __shared__ float wT[NCD][NC4];   // transposed weights; reads are broadcast
  int t = threadIdx.x;
  for (int i=t; i<NCD*NC4; i+=128){ int o = i/NCD, c = i - o*NCD; wT[c][o] = w_in[i]; }
  __syncthreads();

  int gid = blockIdx.x*128 + t;
  int p = gid & (NN-1), b = gid >> 12;
  int hh = p>>6, ww = p&63;

  f32x4 a4[12];
  #pragma unroll
  for (int j=0;j<12;++j) a4[j] = *(const f32x4*)(b_in + 4*j);

  const float* xb = x + (size_t)b*NC*NN + p;
  for (int c=0;c<NC;++c){
    float xv = xb[(size_t)c*NN];
    #pragma unroll
    for (int j=0;j<12;++j){ f32x4 wv = *(const f32x4*)&wT[c][4*j]; a4[j] += wv*xv; }
  }
  { float gx = -1.f + (2.f/63.f)*(float)ww;
    #pragma unroll
    for (int j=0;j<12;++j){ f32x4 wv = *(const f32x4*)&wT[192][4*j]; a4[j] += wv*gx; }
    float gy = -1.f + (2.f/63.f)*(float)hh;
    #pragma unroll
    for (int j=0;j<12;++j){ f32x4 wv = *(const f32x4*)&wT[193][4*j]; a4[j] += wv*gy; }
  }
  float s1=0.f, s2=0.f;
  #pragma unroll
  for (int j=0;j<12;++j){
    #pragma unroll
    for (int k=0;k<4;++k){ float v=a4[j][k]; s1+=v; s2+=v*v; }
  }
  float mean = s1*(1.f/NC4);
  float var  = s2*(1.f/NC4) - mean*mean;
  float rstd = rsqrtf(var + 1e-6f);
  float tsum = 0.f;
  #pragma unroll
  for (int j=0;j<12;++j){
    f32x4 lw = *(const f32x4*)(ln_w + 4*j);
    f32x4 lb = *(const f32x4*)(ln_b + 4*j);
    #pragma unroll
    for (int k=0;k<4;++k){
      float z = lw[k]*((a4[j][k]-mean)*rstd) + lb[k];
      float fv = z>0.f ? z : 0.1f*z;
      tsum += fv;
      f[((size_t)b*NC4 + 4*j+k)*NN + p] = fv;
    }
  }
  float tm = tsum*(1.f/NC4);
  float sv = dlrelu(tm*mw1[0] + mb1[0]);
  float d  = sv*(mw2[0]-mw2[1]) + (mb2[0]-mb2[1]);
  score[b*NN + p] = dsigmoid(d);
}

// ---------------- K1: per-batch top-2048 via 64-bit radix select -----------
// key = (desc(score)<<32)|index (unique). Find exact 2048th-smallest key P by
// byte-wise histogram select (8 passes); select = key <= P. Set matches stable
// argsort(-score)[:2048] exactly; idx1 order is arbitrary (attention+scatter
// are order-invariant).
__global__ __launch_bounds__(1024) void k_topk(const float* __restrict__ score,
                                               int* __restrict__ idx1, int* __restrict__ flag)
{
  int b = blockIdx.x;
  int t = threadIdx.x;
  __shared__ unsigned hist[256];
  __shared__ unsigned long long sP;
  __shared__ unsigned sR;
  __shared__ unsigned cnt;
  unsigned long long key[4];
  #pragma unroll
  for (int j=0;j<4;++j){
    int i = t + j*1024;
    unsigned u = __float_as_uint(score[b*NN+i]);
    unsigned a = (u & 0x80000000u) ? ~u : (u | 0x80000000u); // ascending orderable
    unsigned d = ~a;                                          // descending score
    key[j] = ((unsigned long long)d << 32) | (unsigned)i;
  }
  if (t==0){ sP=0ull; sR=NKEEP-1; cnt=0u; }
  #pragma unroll 1
  for (int pass=0; pass<8; ++pass){
    int shift = 56 - pass*8;
    if (t<256) hist[t]=0u;
    __syncthreads();
    unsigned long long P = sP;
    #pragma unroll
    for (int j=0;j<4;++j){
      bool ok = (pass==0) || ((key[j] >> (shift+8)) == (P >> (shift+8)));
      if (ok) atomicAdd(&hist[(unsigned)((key[j]>>shift)&255ull)], 1u);
    }
    __syncthreads();
    if (t < 64){
      unsigned s[4]; unsigned lsum=0u;
      #pragma unroll
      for (int j=0;j<4;++j){ s[j]=hist[4*t+j]; lsum+=s[j]; }
      unsigned incl = lsum;
      #pragma unroll
      for (int d2=1; d2<64; d2<<=1){
        unsigned v = __shfl_up(incl, d2);
        if (t >= d2) incl += v;
      }
      unsigned before = incl - lsum;
      unsigned R = sR;
      if (R >= before && R < incl){
        unsigned c = before;
        #pragma unroll
        for (int j=0;j<4;++j){
          if (R < c + s[j]){
            sP = sP | ((unsigned long long)(4u*(unsigned)t + (unsigned)j) << shift);
            sR = R - c;
            break;
          }
          c += s[j];
        }
      }
    }
    __syncthreads();
  }
  unsigned long long P = sP;
  #pragma unroll
  for (int j=0;j<4;++j){
    int i = t + j*1024;
    bool sel = (key[j] <= P);
    flag[b*NN+i] = sel ? 1 : 0;
    if (sel){
      unsigned pos = atomicAdd(&cnt, 1u);
      idx1[b*NKEEP + pos] = i;
    }
  }
}

// ---------------- K2: offsets = tanh(conv1x1(lrelu(conv1x1(f))))*8 ----------
__global__ __launch_bounds__(256) void k_offsets(
    const float* __restrict__ f, const float* __restrict__ w1, const float* __restrict__ b1,
    const float* __restrict__ w2, const float* __restrict__ b2, float* __restrict__ offs)
{
  int gid = blockIdx.x*256 + threadIdx.x;
  int p = gid & (NN-1);
  int b = gid >> 12;
  const float* fb = f + (size_t)b*NC4*NN + p;
  float fl[NC4];
  #pragma unroll 8
  for (int c=0;c<NC4;++c) fl[c] = fb[(size_t)c*NN];
  float h1[24];
  for (int o=0;o<24;++o){
    const float* wr = w1 + o*NC4;
    float a = b1[o];
    #pragma unroll 8
    for (int c=0;c<NC4;++c) a += wr[c]*fl[c];
    h1[o] = dlrelu(a);
  }
  #pragma unroll
  for (int o=0;o<2;++o){
    const float* wr = w2 + o*24;
    float a = b2[o];
    #pragma unroll
    for (int c=0;c<24;++c) a += wr[c]*h1[c];
    offs[((size_t)b*2+o)*NN + p] = tanhf(a)*8.f;
  }
}

// ---------------- K3: f spatial mean, then ca = sigmoid(fc) -----------------
__global__ __launch_bounds__(256) void k_fmean(const float* __restrict__ f, float* __restrict__ fmean){
  int bc = blockIdx.x;
  const float* p = f + (size_t)bc*NN;
  float s = 0.f;
  for (int i=threadIdx.x;i<NN;i+=256) s += p[i];
  for (int o=32;o;o>>=1) s += __shfl_xor(s,o);
  __shared__ float r[4];
  if ((threadIdx.x&63)==0) r[threadIdx.x>>6] = s;
  __syncthreads();
  if (threadIdx.x==0) fmean[bc] = (r[0]+r[1]+r[2]+r[3])*(1.f/NN);
}

__global__ void k_ca(const float* __restrict__ fmean, const float* __restrict__ w,
                     const float* __restrict__ bias, float* __restrict__ ca){
  int b = blockIdx.x, o = threadIdx.x;
  const float* fm = fmean + b*NC4;
  float a = bias[o];
  #pragma unroll 8
  for (int c=0;c<NC4;++c) a += w[o*NC4+c]*fm[c];
  ca[b*NC+o] = dsigmoid(a);
}

// ---------------- K4: sa = sigmoid(conv3x3(f, 48->1)) -----------------------
__global__ __launch_bounds__(256) void k_sa(const float* __restrict__ f, const float* __restrict__ w,
                                            const float* __restrict__ bias, float* __restrict__ sa){
  int gid = blockIdx.x*256 + threadIdx.x;
  int p = gid & (NN-1);
  int b = gid >> 12;
  int hh=p>>6, ww=p&63;
  float acc = bias[0];
  for (int c=0;c<NC4;++c){
    const float* fp = f + ((size_t)b*NC4+c)*NN;
    const float* wc = w + c*9;
    #pragma unroll
    for (int dy=0;dy<3;++dy){ int yy=hh+dy-1; if(yy<0||yy>63) continue;
      #pragma unroll
      for (int dx=0;dx<3;++dx){ int xx=ww+dx-1; if(xx<0||xx>63) continue;
        acc += fp[yy*64+xx]*wc[dy*3+dx]; } }
  }
  sa[gid] = dsigmoid(acc);
}

// ---------------- weights fp32 -> bf16 (4 matrices of 192x192) --------------
__global__ __launch_bounds__(256) void k_w2bf(const float* __restrict__ a, const float* __restrict__ b,
                                              const float* __restrict__ c, const float* __restrict__ d,
                                              bf16* __restrict__ oa, bf16* __restrict__ ob,
                                              bf16* __restrict__ oc, bf16* __restrict__ od){
  int i = blockIdx.x*256 + threadIdx.x;
  if (i < NC*NC){
    oa[i] = __float2bfloat16(a[i]);
    ob[i] = __float2bfloat16(b[i]);
    oc[i] = __float2bfloat16(c[i]);
    od[i] = __float2bfloat16(d[i]);
  }
}

// ---------------- transpose [b][c][p] fp32 -> [b][p][c] bf16 ----------------
__global__ __launch_bounds__(256) void k_transpose(const float* __restrict__ in, bf16* __restrict__ outT){
  int b = blockIdx.z;
  int c0 = blockIdx.y*32, p0 = blockIdx.x*32;
  __shared__ float tile[32][33];
  int col = threadIdx.x & 31, row8 = threadIdx.x >> 5;
  #pragma unroll
  for (int ph=0;ph<4;++ph){
    int c = c0 + ph*8 + row8;
    tile[ph*8+row8][col] = in[((size_t)b*NC + c)*NN + p0 + col];
  }
  __syncthreads();
  #pragma unroll
  for (int ph=0;ph<4;++ph){
    int p = p0 + ph*8 + row8;
    outT[((size_t)b*NN + p)*NC + c0 + col] = __float2bfloat16(tile[col][ph*8+row8]);
  }
}

// ---------------- conv1x1 via MFMA: out[b][o][p] = inT[b][p][:]·w[o][:] -----
__global__ __launch_bounds__(256) void k_conv_mfma(const bf16* __restrict__ inT, const bf16* __restrict__ wb,
                                                   const float* __restrict__ bias, float* __restrict__ outp){
  int b = blockIdx.y;
  int px0 = blockIdx.x*64;
  int wv = threadIdx.x>>6, lane = threadIdx.x&63, g = lane>>4, r = lane&15;
  int o0 = wv*48;
  bf16x8 bw[3][6];
  #pragma unroll
  for (int jo=0;jo<3;++jo)
    #pragma unroll
    for (int ks=0;ks<6;++ks)
      bw[jo][ks] = *(const bf16x8*)(wb + (size_t)(o0+jo*16+r)*NC + ks*32 + 8*g);
  float bv[3];
  #pragma unroll
  for (int jo=0;jo<3;++jo) bv[jo] = bias[o0+jo*16+r];

  const bf16* ib = inT + (size_t)b*NN*NC;
  #pragma unroll
  for (int t=0;t<4;++t){
    int px = px0 + t*16;
    bf16x8 a[6];
    #pragma unroll
    for (int ks=0;ks<6;++ks) a[ks] = *(const bf16x8*)(ib + (size_t)(px+r)*NC + ks*32 + 8*g);
    f32x4 acc[3];
    #pragma unroll
    for (int jo=0;jo<3;++jo){ acc[jo][0]=0.f; acc[jo][1]=0.f; acc[jo][2]=0.f; acc[jo][3]=0.f; }
    #pragma unroll
    for (int ks=0;ks<6;++ks)
      #pragma unroll
      for (int jo=0;jo<3;++jo)
        acc[jo] = __builtin_amdgcn_mfma_f32_16x16x32_bf16(a[ks], bw[jo][ks], acc[jo], 0,0,0);
    #pragma unroll
    for (int jo=0;jo<3;++jo){
      float4 rv; rv.x=acc[jo][0]+bv[jo]; rv.y=acc[jo][1]+bv[jo]; rv.z=acc[jo][2]+bv[jo]; rv.w=acc[jo][3]+bv[jo];
      *(float4*)(outp + ((size_t)b*NC + o0+jo*16+r)*NN + px + 4*g) = rv;
    }
  }
}

// ---------------- token GEMM via MFMA: out[b][s][o] bf16 --------------------
__global__ __launch_bounds__(256) void k_gemm_mfma(const bf16* __restrict__ in, const bf16* __restrict__ wb,
                                                   const float* __restrict__ bias, bf16* __restrict__ outp){
  int b = blockIdx.y;
  int s0 = blockIdx.x*32;
  int wv = threadIdx.x>>6, lane = threadIdx.x&63, g = lane>>4, r = lane&15;
  int o0 = wv*48;
  bf16x8 bw[3][6];
  #pragma unroll
  for (int jo=0;jo<3;++jo)
    #pragma unroll
    for (int ks=0;ks<6;++ks)
      bw[jo][ks] = *(const bf16x8*)(wb + (size_t)(o0+jo*16+r)*NC + ks*32 + 8*g);
  float bv[3];
  #pragma unroll
  for (int jo=0;jo<3;++jo) bv[jo] = bias[o0+jo*16+r];

  const bf16* ib = in + (size_t)b*NKEEP*NC;
  bf16* ob = outp + (size_t)b*NKEEP*NC;
  #pragma unroll
  for (int t=0;t<2;++t){
    int s = s0 + t*16;
    bf16x8 a[6];
    #pragma unroll
    for (int ks=0;ks<6;++ks) a[ks] = *(const bf16x8*)(ib + (size_t)(s+r)*NC + ks*32 + 8*g);
    f32x4 acc[3];
    #pragma unroll
    for (int jo=0;jo<3;++jo){ acc[jo][0]=0.f; acc[jo][1]=0.f; acc[jo][2]=0.f; acc[jo][3]=0.f; }
    #pragma unroll
    for (int ks=0;ks<6;++ks)
      #pragma unroll
      for (int jo=0;jo<3;++jo)
        acc[jo] = __builtin_amdgcn_mfma_f32_16x16x32_bf16(a[ks], bw[jo][ks], acc[jo], 0,0,0);
    #pragma unroll
    for (int jo=0;jo<3;++jo)
      #pragma unroll
      for (int i=0;i<4;++i)
        ob[(size_t)(s+4*g+i)*NC + o0+jo*16+r] = __float2bfloat16(acc[jo][i]+bv[jo]);
  }
}

// ---------------- warp params per selected token ----------------------------
__global__ __launch_bounds__(256) void k_warp_params(const int* __restrict__ idx1, const float* __restrict__ offs,
                                                     float4* __restrict__ wpar, int4* __restrict__ ipar){
  int gid = blockIdx.x*256 + threadIdx.x;  // B*KEEP
  int b = gid >> 11;
  int p = idx1[gid];
  int ph = p >> 6, pwx = p & 63;
  float fx = offs[((size_t)b*2+0)*NN + p];
  float fy = offs[((size_t)b*2+1)*NN + p];
  float sx = (float)pwx + fx, sy = (float)ph + fy;
  float x0f = floorf(sx), y0f = floorf(sy);
  float wx = sx - x0f, wy = sy - y0f;
  int x0 = (int)x0f, y0 = (int)y0f;
  bool vx0 = (x0f >= 0.f) && (x0f <= 63.f);
  bool vx1 = (x0f+1.f >= 0.f) && (x0f+1.f <= 63.f);
  bool vy0 = (y0f >= 0.f) && (y0f <= 63.f);
  bool vy1 = (y0f+1.f >= 0.f) && (y0f+1.f <= 63.f);
  int cx0 = min(max(x0,0),63), cx1 = min(max(x0+1,0),63);
  int cy0 = min(max(y0,0),63), cy1 = min(max(y0+1,0),63);
  float4 w4;
  w4.x = (vx0&&vy0) ? (1.f-wx)*(1.f-wy) : 0.f;
  w4.y = (vx1&&vy0) ? wx*(1.f-wy)       : 0.f;
  w4.z = (vx0&&vy1) ? (1.f-wx)*wy       : 0.f;
  w4.w = (vx1&&vy1) ? wx*wy             : 0.f;
  int4 i4;
  i4.x = cy0*64+cx0; i4.y = cy0*64+cx1; i4.z = cy1*64+cx0; i4.w = cy1*64+cx1;
  wpar[gid]=w4; ipar[gid]=i4;
}

// ---------------- gathers from xT (token rows, vectorized) ------------------
__global__ __launch_bounds__(256) void k_gather_qT(const bf16* __restrict__ xT, const int* __restrict__ idx1,
                                                   bf16* __restrict__ qin){
  int gid = blockIdx.x*256 + threadIdx.x;   // B*KEEP*24
  int j = gid % 24;
  int bs = gid / 24;
  int b = bs >> 11;
  int p = idx1[bs];
  *(bf16x8*)(qin + (size_t)bs*NC + j*8) = *(const bf16x8*)(xT + ((size_t)b*NN + p)*NC + j*8);
}

__global__ __launch_bounds__(256) void k_gather_kT(const bf16* __restrict__ xT, const int* __restrict__ idx1,
                                                   const float4* __restrict__ wpar, const int4* __restrict__ ipar,
                                                   bf16* __restrict__ kin){
  int gid = blockIdx.x*256 + threadIdx.x;   // B*KEEP*24
  int j = gid % 24;
  int bs = gid / 24;
  int b = bs >> 11;
  int p = idx1[bs];
  float4 w4 = wpar[bs]; int4 i4 = ipar[bs];
  const bf16* xb = xT + (size_t)b*NN*NC + j*8;
  bf16x8 v0 = *(const bf16x8*)(xb + (size_t)p*NC);
  bf16x8 v1 = *(const bf16x8*)(xb + (size_t)i4.x*NC);
  bf16x8 v2 = *(const bf16x8*)(xb + (size_t)i4.y*NC);
  bf16x8 v3 = *(const bf16x8*)(xb + (size_t)i4.z*NC);
  bf16x8 v4 = *(const bf16x8*)(xb + (size_t)i4.w*NC);
  bf16x8 o;
  #pragma unroll
  for (int k=0;k<8;++k){
    float vv = b2f(v0[k]) + w4.x*b2f(v1[k]) + w4.y*b2f(v2[k]) + w4.z*b2f(v3[k]) + w4.w*b2f(v4[k]);
    bf16 h = __float2bfloat16(vv);
    o[k] = *(short*)&h;
  }
  *(bf16x8*)(kin + (size_t)bs*NC + j*8) = o;
}

__global__ __launch_bounds__(256) void k_gather_vT(const float* __restrict__ v, const int* __restrict__ idx1,
                                                   bf16* __restrict__ v1T){
  int gid = blockIdx.x*256 + threadIdx.x;
  int s = gid & (NKEEP-1);
  int bc = gid >> 11;
  int b = bc/NC;
  v1T[gid] = __float2bfloat16(v[(size_t)bc*NN + idx1[b*NKEEP+s]]);
}

// ---------------- fill unselected: out_img = v*sa (in place in v) -----------
__global__ __launch_bounds__(256) void k_fill(const float* __restrict__ sa, const int* __restrict__ flag,
                                              float* __restrict__ vout){
  int gid = blockIdx.x*256 + threadIdx.x;  // B*C*N
  int p = gid & (NN-1);
  int bc = gid >> 12;
  int b = bc/NC;
  if (!flag[b*NN+p]) vout[gid] *= sa[b*NN+p];
}

// ---------------- flash attention: LDS-staged K/V, K-split x4 ---------------
__global__ __launch_bounds__(256) void k_attn(const bf16* __restrict__ q1, const bf16* __restrict__ k1,
                                              const bf16* __restrict__ v1T,
                                              bf16* __restrict__ pacc, float* __restrict__ pl)
{
  int b = blockIdx.y, qb = blockIdx.x, sp = blockIdx.z;
  int tid = threadIdx.x;
  int wv = tid >> 6;
  int lane = tid & 63;
  int g = lane >> 4, r = lane & 15;
  int q0 = qb*64 + wv*16;

  const bf16* qbp = q1 + (size_t)b*NKEEP*NC;
  const char* kgb = (const char*)(k1 + (size_t)b*NKEEP*NC);
  const char* vgb = (const char*)(v1T + (size_t)b*NC*NKEEP);

  __shared__ __align__(1024) char kl[12288];        // K tile, swizzled rows
  __shared__ __align__(1024) char vl[2][12288];     // V tile, double-buffered
  __shared__ __align__(16) bf16 plds[4][16][40];    // per-wave P transpose
  bf16 (* __restrict__ pw)[40] = plds[wv];
  char* klc = kl;

  int ksrc[3], vsrc[3];
  #pragma unroll
  for (int i=0;i<3;++i){
    int j = wv*3 + i;
    int o = j*1024 + lane*16;
    int rr = o/384, cb = o - rr*384;
    ksrc[i] = rr*384 + (cb ^ ((rr&7)<<4));
    int ch = o>>6, kb2 = o&63;
    vsrc[i] = ch*(NKEEP*2) + kb2;
  }

  const int kbase = sp*KPS;
  auto stage = [&](int k0, int vb){
    char* vlc = vl[vb];
    #pragma unroll
    for (int i=0;i<3;++i){
      int j = wv*3 + i;
      __builtin_amdgcn_global_load_lds(
        (const __attribute__((address_space(1))) void*)(kgb + (size_t)k0*384 + ksrc[i]),
        (__attribute__((address_space(3))) void*)(klc + j*1024), 16, 0, 0);
      __builtin_amdgcn_global_load_lds(
        (const __attribute__((address_space(1))) void*)(vgb + (size_t)k0*2 + vsrc[i]),
        (__attribute__((address_space(3))) void*)(vlc + j*1024), 16, 0, 0);
    }
  };

  bf16x8 aq[6];
  #pragma unroll
  for (int ks=0;ks<6;++ks)
    aq[ks] = *(const bf16x8*)(qbp + (size_t)(q0+r)*NC + 32*ks + 8*g);

  f32x4 acc[12];
  #pragma unroll
  for (int i=0;i<12;++i){ acc[i][0]=0.f; acc[i][1]=0.f; acc[i][2]=0.f; acc[i][3]=0.f; }
  float l[4]={0.f,0.f,0.f,0.f};

  const float scale = 0.07216878364870323f;        // 192^-0.5
  const float shift = 20.f;                        // uniform; cancels in v/l
  const int swz = (r&7)<<4;

  stage(kbase, 0);
  __syncthreads();

  int vb = 0;
  for (int t16=0;t16<NT;++t16) {
    f32x4 s0v, s1v;
    s0v[0]=s0v[1]=s0v[2]=s0v[3]=0.f;
    s1v[0]=s1v[1]=s1v[2]=s1v[3]=0.f;
    #pragma unroll
    for (int ks=0;ks<6;++ks) {
      int co = (ks*64 + g*16) ^ swz;
      bf16x8 bk0 = *(const bf16x8*)(klc + r*384 + co);
      bf16x8 bk1 = *(const bf16x8*)(klc + (16+r)*384 + co);
      s0v = __builtin_amdgcn_mfma_f32_16x16x32_bf16(aq[ks], bk0, s0v, 0,0,0);
      s1v = __builtin_amdgcn_mfma_f32_16x16x32_bf16(aq[ks], bk1, s1v, 0,0,0);
    }
    #pragma unroll
    for (int i=0;i<4;++i) {
      float e0 = __expf(s0v[i]*scale - shift);
      float e1 = __expf(s1v[i]*scale - shift);
      l[i] += e0 + e1;
      pw[4*g+i][r]    = __float2bfloat16(e0);
      pw[4*g+i][16+r] = __float2bfloat16(e1);
    }
    bf16x8 pa = *(const bf16x8*)(&pw[r][8*g]);

    __syncthreads();
    if (t16+1 < NT) stage(kbase + (t16+1)*32, vb^1);

    const char* vlc = vl[vb];
    #pragma unroll
    for (int ct=0;ct<12;++ct) {
      bf16x8 bvv = *(const bf16x8*)(vlc + (16*ct + r)*64 + g*16);
      acc[ct] = __builtin_amdgcn_mfma_f32_16x16x32_bf16(pa, bvv, acc[ct], 0,0,0);
    }
    __syncthreads();
    vb ^= 1;
  }

  #pragma unroll
  for (int i=0;i<4;++i){
    #pragma unroll
    for (int o=1;o<16;o<<=1) l[i] += __shfl_xor(l[i],o);
  }
  size_t pbase = (((size_t)(b*32+qb)*NSPLIT + sp)*64);
  if (r==0){
    #pragma unroll
    for (int i=0;i<4;++i) pl[pbase + wv*16 + 4*g + i] = l[i];
  }
  #pragma unroll
  for (int ct=0;ct<12;++ct)
    #pragma unroll
    for (int i=0;i<4;++i)
      pacc[(pbase + wv*16 + 4*g + i)*NC + 16*ct + r] = __float2bfloat16(acc[ct][i]);
}

// ---------------- merge the NSPLIT attention partials + scatter -------------
__global__ __launch_bounds__(256) void k_merge(const bf16* __restrict__ pacc,
                                               const float* __restrict__ pl, const int* __restrict__ idx1,
                                               float* __restrict__ out_img)
{
  int gid = blockIdx.x*256 + threadIdx.x;   // B*KEEP*NC, c fastest
  int c = gid % NC;
  int bs = gid / NC;
  int s = bs & (NKEEP-1);
  int b = bs >> 11;
  int qb = s >> 6, ql = s & 63;
  size_t base = ((size_t)(b*32+qb)*NSPLIT)*64 + ql;
  float l = pl[base] + pl[base+64] + pl[base+128] + pl[base+192];
  size_t pb = base*NC + c;
  float v = __bfloat162float(pacc[pb])
          + __bfloat162float(pacc[pb + (size_t)64*NC])
          + __bfloat162float(pacc[pb + (size_t)128*NC])
          + __bfloat162float(pacc[pb + (size_t)192*NC]);
  out_img[((size_t)b*NC + c)*NN + idx1[b*NKEEP + s]] = v / l;
}

// ---------------- depthwise 3x3 + gelu*ca + residual ------------------------
__global__ __launch_bounds__(256) void k_dwgelu(const float* __restrict__ vin, const float* __restrict__ ca,
                                                const float* __restrict__ cw, const float* __restrict__ cb,
                                                float* __restrict__ out2){
  int gid = blockIdx.x*256 + threadIdx.x;
  int p = gid & (NN-1);
  int bc = gid >> 12;
  int c = bc % NC, b = bc / NC;
  int hh = p>>6, ww = p&63;
  const float* ip = vin + (size_t)bc*NN;
  float a = cb[c];
  #pragma unroll
  for (int dy=0;dy<3;++dy){ int yy=hh+dy-1; if(yy<0||yy>63) continue;
    #pragma unroll
    for (int dx=0;dx<3;++dx){ int xx=ww+dx-1; if(xx<0||xx>63) continue;
      a += ip[yy*64+xx]*cw[c*9+dy*3+dx]; } }
  float gl = 0.5f*a*(1.f+tanhf(0.79788456080286536f*(a+0.044715f*a*a*a)));
  out2[gid] = gl*ca[b*NC+c] + ip[p];
}

// ============================================================================
extern "C" void kernel_launch(void* const* d_in, const int* in_sizes, int n_in,
                              void* d_out, int out_size, void* d_ws, size_t ws_size,
                              hipStream_t stream)
{
  const float* x       = (const float*)d_in[0];
  const float* p_in_w  = (const float*)d_in[1];
  const float* p_in_b  = (const float*)d_in[2];
  const float* p_ln_w  = (const float*)d_in[3];
  const float* p_ln_b  = (const float*)d_in[4];
  const float* p_off_w1= (const float*)d_in[5];
  const float* p_off_b1= (const float*)d_in[6];
  const float* p_off_w2= (const float*)d_in[7];
  const float* p_off_b2= (const float*)d_in[8];
  const float* p_ca_w  = (const float*)d_in[9];
  const float* p_ca_b  = (const float*)d_in[10];
  const float* p_sa_w  = (const float*)d_in[11];
  const float* p_sa_b  = (const float*)d_in[12];
  const float* p_mask_w1=(const float*)d_in[13];
  const float* p_mask_b1=(const float*)d_in[14];
  const float* p_mask_w2=(const float*)d_in[15];
  const float* p_mask_b2=(const float*)d_in[16];
  const float* v_w     = (const float*)d_in[17];
  const float* v_b     = (const float*)d_in[18];
  const float* q_w     = (const float*)d_in[19];
  const float* q_b     = (const float*)d_in[20];
  const float* k_w     = (const float*)d_in[21];
  const float* k_b     = (const float*)d_in[22];
  const float* cs_w    = (const float*)d_in[23];
  const float* cs_b    = (const float*)d_in[24];
  const float* out_w   = (const float*)d_in[25];
  const float* out_b   = (const float*)d_in[26];
  float* out = (float*)d_out;
  (void)in_sizes; (void)n_in; (void)out_size;

  char* wsp = (char*)d_ws;
  size_t off = 0;
  auto alloc = [&](size_t bytes)->char*{ char* p = wsp + off; off += (bytes + 255) & ~(size_t)255; return p; };
  float* f     = (float*)alloc((size_t)NB*NC4*NN*4);
  float* score = (float*)alloc((size_t)NB*NN*4);
  int*   idx1  = (int*)  alloc((size_t)NB*NKEEP*4);
  int*   flag  = (int*)  alloc((size_t)NB*NN*4);
  float* offs  = (float*)alloc((size_t)NB*2*NN*4);
  float* sa    = (float*)alloc((size_t)NB*NN*4);
  float* fmean = (float*)alloc((size_t)NB*NC4*4);
  float* ca    = (float*)alloc((size_t)NB*NC*4);
  float* vbuf  = (float*)alloc((size_t)NB*NC*NN*4);     // v, later out_img (in place)
  bf16*  q1bf  = (bf16*) alloc((size_t)NB*NKEEP*NC*2);
  bf16*  k1bf  = (bf16*) alloc((size_t)NB*NKEEP*NC*2);
  bf16*  v1T   = (bf16*) alloc((size_t)NB*NC*NKEEP*2);
  float4* wpar = (float4*)alloc((size_t)NB*NKEEP*16);
  int4*   ipar = (int4*) alloc((size_t)NB*NKEEP*16);
  float* out2  = (float*)alloc((size_t)NB*NC*NN*4);
  float* pl    = (float*)alloc((size_t)NB*32*NSPLIT*64*4);
  bf16*  xT    = (bf16*) alloc((size_t)NB*NN*NC*2);     // x tokens; later out2T
  bf16*  wqb   = (bf16*) alloc((size_t)NC*NC*2);
  bf16*  wkb   = (bf16*) alloc((size_t)NC*NC*2);
  bf16*  wvb   = (bf16*) alloc((size_t)NC*NC*2);
  bf16*  wob   = (bf16*) alloc((size_t)NC*NC*2);
  if (off > ws_size) return;
  // aliases inside out2 (sequentially dead):
  //   qin/kin (gathers+gemms) -> pacc (attn+merge) -> out2 fp32 (dwgelu+transpose)
  bf16* qin  = (bf16*)out2;
  bf16* kin  = qin + (size_t)NB*NKEEP*NC;
  bf16* pacc = (bf16*)out2;
  bf16* out2T = xT;   // xT dead after gather_kT

  k_w2bf<<<(NC*NC+255)/256, 256, 0, stream>>>(q_w, k_w, v_w, out_w, wqb, wkb, wvb, wob);
  k_transpose<<<dim3(NN/32, NC/32, NB), 256, 0, stream>>>(x, xT);
  k_f_score<<<NB*NN/128, 128, 0, stream>>>(x, p_in_w, p_in_b, p_ln_w, p_ln_b,
      p_mask_w1, p_mask_b1, p_mask_w2, p_mask_b2, f, score);
  k_topk<<<NB, 1024, 0, stream>>>(score, idx1, flag);
  k_offsets<<<NB*NN/256, 256, 0, stream>>>(f, p_off_w1, p_off_b1, p_off_w2, p_off_b2, offs);
  k_fmean<<<NB*NC4, 256, 0, stream>>>(f, fmean);
  k_ca<<<NB, NC, 0, stream>>>(fmean, p_ca_w, p_ca_b, ca);
  k_sa<<<NB*NN/256, 256, 0, stream>>>(f, p_sa_w, p_sa_b, sa);
  k_conv_mfma<<<dim3(NN/64, NB), 256, 0, stream>>>(xT, wvb, v_b, vbuf);
  k_warp_params<<<NB*NKEEP/256, 256, 0, stream>>>(idx1, offs, wpar, ipar);
  k_gather_qT<<<NB*NKEEP*24/256, 256, 0, stream>>>(xT, idx1, qin);
  k_gather_kT<<<NB*NKEEP*24/256, 256, 0, stream>>>(xT, idx1, wpar, ipar, kin);
  k_gemm_mfma<<<dim3(NKEEP/32, NB), 256, 0, stream>>>(qin, wqb, q_b, q1bf);
  k_gemm_mfma<<<dim3(NKEEP/32, NB), 256, 0, stream>>>(kin, wkb, k_b, k1bf);
  k_gather_vT<<<NB*NC*NKEEP/256, 256, 0, stream>>>(vbuf, idx1, v1T);
  k_fill<<<NB*NC*NN/256, 256, 0, stream>>>(sa, flag, vbuf);
  k_attn<<<dim3(NKEEP/64, NB, NSPLIT), 256, 0, stream>>>(q1bf, k1bf, v1T, pacc, pl);
  k_merge<<<NB*NKEEP*NC/256, 256, 0, stream>>>(pacc, pl, idx1, vbuf);
  k_dwgelu<<<NB*NC*NN/256, 256, 0, stream>>>(vbuf, ca, cs_w, cs_b, out2);
  k_transpose<<<dim3(NN/32, NC/32, NB), 256, 0, stream>>>(out2, out2T);
  k_conv_mfma<<<dim3(NN/64, NB), 256, 0, stream>>>(out2T, wob, out_b, out);
}

// Round 8
// 433.169 us; speedup vs baseline: 3.2312x; 1.1199x over previous
//
#include <hip/hip_runtime.h>
#include <hip/hip_bf16.h>

#define NB   8
#define NC   192
#define NH   64
#define NW   64
#define NN   4096        // H*W
#define NCD  194         // C+2
#define NC4  48          // (C+2)/4
#define NKEEP 2048       // N*RATIO
#define NSPLIT 4         // attention K-splits
#define KPS   (NKEEP/NSPLIT)   // 512 keys per split
#define NT    (KPS/32)         // 16 key-tiles per split

typedef __attribute__((ext_vector_type(8))) short bf16x8;  // 8 bf16 (4 VGPRs)
typedef __attribute__((ext_vector_type(4))) float f32x4;
typedef __hip_bfloat16 bf16;

__device__ __forceinline__ float dsigmoid(float x){ return 1.f/(1.f+__expf(-x)); }
__device__ __forceinline__ float dlrelu(float x){ return x>0.f ? x : 0.1f*x; }
__device__ __forceinline__ float b2f(short s){ return __uint_as_float(((unsigned)(unsigned short)s)<<16); }

// ---------------- K0: f = lrelu(LN(conv1x1(cond))), plus score ----------------
__global__ __launch_bounds__(128) void k_f_score(
    const float* __restrict__ x, const float* __restrict__ w_in, const float* __restrict__ b_in,
    const float* __restrict__ ln_w, const float* __restrict__ ln_b,
    const float* __restrict__ mw1, const float* __restrict__ mb1,
    const float* __restrict__ mw2, const float* __restrict__ mb2,
    float* __restrict__ f, float* __restrict__ score)
{
  __shared__ float wT[NCD][NC4];   // transposed weights; reads are broadcast
  int t = threadIdx.x;
  for (int i=t; i<NCD*NC4; i+=128){ int o = i/NCD, c = i - o*NCD; wT[c][o] = w_in[i]; }
  __syncthreads();

  int gid = blockIdx.x*128 + t;
  int p = gid & (NN-1), b = gid >> 12;
  int hh = p>>6, ww = p&63;

  f32x4 a4[12];
  #pragma unroll
  for (int j=0;j<12;++j) a4[j] = *(const f32x4*)(b_in + 4*j);

  const float* xb = x + (size_t)b*NC*NN + p;
  for (int c=0;c<NC;++c){
    float xv = xb[(size_t)c*NN];
    #pragma unroll
    for (int j=0;j<12;++j){ f32x4 wv = *(const f32x4*)&wT[c][4*j]; a4[j] += wv*xv; }
  }
  { float gx = -1.f + (2.f/63.f)*(float)ww;
    #pragma unroll
    for (int j=0;j<12;++j){ f32x4 wv = *(const f32x4*)&wT[192][4*j]; a4[j] += wv*gx; }
    float gy = -1.f + (2.f/63.f)*(float)hh;
    #pragma unroll
    for (int j=0;j<12;++j){ f32x4 wv = *(const f32x4*)&wT[193][4*j]; a4[j] += wv*gy; }
  }
  float s1=0.f, s2=0.f;
  #pragma unroll
  for (int j=0;j<12;++j){
    #pragma unroll
    for (int k=0;k<4;++k){ float v=a4[j][k]; s1+=v; s2+=v*v; }
  }
  float mean = s1*(1.f/NC4);
  float var  = s2*(1.f/NC4) - mean*mean;
  float rstd = rsqrtf(var + 1e-6f);
  float tsum = 0.f;
  #pragma unroll
  for (int j=0;j<12;++j){
    f32x4 lw = *(const f32x4*)(ln_w + 4*j);
    f32x4 lb = *(const f32x4*)(ln_b + 4*j);
    #pragma unroll
    for (int k=0;k<4;++k){
      float z = lw[k]*((a4[j][k]-mean)*rstd) + lb[k];
      float fv = z>0.f ? z : 0.1f*z;
      tsum += fv;
      f[((size_t)b*NC4 + 4*j+k)*NN + p] = fv;
    }
  }
  float tm = tsum*(1.f/NC4);
  float sv = dlrelu(tm*mw1[0] + mb1[0]);
  float d  = sv*(mw2[0]-mw2[1]) + (mb2[0]-mb2[1]);
  score[b*NN + p] = dsigmoid(d);
}

// ---------------- K1: per-batch top-2048 via 64-bit radix select -----------
__global__ __launch_bounds__(1024) void k_topk(const float* __restrict__ score,
                                               int* __restrict__ idx1, int* __restrict__ flag)
{
  int b = blockIdx.x;
  int t = threadIdx.x;
  __shared__ unsigned hist[256];
  __shared__ unsigned long long sP;
  __shared__ unsigned sR;
  __shared__ unsigned cnt;
  unsigned long long key[4];
  #pragma unroll
  for (int j=0;j<4;++j){
    int i = t + j*1024;
    unsigned u = __float_as_uint(score[b*NN+i]);
    unsigned a = (u & 0x80000000u) ? ~u : (u | 0x80000000u); // ascending orderable
    unsigned d = ~a;                                          // descending score
    key[j] = ((unsigned long long)d << 32) | (unsigned)i;
  }
  if (t==0){ sP=0ull; sR=NKEEP-1; cnt=0u; }
  #pragma unroll 1
  for (int pass=0; pass<8; ++pass){
    int shift = 56 - pass*8;
    if (t<256) hist[t]=0u;
    __syncthreads();
    unsigned long long P = sP;
    #pragma unroll
    for (int j=0;j<4;++j){
      bool ok = (pass==0) || ((key[j] >> (shift+8)) == (P >> (shift+8)));
      if (ok) atomicAdd(&hist[(unsigned)((key[j]>>shift)&255ull)], 1u);
    }
    __syncthreads();
    if (t < 64){
      unsigned s[4]; unsigned lsum=0u;
      #pragma unroll
      for (int j=0;j<4;++j){ s[j]=hist[4*t+j]; lsum+=s[j]; }
      unsigned incl = lsum;
      #pragma unroll
      for (int d2=1; d2<64; d2<<=1){
        unsigned v = __shfl_up(incl, d2);
        if (t >= d2) incl += v;
      }
      unsigned before = incl - lsum;
      unsigned R = sR;
      if (R >= before && R < incl){
        unsigned c = before;
        #pragma unroll
        for (int j=0;j<4;++j){
          if (R < c + s[j]){
            sP = sP | ((unsigned long long)(4u*(unsigned)t + (unsigned)j) << shift);
            sR = R - c;
            break;
          }
          c += s[j];
        }
      }
    }
    __syncthreads();
  }
  unsigned long long P = sP;
  #pragma unroll
  for (int j=0;j<4;++j){
    int i = t + j*1024;
    bool sel = (key[j] <= P);
    flag[b*NN+i] = sel ? 1 : 0;
    if (sel){
      unsigned pos = atomicAdd(&cnt, 1u);
      idx1[b*NKEEP + pos] = i;
    }
  }
}

// ---------------- K2: offsets = tanh(conv1x1(lrelu(conv1x1(f))))*8 ----------
__global__ __launch_bounds__(256) void k_offsets(
    const float* __restrict__ f, const float* __restrict__ w1, const float* __restrict__ b1,
    const float* __restrict__ w2, const float* __restrict__ b2, float* __restrict__ offs)
{
  int gid = blockIdx.x*256 + threadIdx.x;
  int p = gid & (NN-1);
  int b = gid >> 12;
  const float* fb = f + (size_t)b*NC4*NN + p;
  float fl[NC4];
  #pragma unroll 8
  for (int c=0;c<NC4;++c) fl[c] = fb[(size_t)c*NN];
  float h1[24];
  for (int o=0;o<24;++o){
    const float* wr = w1 + o*NC4;
    float a = b1[o];
    #pragma unroll 8
    for (int c=0;c<NC4;++c) a += wr[c]*fl[c];
    h1[o] = dlrelu(a);
  }
  #pragma unroll
  for (int o=0;o<2;++o){
    const float* wr = w2 + o*24;
    float a = b2[o];
    #pragma unroll
    for (int c=0;c<24;++c) a += wr[c]*h1[c];
    offs[((size_t)b*2+o)*NN + p] = tanhf(a)*8.f;
  }
}

// ---------------- K3: f spatial mean, then ca = sigmoid(fc) -----------------
__global__ __launch_bounds__(256) void k_fmean(const float* __restrict__ f, float* __restrict__ fmean){
  int bc = blockIdx.x;
  const float* p = f + (size_t)bc*NN;
  float s = 0.f;
  for (int i=threadIdx.x;i<NN;i+=256) s += p[i];
  for (int o=32;o;o>>=1) s += __shfl_xor(s,o);
  __shared__ float r[4];
  if ((threadIdx.x&63)==0) r[threadIdx.x>>6] = s;
  __syncthreads();
  if (threadIdx.x==0) fmean[bc] = (r[0]+r[1]+r[2]+r[3])*(1.f/NN);
}

__global__ void k_ca(const float* __restrict__ fmean, const float* __restrict__ w,
                     const float* __restrict__ bias, float* __restrict__ ca){
  int b = blockIdx.x, o = threadIdx.x;
  const float* fm = fmean + b*NC4;
  float a = bias[o];
  #pragma unroll 8
  for (int c=0;c<NC4;++c) a += w[o*NC4+c]*fm[c];
  ca[b*NC+o] = dsigmoid(a);
}

// ---------------- K4: sa = sigmoid(conv3x3(f, 48->1)), LDS-staged -----------
// block = (row hh, batch b); stage 3 rows x 48 ch (+/-1 col zero-pad) in LDS;
// thread = (pixel ww, 12-ch group); 4-way LDS reduce at the end.
__global__ __launch_bounds__(256) void k_sa(const float* __restrict__ f, const float* __restrict__ w,
                                            const float* __restrict__ bias, float* __restrict__ sa){
  int hh = blockIdx.x;
  int b  = blockIdx.y;
  __shared__ float fl[3][NC4][66];   // 38016 B
  __shared__ float wl[NC4*9];        // 1728 B
  __shared__ float ps[4][64];        // 1024 B
  int t = threadIdx.x;

  for (int i=t; i<3*NC4*64; i+=256){
    int col = i & 63;
    int rc  = i >> 6;            // 0..143
    int cc  = rc % NC4;
    int rr  = rc / NC4;          // 0..2
    int yy  = hh + rr - 1;
    float v = (yy>=0 && yy<=63) ? f[((size_t)b*NC4+cc)*NN + yy*64 + col] : 0.f;
    fl[rr][cc][1+col] = v;
  }
  if (t < 3*NC4){ int rr=t/NC4, cc=t%NC4; fl[rr][cc][0]=0.f; fl[rr][cc][65]=0.f; }
  for (int i=t; i<NC4*9; i+=256) wl[i] = w[i];
  __syncthreads();

  int ww = t & 63, gq = t >> 6;
  float acc = 0.f;
  #pragma unroll
  for (int j=0;j<12;++j){
    int cc = gq*12 + j;
    const float* wc = &wl[cc*9];
    #pragma unroll
    for (int dy=0;dy<3;++dy){
      acc += fl[dy][cc][ww  ]*wc[dy*3+0];
      acc += fl[dy][cc][ww+1]*wc[dy*3+1];
      acc += fl[dy][cc][ww+2]*wc[dy*3+2];
    }
  }
  ps[gq][ww] = acc;
  __syncthreads();
  if (t < 64){
    float s = ps[0][t]+ps[1][t]+ps[2][t]+ps[3][t] + bias[0];
    sa[(size_t)b*NN + hh*64 + t] = dsigmoid(s);
  }
}

// ---------------- weights fp32 -> bf16 (4 matrices of 192x192) --------------
__global__ __launch_bounds__(256) void k_w2bf(const float* __restrict__ a, const float* __restrict__ b,
                                              const float* __restrict__ c, const float* __restrict__ d,
                                              bf16* __restrict__ oa, bf16* __restrict__ ob,
                                              bf16* __restrict__ oc, bf16* __restrict__ od){
  int i = blockIdx.x*256 + threadIdx.x;
  if (i < NC*NC){
    oa[i] = __float2bfloat16(a[i]);
    ob[i] = __float2bfloat16(b[i]);
    oc[i] = __float2bfloat16(c[i]);
    od[i] = __float2bfloat16(d[i]);
  }
}

// ---------------- transpose [b][c][p] fp32 -> [b][p][c] bf16 ----------------
__global__ __launch_bounds__(256) void k_transpose(const float* __restrict__ in, bf16* __restrict__ outT){
  int b = blockIdx.z;
  int c0 = blockIdx.y*32, p0 = blockIdx.x*32;
  __shared__ float tile[32][33];
  int col = threadIdx.x & 31, row8 = threadIdx.x >> 5;
  #pragma unroll
  for (int ph=0;ph<4;++ph){
    int c = c0 + ph*8 + row8;
    tile[ph*8+row8][col] = in[((size_t)b*NC + c)*NN + p0 + col];
  }
  __syncthreads();
  #pragma unroll
  for (int ph=0;ph<4;++ph){
    int p = p0 + ph*8 + row8;
    outT[((size_t)b*NN + p)*NC + c0 + col] = __float2bfloat16(tile[col][ph*8+row8]);
  }
}

// ---------------- conv1x1 via MFMA: out[b][o][p] = inT[b][p][:]·w[o][:] -----
__global__ __launch_bounds__(256) void k_conv_mfma(const bf16* __restrict__ inT, const bf16* __restrict__ wb,
                                                   const float* __restrict__ bias, float* __restrict__ outp){
  int b = blockIdx.y;
  int px0 = blockIdx.x*64;
  int wv = threadIdx.x>>6, lane = threadIdx.x&63, g = lane>>4, r = lane&15;
  int o0 = wv*48;
  bf16x8 bw[3][6];
  #pragma unroll
  for (int jo=0;jo<3;++jo)
    #pragma unroll
    for (int ks=0;ks<6;++ks)
      bw[jo][ks] = *(const bf16x8*)(wb + (size_t)(o0+jo*16+r)*NC + ks*32 + 8*g);
  float bv[3];
  #pragma unroll
  for (int jo=0;jo<3;++jo) bv[jo] = bias[o0+jo*16+r];

  const bf16* ib = inT + (size_t)b*NN*NC;
  #pragma unroll
  for (int t=0;t<4;++t){
    int px = px0 + t*16;
    bf16x8 a[6];
    #pragma unroll
    for (int ks=0;ks<6;++ks) a[ks] = *(const bf16x8*)(ib + (size_t)(px+r)*NC + ks*32 + 8*g);
    f32x4 acc[3];
    #pragma unroll
    for (int jo=0;jo<3;++jo){ acc[jo][0]=0.f; acc[jo][1]=0.f; acc[jo][2]=0.f; acc[jo][3]=0.f; }
    #pragma unroll
    for (int ks=0;ks<6;++ks)
      #pragma unroll
      for (int jo=0;jo<3;++jo)
        acc[jo] = __builtin_amdgcn_mfma_f32_16x16x32_bf16(a[ks], bw[jo][ks], acc[jo], 0,0,0);
    #pragma unroll
    for (int jo=0;jo<3;++jo){
      float4 rv; rv.x=acc[jo][0]+bv[jo]; rv.y=acc[jo][1]+bv[jo]; rv.z=acc[jo][2]+bv[jo]; rv.w=acc[jo][3]+bv[jo];
      *(float4*)(outp + ((size_t)b*NC + o0+jo*16+r)*NN + px + 4*g) = rv;
    }
  }
}

// ---------------- token GEMM via MFMA: out[b][s][o] bf16 --------------------
__global__ __launch_bounds__(256) void k_gemm_mfma(const bf16* __restrict__ in, const bf16* __restrict__ wb,
                                                   const float* __restrict__ bias, bf16* __restrict__ outp){
  int b = blockIdx.y;
  int s0 = blockIdx.x*32;
  int wv = threadIdx.x>>6, lane = threadIdx.x&63, g = lane>>4, r = lane&15;
  int o0 = wv*48;
  bf16x8 bw[3][6];
  #pragma unroll
  for (int jo=0;jo<3;++jo)
    #pragma unroll
    for (int ks=0;ks<6;++ks)
      bw[jo][ks] = *(const bf16x8*)(wb + (size_t)(o0+jo*16+r)*NC + ks*32 + 8*g);
  float bv[3];
  #pragma unroll
  for (int jo=0;jo<3;++jo) bv[jo] = bias[o0+jo*16+r];

  const bf16* ib = in + (size_t)b*NKEEP*NC;
  bf16* ob = outp + (size_t)b*NKEEP*NC;
  #pragma unroll
  for (int t=0;t<2;++t){
    int s = s0 + t*16;
    bf16x8 a[6];
    #pragma unroll
    for (int ks=0;ks<6;++ks) a[ks] = *(const bf16x8*)(ib + (size_t)(s+r)*NC + ks*32 + 8*g);
    f32x4 acc[3];
    #pragma unroll
    for (int jo=0;jo<3;++jo){ acc[jo][0]=0.f; acc[jo][1]=0.f; acc[jo][2]=0.f; acc[jo][3]=0.f; }
    #pragma unroll
    for (int ks=0;ks<6;++ks)
      #pragma unroll
      for (int jo=0;jo<3;++jo)
        acc[jo] = __builtin_amdgcn_mfma_f32_16x16x32_bf16(a[ks], bw[jo][ks], acc[jo], 0,0,0);
    #pragma unroll
    for (int jo=0;jo<3;++jo)
      #pragma unroll
      for (int i=0;i<4;++i)
        ob[(size_t)(s+4*g+i)*NC + o0+jo*16+r] = __float2bfloat16(acc[jo][i]+bv[jo]);
  }
}

// ---------------- warp params per selected token ----------------------------
__global__ __launch_bounds__(256) void k_warp_params(const int* __restrict__ idx1, const float* __restrict__ offs,
                                                     float4* __restrict__ wpar, int4* __restrict__ ipar){
  int gid = blockIdx.x*256 + threadIdx.x;  // B*KEEP
  int b = gid >> 11;
  int p = idx1[gid];
  int ph = p >> 6, pwx = p & 63;
  float fx = offs[((size_t)b*2+0)*NN + p];
  float fy = offs[((size_t)b*2+1)*NN + p];
  float sx = (float)pwx + fx, sy = (float)ph + fy;
  float x0f = floorf(sx), y0f = floorf(sy);
  float wx = sx - x0f, wy = sy - y0f;
  int x0 = (int)x0f, y0 = (int)y0f;
  bool vx0 = (x0f >= 0.f) && (x0f <= 63.f);
  bool vx1 = (x0f+1.f >= 0.f) && (x0f+1.f <= 63.f);
  bool vy0 = (y0f >= 0.f) && (y0f <= 63.f);
  bool vy1 = (y0f+1.f >= 0.f) && (y0f+1.f <= 63.f);
  int cx0 = min(max(x0,0),63), cx1 = min(max(x0+1,0),63);
  int cy0 = min(max(y0,0),63), cy1 = min(max(y0+1,0),63);
  float4 w4;
  w4.x = (vx0&&vy0) ? (1.f-wx)*(1.f-wy) : 0.f;
  w4.y = (vx1&&vy0) ? wx*(1.f-wy)       : 0.f;
  w4.z = (vx0&&vy1) ? (1.f-wx)*wy       : 0.f;
  w4.w = (vx1&&vy1) ? wx*wy             : 0.f;
  int4 i4;
  i4.x = cy0*64+cx0; i4.y = cy0*64+cx1; i4.z = cy1*64+cx0; i4.w = cy1*64+cx1;
  wpar[gid]=w4; ipar[gid]=i4;
}

// ---------------- gathers from xT (token rows, vectorized) ------------------
__global__ __launch_bounds__(256) void k_gather_qT(const bf16* __restrict__ xT, const int* __restrict__ idx1,
                                                   bf16* __restrict__ qin){
  int gid = blockIdx.x*256 + threadIdx.x;   // B*KEEP*24
  int j = gid % 24;
  int bs = gid / 24;
  int b = bs >> 11;
  int p = idx1[bs];
  *(bf16x8*)(qin + (size_t)bs*NC + j*8) = *(const bf16x8*)(xT + ((size_t)b*NN + p)*NC + j*8);
}

__global__ __launch_bounds__(256) void k_gather_kT(const bf16* __restrict__ xT, const int* __restrict__ idx1,
                                                   const float4* __restrict__ wpar, const int4* __restrict__ ipar,
                                                   bf16* __restrict__ kin){
  int gid = blockIdx.x*256 + threadIdx.x;   // B*KEEP*24
  int j = gid % 24;
  int bs = gid / 24;
  int b = bs >> 11;
  int p = idx1[bs];
  float4 w4 = wpar[bs]; int4 i4 = ipar[bs];
  const bf16* xb = xT + (size_t)b*NN*NC + j*8;
  bf16x8 v0 = *(const bf16x8*)(xb + (size_t)p*NC);
  bf16x8 v1 = *(const bf16x8*)(xb + (size_t)i4.x*NC);
  bf16x8 v2 = *(const bf16x8*)(xb + (size_t)i4.y*NC);
  bf16x8 v3 = *(const bf16x8*)(xb + (size_t)i4.z*NC);
  bf16x8 v4 = *(const bf16x8*)(xb + (size_t)i4.w*NC);
  bf16x8 o;
  #pragma unroll
  for (int k=0;k<8;++k){
    float vv = b2f(v0[k]) + w4.x*b2f(v1[k]) + w4.y*b2f(v2[k]) + w4.z*b2f(v3[k]) + w4.w*b2f(v4[k]);
    bf16 h = __float2bfloat16(vv);
    o[k] = *(short*)&h;
  }
  *(bf16x8*)(kin + (size_t)bs*NC + j*8) = o;
}

__global__ __launch_bounds__(256) void k_gather_vT(const float* __restrict__ v, const int* __restrict__ idx1,
                                                   bf16* __restrict__ v1T){
  int gid = blockIdx.x*256 + threadIdx.x;
  int s = gid & (NKEEP-1);
  int bc = gid >> 11;
  int b = bc/NC;
  v1T[gid] = __float2bfloat16(v[(size_t)bc*NN + idx1[b*NKEEP+s]]);
}

// ---------------- fill unselected: out_img = v*sa (in place in v) -----------
__global__ __launch_bounds__(256) void k_fill(const float* __restrict__ sa, const int* __restrict__ flag,
                                              float* __restrict__ vout){
  int gid = blockIdx.x*256 + threadIdx.x;  // B*C*N
  int p = gid & (NN-1);
  int bc = gid >> 12;
  int b = bc/NC;
  if (!flag[b*NN+p]) vout[gid] *= sa[b*NN+p];
}

// ---------------- flash attention: LDS-staged K/V, K-split x4 ---------------
__global__ __launch_bounds__(256) void k_attn(const bf16* __restrict__ q1, const bf16* __restrict__ k1,
                                              const bf16* __restrict__ v1T,
                                              bf16* __restrict__ pacc, float* __restrict__ pl)
{
  int b = blockIdx.y, qb = blockIdx.x, sp = blockIdx.z;
  int tid = threadIdx.x;
  int wv = tid >> 6;
  int lane = tid & 63;
  int g = lane >> 4, r = lane & 15;
  int q0 = qb*64 + wv*16;

  const bf16* qbp = q1 + (size_t)b*NKEEP*NC;
  const char* kgb = (const char*)(k1 + (size_t)b*NKEEP*NC);
  const char* vgb = (const char*)(v1T + (size_t)b*NC*NKEEP);

  __shared__ __align__(1024) char kl[12288];        // K tile, swizzled rows
  __shared__ __align__(1024) char vl[2][12288];     // V tile, double-buffered
  __shared__ __align__(16) bf16 plds[4][16][40];    // per-wave P transpose
  bf16 (* __restrict__ pw)[40] = plds[wv];
  char* klc = kl;

  int ksrc[3], vsrc[3];
  #pragma unroll
  for (int i=0;i<3;++i){
    int j = wv*3 + i;
    int o = j*1024 + lane*16;
    int rr = o/384, cb = o - rr*384;
    ksrc[i] = rr*384 + (cb ^ ((rr&7)<<4));
    int ch = o>>6, kb2 = o&63;
    vsrc[i] = ch*(NKEEP*2) + kb2;
  }

  const int kbase = sp*KPS;
  auto stage = [&](int k0, int vb){
    char* vlc = vl[vb];
    #pragma unroll
    for (int i=0;i<3;++i){
      int j = wv*3 + i;
      __builtin_amdgcn_global_load_lds(
        (const __attribute__((address_space(1))) void*)(kgb + (size_t)k0*384 + ksrc[i]),
        (__attribute__((address_space(3))) void*)(klc + j*1024), 16, 0, 0);
      __builtin_amdgcn_global_load_lds(
        (const __attribute__((address_space(1))) void*)(vgb + (size_t)k0*2 + vsrc[i]),
        (__attribute__((address_space(3))) void*)(vlc + j*1024), 16, 0, 0);
    }
  };

  bf16x8 aq[6];
  #pragma unroll
  for (int ks=0;ks<6;++ks)
    aq[ks] = *(const bf16x8*)(qbp + (size_t)(q0+r)*NC + 32*ks + 8*g);

  f32x4 acc[12];
  #pragma unroll
  for (int i=0;i<12;++i){ acc[i][0]=0.f; acc[i][1]=0.f; acc[i][2]=0.f; acc[i][3]=0.f; }
  float l[4]={0.f,0.f,0.f,0.f};

  const float scale = 0.07216878364870323f;        // 192^-0.5
  const float shift = 20.f;                        // uniform; cancels in v/l
  const int swz = (r&7)<<4;

  stage(kbase, 0);
  __syncthreads();

  int vb = 0;
  for (int t16=0;t16<NT;++t16) {
    f32x4 s0v, s1v;
    s0v[0]=s0v[1]=s0v[2]=s0v[3]=0.f;
    s1v[0]=s1v[1]=s1v[2]=s1v[3]=0.f;
    #pragma unroll
    for (int ks=0;ks<6;++ks) {
      int co = (ks*64 + g*16) ^ swz;
      bf16x8 bk0 = *(const bf16x8*)(klc + r*384 + co);
      bf16x8 bk1 = *(const bf16x8*)(klc + (16+r)*384 + co);
      s0v = __builtin_amdgcn_mfma_f32_16x16x32_bf16(aq[ks], bk0, s0v, 0,0,0);
      s1v = __builtin_amdgcn_mfma_f32_16x16x32_bf16(aq[ks], bk1, s1v, 0,0,0);
    }
    #pragma unroll
    for (int i=0;i<4;++i) {
      float e0 = __expf(s0v[i]*scale - shift);
      float e1 = __expf(s1v[i]*scale - shift);
      l[i] += e0 + e1;
      pw[4*g+i][r]    = __float2bfloat16(e0);
      pw[4*g+i][16+r] = __float2bfloat16(e1);
    }
    bf16x8 pa = *(const bf16x8*)(&pw[r][8*g]);

    __syncthreads();
    if (t16+1 < NT) stage(kbase + (t16+1)*32, vb^1);

    const char* vlc = vl[vb];
    #pragma unroll
    for (int ct=0;ct<12;++ct) {
      bf16x8 bvv = *(const bf16x8*)(vlc + (16*ct + r)*64 + g*16);
      acc[ct] = __builtin_amdgcn_mfma_f32_16x16x32_bf16(pa, bvv, acc[ct], 0,0,0);
    }
    __syncthreads();
    vb ^= 1;
  }

  #pragma unroll
  for (int i=0;i<4;++i){
    #pragma unroll
    for (int o=1;o<16;o<<=1) l[i] += __shfl_xor(l[i],o);
  }
  size_t pbase = (((size_t)(b*32+qb)*NSPLIT + sp)*64);
  if (r==0){
    #pragma unroll
    for (int i=0;i<4;++i) pl[pbase + wv*16 + 4*g + i] = l[i];
  }
  #pragma unroll
  for (int ct=0;ct<12;++ct)
    #pragma unroll
    for (int i=0;i<4;++i)
      pacc[(pbase + wv*16 + 4*g + i)*NC + 16*ct + r] = __float2bfloat16(acc[ct][i]);
}

// ---------------- merge the NSPLIT attention partials + scatter -------------
__global__ __launch_bounds__(256) void k_merge(const bf16* __restrict__ pacc,
                                               const float* __restrict__ pl, const int* __restrict__ idx1,
                                               float* __restrict__ out_img)
{
  int gid = blockIdx.x*256 + threadIdx.x;   // B*KEEP*NC, c fastest
  int c = gid % NC;
  int bs = gid / NC;
  int s = bs & (NKEEP-1);
  int b = bs >> 11;
  int qb = s >> 6, ql = s & 63;
  size_t base = ((size_t)(b*32+qb)*NSPLIT)*64 + ql;
  float l = pl[base] + pl[base+64] + pl[base+128] + pl[base+192];
  size_t pb = base*NC + c;
  float v = __bfloat162float(pacc[pb])
          + __bfloat162float(pacc[pb + (size_t)64*NC])
          + __bfloat162float(pacc[pb + (size_t)128*NC])
          + __bfloat162float(pacc[pb + (size_t)192*NC]);
  out_img[((size_t)b*NC + c)*NN + idx1[b*NKEEP + s]] = v / l;
}

// ---------------- depthwise 3x3 + gelu*ca + residual, LDS-staged ------------
// block = one (b,c) plane; stage 64x64 (+zero halo) in LDS; 16 px/thread.
__global__ __launch_bounds__(256) void k_dwgelu(const float* __restrict__ vin, const float* __restrict__ ca,
                                                const float* __restrict__ cw, const float* __restrict__ cb,
                                                float* __restrict__ out2){
  int bc = blockIdx.x;           // b*NC + c
  int c = bc % NC, b = bc / NC;
  __shared__ float tl[66][66];   // 17424 B, zero halo
  int t = threadIdx.x;

  if (t < 66){ tl[0][t] = 0.f; tl[65][t] = 0.f; }
  if (t < 64){ tl[t+1][0] = 0.f; tl[t+1][65] = 0.f; }
  const float* ip = vin + (size_t)bc*NN;
  #pragma unroll
  for (int k=0;k<4;++k){
    int p4 = (t + k*256)*4;
    int hh = p4 >> 6, ww = p4 & 63;
    float4 v4 = *(const float4*)(ip + p4);
    tl[1+hh][1+ww  ] = v4.x;
    tl[1+hh][1+ww+1] = v4.y;
    tl[1+hh][1+ww+2] = v4.z;
    tl[1+hh][1+ww+3] = v4.w;
  }
  float wr[9];
  #pragma unroll
  for (int i=0;i<9;++i) wr[i] = cw[c*9+i];
  float cbv = cb[c];
  float cav = ca[b*NC+c];
  __syncthreads();

  float* op = out2 + (size_t)bc*NN;
  #pragma unroll
  for (int k=0;k<16;++k){
    int p = t + k*256;
    int hh = p >> 6, ww = p & 63;
    float a = cbv;
    #pragma unroll
    for (int dy=0;dy<3;++dy){
      a += tl[hh+dy][ww  ]*wr[dy*3+0];
      a += tl[hh+dy][ww+1]*wr[dy*3+1];
      a += tl[hh+dy][ww+2]*wr[dy*3+2];
    }
    float gl = 0.5f*a*(1.f+tanhf(0.79788456080286536f*(a+0.044715f*a*a*a)));
    op[p] = gl*cav + tl[1+hh][1+ww];
  }
}

// ============================================================================
extern "C" void kernel_launch(void* const* d_in, const int* in_sizes, int n_in,
                              void* d_out, int out_size, void* d_ws, size_t ws_size,
                              hipStream_t stream)
{
  const float* x       = (const float*)d_in[0];
  const float* p_in_w  = (const float*)d_in[1];
  const float* p_in_b  = (const float*)d_in[2];
  const float* p_ln_w  = (const float*)d_in[3];
  const float* p_ln_b  = (const float*)d_in[4];
  const float* p_off_w1= (const float*)d_in[5];
  const float* p_off_b1= (const float*)d_in[6];
  const float* p_off_w2= (const float*)d_in[7];
  const float* p_off_b2= (const float*)d_in[8];
  const float* p_ca_w  = (const float*)d_in[9];
  const float* p_ca_b  = (const float*)d_in[10];
  const float* p_sa_w  = (const float*)d_in[11];
  const float* p_sa_b  = (const float*)d_in[12];
  const float* p_mask_w1=(const float*)d_in[13];
  const float* p_mask_b1=(const float*)d_in[14];
  const float* p_mask_w2=(const float*)d_in[15];
  const float* p_mask_b2=(const float*)d_in[16];
  const float* v_w     = (const float*)d_in[17];
  const float* v_b     = (const float*)d_in[18];
  const float* q_w     = (const float*)d_in[19];
  const float* q_b     = (const float*)d_in[20];
  const float* k_w     = (const float*)d_in[21];
  const float* k_b     = (const float*)d_in[22];
  const float* cs_w    = (const float*)d_in[23];
  const float* cs_b    = (const float*)d_in[24];
  const float* out_w   = (const float*)d_in[25];
  const float* out_b   = (const float*)d_in[26];
  float* out = (float*)d_out;
  (void)in_sizes; (void)n_in; (void)out_size;

  char* wsp = (char*)d_ws;
  size_t off = 0;
  auto alloc = [&](size_t bytes)->char*{ char* p = wsp + off; off += (bytes + 255) & ~(size_t)255; return p; };
  float* f     = (float*)alloc((size_t)NB*NC4*NN*4);
  float* score = (float*)alloc((size_t)NB*NN*4);
  int*   idx1  = (int*)  alloc((size_t)NB*NKEEP*4);
  int*   flag  = (int*)  alloc((size_t)NB*NN*4);
  float* offs  = (float*)alloc((size_t)NB*2*NN*4);
  float* sa    = (float*)alloc((size_t)NB*NN*4);
  float* fmean = (float*)alloc((size_t)NB*NC4*4);
  float* ca    = (float*)alloc((size_t)NB*NC*4);
  float* vbuf  = (float*)alloc((size_t)NB*NC*NN*4);     // v, later out_img (in place)
  bf16*  q1bf  = (bf16*) alloc((size_t)NB*NKEEP*NC*2);
  bf16*  k1bf  = (bf16*) alloc((size_t)NB*NKEEP*NC*2);
  bf16*  v1T   = (bf16*) alloc((size_t)NB*NC*NKEEP*2);
  float4* wpar = (float4*)alloc((size_t)NB*NKEEP*16);
  int4*   ipar = (int4*) alloc((size_t)NB*NKEEP*16);
  float* out2  = (float*)alloc((size_t)NB*NC*NN*4);
  float* pl    = (float*)alloc((size_t)NB*32*NSPLIT*64*4);
  bf16*  xT    = (bf16*) alloc((size_t)NB*NN*NC*2);     // x tokens; later out2T
  bf16*  wqb   = (bf16*) alloc((size_t)NC*NC*2);
  bf16*  wkb   = (bf16*) alloc((size_t)NC*NC*2);
  bf16*  wvb   = (bf16*) alloc((size_t)NC*NC*2);
  bf16*  wob   = (bf16*) alloc((size_t)NC*NC*2);
  if (off > ws_size) return;
  // aliases inside out2 (sequentially dead):
  //   qin/kin (gathers+gemms) -> pacc (attn+merge) -> out2 fp32 (dwgelu+transpose)
  bf16* qin  = (bf16*)out2;
  bf16* kin  = qin + (size_t)NB*NKEEP*NC;
  bf16* pacc = (bf16*)out2;
  bf16* out2T = xT;   // xT dead after gather_kT

  k_w2bf<<<(NC*NC+255)/256, 256, 0, stream>>>(q_w, k_w, v_w, out_w, wqb, wkb, wvb, wob);
  k_transpose<<<dim3(NN/32, NC/32, NB), 256, 0, stream>>>(x, xT);
  k_f_score<<<NB*NN/128, 128, 0, stream>>>(x, p_in_w, p_in_b, p_ln_w, p_ln_b,
      p_mask_w1, p_mask_b1, p_mask_w2, p_mask_b2, f, score);
  k_topk<<<NB, 1024, 0, stream>>>(score, idx1, flag);
  k_offsets<<<NB*NN/256, 256, 0, stream>>>(f, p_off_w1, p_off_b1, p_off_w2, p_off_b2, offs);
  k_fmean<<<NB*NC4, 256, 0, stream>>>(f, fmean);
  k_ca<<<NB, NC, 0, stream>>>(fmean, p_ca_w, p_ca_b, ca);
  k_sa<<<dim3(NH, NB), 256, 0, stream>>>(f, p_sa_w, p_sa_b, sa);
  k_conv_mfma<<<dim3(NN/64, NB), 256, 0, stream>>>(xT, wvb, v_b, vbuf);
  k_warp_params<<<NB*NKEEP/256, 256, 0, stream>>>(idx1, offs, wpar, ipar);
  k_gather_qT<<<NB*NKEEP*24/256, 256, 0, stream>>>(xT, idx1, qin);
  k_gather_kT<<<NB*NKEEP*24/256, 256, 0, stream>>>(xT, idx1, wpar, ipar, kin);
  k_gemm_mfma<<<dim3(NKEEP/32, NB), 256, 0, stream>>>(qin, wqb, q_b, q1bf);
  k_gemm_mfma<<<dim3(NKEEP/32, NB), 256, 0, stream>>>(kin, wkb, k_b, k1bf);
  k_gather_vT<<<NB*NC*NKEEP/256, 256, 0, stream>>>(vbuf, idx1, v1T);
  k_fill<<<NB*NC*NN/256, 256, 0, stream>>>(sa, flag, vbuf);
  k_attn<<<dim3(NKEEP/64, NB, NSPLIT), 256, 0, stream>>>(q1bf, k1bf, v1T, pacc, pl);
  k_merge<<<NB*NKEEP*NC/256, 256, 0, stream>>>(pacc, pl, idx1, vbuf);
  k_dwgelu<<<NB*NC, 256, 0, stream>>>(vbuf, ca, cs_w, cs_b, out2);
  k_transpose<<<dim3(NN/32, NC/32, NB), 256, 0, stream>>>(out2, out2T);
  k_conv_mfma<<<dim3(NN/64, NB), 256, 0, stream>>>(out2T, wob, out_b, out);
}

// Round 9
// 426.767 us; speedup vs baseline: 3.2796x; 1.0150x over previous
//
#include <hip/hip_runtime.h>
#include <hip/hip_bf16.h>

#define NB   8
#define NC   192
#define NH   64
#define NW   64
#define NN   4096        // H*W
#define NCD  194         // C+2
#define NC4  48          // (C+2)/4
#define NKEEP 2048       // N*RATIO
#define NSPLIT 2         // attention K-splits
#define KPS   (NKEEP/NSPLIT)   // 1024 keys per split
#define NT    (KPS/32)         // 32 key-tiles per split

typedef __attribute__((ext_vector_type(8))) short bf16x8;  // 8 bf16 (4 VGPRs)
typedef __attribute__((ext_vector_type(4))) float f32x4;
typedef __hip_bfloat16 bf16;

__device__ __forceinline__ float dsigmoid(float x){ return 1.f/(1.f+__expf(-x)); }
__device__ __forceinline__ float dlrelu(float x){ return x>0.f ? x : 0.1f*x; }
__device__ __forceinline__ float b2f(short s){ return __uint_as_float(((unsigned)(unsigned short)s)<<16); }

// ---------------- K0: f = lrelu(LN(conv1x1(cond))), plus score ----------------
__global__ __launch_bounds__(128) void k_f_score(
    const float* __restrict__ x, const float* __restrict__ w_in, const float* __restrict__ b_in,
    const float* __restrict__ ln_w, const float* __restrict__ ln_b,
    const float* __restrict__ mw1, const float* __restrict__ mb1,
    const float* __restrict__ mw2, const float* __restrict__ mb2,
    float* __restrict__ f, float* __restrict__ score)
{
  __shared__ float wT[NCD][NC4];   // transposed weights; reads are broadcast
  int t = threadIdx.x;
  for (int i=t; i<NCD*NC4; i+=128){ int o = i/NCD, c = i - o*NCD; wT[c][o] = w_in[i]; }
  __syncthreads();

  int gid = blockIdx.x*128 + t;
  int p = gid & (NN-1), b = gid >> 12;
  int hh = p>>6, ww = p&63;

  f32x4 a4[12];
  #pragma unroll
  for (int j=0;j<12;++j) a4[j] = *(const f32x4*)(b_in + 4*j);

  const float* xb = x + (size_t)b*NC*NN + p;
  for (int c=0;c<NC;++c){
    float xv = xb[(size_t)c*NN];
    #pragma unroll
    for (int j=0;j<12;++j){ f32x4 wv = *(const f32x4*)&wT[c][4*j]; a4[j] += wv*xv; }
  }
  { float gx = -1.f + (2.f/63.f)*(float)ww;
    #pragma unroll
    for (int j=0;j<12;++j){ f32x4 wv = *(const f32x4*)&wT[192][4*j]; a4[j] += wv*gx; }
    float gy = -1.f + (2.f/63.f)*(float)hh;
    #pragma unroll
    for (int j=0;j<12;++j){ f32x4 wv = *(const f32x4*)&wT[193][4*j]; a4[j] += wv*gy; }
  }
  float s1=0.f, s2=0.f;
  #pragma unroll
  for (int j=0;j<12;++j){
    #pragma unroll
    for (int k=0;k<4;++k){ float v=a4[j][k]; s1+=v; s2+=v*v; }
  }
  float mean = s1*(1.f/NC4);
  float var  = s2*(1.f/NC4) - mean*mean;
  float rstd = rsqrtf(var + 1e-6f);
  float tsum = 0.f;
  #pragma unroll
  for (int j=0;j<12;++j){
    f32x4 lw = *(const f32x4*)(ln_w + 4*j);
    f32x4 lb = *(const f32x4*)(ln_b + 4*j);
    #pragma unroll
    for (int k=0;k<4;++k){
      float z = lw[k]*((a4[j][k]-mean)*rstd) + lb[k];
      float fv = z>0.f ? z : 0.1f*z;
      tsum += fv;
      f[((size_t)b*NC4 + 4*j+k)*NN + p] = fv;
    }
  }
  float tm = tsum*(1.f/NC4);
  float sv = dlrelu(tm*mw1[0] + mb1[0]);
  float d  = sv*(mw2[0]-mw2[1]) + (mb2[0]-mb2[1]);
  score[b*NN + p] = dsigmoid(d);
}

// ---------------- K1: per-batch top-2048 via 64-bit radix select -----------
__global__ __launch_bounds__(1024) void k_topk(const float* __restrict__ score,
                                               int* __restrict__ idx1, int* __restrict__ flag)
{
  int b = blockIdx.x;
  int t = threadIdx.x;
  __shared__ unsigned hist[256];
  __shared__ unsigned long long sP;
  __shared__ unsigned sR;
  __shared__ unsigned cnt;
  unsigned long long key[4];
  #pragma unroll
  for (int j=0;j<4;++j){
    int i = t + j*1024;
    unsigned u = __float_as_uint(score[b*NN+i]);
    unsigned a = (u & 0x80000000u) ? ~u : (u | 0x80000000u); // ascending orderable
    unsigned d = ~a;                                          // descending score
    key[j] = ((unsigned long long)d << 32) | (unsigned)i;
  }
  if (t==0){ sP=0ull; sR=NKEEP-1; cnt=0u; }
  #pragma unroll 1
  for (int pass=0; pass<8; ++pass){
    int shift = 56 - pass*8;
    if (t<256) hist[t]=0u;
    __syncthreads();
    unsigned long long P = sP;
    #pragma unroll
    for (int j=0;j<4;++j){
      bool ok = (pass==0) || ((key[j] >> (shift+8)) == (P >> (shift+8)));
      if (ok) atomicAdd(&hist[(unsigned)((key[j]>>shift)&255ull)], 1u);
    }
    __syncthreads();
    if (t < 64){
      unsigned s[4]; unsigned lsum=0u;
      #pragma unroll
      for (int j=0;j<4;++j){ s[j]=hist[4*t+j]; lsum+=s[j]; }
      unsigned incl = lsum;
      #pragma unroll
      for (int d2=1; d2<64; d2<<=1){
        unsigned v = __shfl_up(incl, d2);
        if (t >= d2) incl += v;
      }
      unsigned before = incl - lsum;
      unsigned R = sR;
      if (R >= before && R < incl){
        unsigned c = before;
        #pragma unroll
        for (int j=0;j<4;++j){
          if (R < c + s[j]){
            sP = sP | ((unsigned long long)(4u*(unsigned)t + (unsigned)j) << shift);
            sR = R - c;
            break;
          }
          c += s[j];
        }
      }
    }
    __syncthreads();
  }
  unsigned long long P = sP;
  #pragma unroll
  for (int j=0;j<4;++j){
    int i = t + j*1024;
    bool sel = (key[j] <= P);
    flag[b*NN+i] = sel ? 1 : 0;
    if (sel){
      unsigned pos = atomicAdd(&cnt, 1u);
      idx1[b*NKEEP + pos] = i;
    }
  }
}

// ---------------- K2: offsets = tanh(conv1x1(lrelu(conv1x1(f))))*8 ----------
__global__ __launch_bounds__(256) void k_offsets(
    const float* __restrict__ f, const float* __restrict__ w1, const float* __restrict__ b1,
    const float* __restrict__ w2, const float* __restrict__ b2, float* __restrict__ offs)
{
  int gid = blockIdx.x*256 + threadIdx.x;
  int p = gid & (NN-1);
  int b = gid >> 12;
  const float* fb = f + (size_t)b*NC4*NN + p;
  float fl[NC4];
  #pragma unroll 8
  for (int c=0;c<NC4;++c) fl[c] = fb[(size_t)c*NN];
  float h1[24];
  for (int o=0;o<24;++o){
    const float* wr = w1 + o*NC4;
    float a = b1[o];
    #pragma unroll 8
    for (int c=0;c<NC4;++c) a += wr[c]*fl[c];
    h1[o] = dlrelu(a);
  }
  #pragma unroll
  for (int o=0;o<2;++o){
    const float* wr = w2 + o*24;
    float a = b2[o];
    #pragma unroll
    for (int c=0;c<24;++c) a += wr[c]*h1[c];
    offs[((size_t)b*2+o)*NN + p] = tanhf(a)*8.f;
  }
}

// ---------------- K3: f spatial mean, then ca = sigmoid(fc) -----------------
__global__ __launch_bounds__(256) void k_fmean(const float* __restrict__ f, float* __restrict__ fmean){
  int bc = blockIdx.x;
  const float* p = f + (size_t)bc*NN;
  float s = 0.f;
  for (int i=threadIdx.x;i<NN;i+=256) s += p[i];
  for (int o=32;o;o>>=1) s += __shfl_xor(s,o);
  __shared__ float r[4];
  if ((threadIdx.x&63)==0) r[threadIdx.x>>6] = s;
  __syncthreads();
  if (threadIdx.x==0) fmean[bc] = (r[0]+r[1]+r[2]+r[3])*(1.f/NN);
}

__global__ void k_ca(const float* __restrict__ fmean, const float* __restrict__ w,
                     const float* __restrict__ bias, float* __restrict__ ca){
  int b = blockIdx.x, o = threadIdx.x;
  const float* fm = fmean + b*NC4;
  float a = bias[o];
  #pragma unroll 8
  for (int c=0;c<NC4;++c) a += w[o*NC4+c]*fm[c];
  ca[b*NC+o] = dsigmoid(a);
}

// ---------------- K4: sa = sigmoid(conv3x3(f, 48->1)), LDS-staged -----------
__global__ __launch_bounds__(256) void k_sa(const float* __restrict__ f, const float* __restrict__ w,
                                            const float* __restrict__ bias, float* __restrict__ sa){
  int hh = blockIdx.x;
  int b  = blockIdx.y;
  __shared__ float fl[3][NC4][66];   // 38016 B
  __shared__ float wl[NC4*9];        // 1728 B
  __shared__ float ps[4][64];        // 1024 B
  int t = threadIdx.x;

  for (int i=t; i<3*NC4*64; i+=256){
    int col = i & 63;
    int rc  = i >> 6;            // 0..143
    int cc  = rc % NC4;
    int rr  = rc / NC4;          // 0..2
    int yy  = hh + rr - 1;
    float v = (yy>=0 && yy<=63) ? f[((size_t)b*NC4+cc)*NN + yy*64 + col] : 0.f;
    fl[rr][cc][1+col] = v;
  }
  if (t < 3*NC4){ int rr=t/NC4, cc=t%NC4; fl[rr][cc][0]=0.f; fl[rr][cc][65]=0.f; }
  for (int i=t; i<NC4*9; i+=256) wl[i] = w[i];
  __syncthreads();

  int ww = t & 63, gq = t >> 6;
  float acc = 0.f;
  #pragma unroll
  for (int j=0;j<12;++j){
    int cc = gq*12 + j;
    const float* wc = &wl[cc*9];
    #pragma unroll
    for (int dy=0;dy<3;++dy){
      acc += fl[dy][cc][ww  ]*wc[dy*3+0];
      acc += fl[dy][cc][ww+1]*wc[dy*3+1];
      acc += fl[dy][cc][ww+2]*wc[dy*3+2];
    }
  }
  ps[gq][ww] = acc;
  __syncthreads();
  if (t < 64){
    float s = ps[0][t]+ps[1][t]+ps[2][t]+ps[3][t] + bias[0];
    sa[(size_t)b*NN + hh*64 + t] = dsigmoid(s);
  }
}

// ---------------- weights fp32 -> bf16 (4 matrices of 192x192) --------------
__global__ __launch_bounds__(256) void k_w2bf(const float* __restrict__ a, const float* __restrict__ b,
                                              const float* __restrict__ c, const float* __restrict__ d,
                                              bf16* __restrict__ oa, bf16* __restrict__ ob,
                                              bf16* __restrict__ oc, bf16* __restrict__ od){
  int i = blockIdx.x*256 + threadIdx.x;
  if (i < NC*NC){
    oa[i] = __float2bfloat16(a[i]);
    ob[i] = __float2bfloat16(b[i]);
    oc[i] = __float2bfloat16(c[i]);
    od[i] = __float2bfloat16(d[i]);
  }
}

// ---------------- transpose [b][c][p] fp32 -> [b][p][c] bf16 ----------------
__global__ __launch_bounds__(256) void k_transpose(const float* __restrict__ in, bf16* __restrict__ outT){
  int b = blockIdx.z;
  int c0 = blockIdx.y*32, p0 = blockIdx.x*32;
  __shared__ float tile[32][33];
  int col = threadIdx.x & 31, row8 = threadIdx.x >> 5;
  #pragma unroll
  for (int ph=0;ph<4;++ph){
    int c = c0 + ph*8 + row8;
    tile[ph*8+row8][col] = in[((size_t)b*NC + c)*NN + p0 + col];
  }
  __syncthreads();
  #pragma unroll
  for (int ph=0;ph<4;++ph){
    int p = p0 + ph*8 + row8;
    outT[((size_t)b*NN + p)*NC + c0 + col] = __float2bfloat16(tile[col][ph*8+row8]);
  }
}

// ---------------- conv1x1 via MFMA; optional fused (flag ? 1 : sa) gate -----
__global__ __launch_bounds__(256) void k_conv_mfma(const bf16* __restrict__ inT, const bf16* __restrict__ wb,
                                                   const float* __restrict__ bias, float* __restrict__ outp,
                                                   const int* __restrict__ flag, const float* __restrict__ sa){
  int b = blockIdx.y;
  int px0 = blockIdx.x*64;
  int wv = threadIdx.x>>6, lane = threadIdx.x&63, g = lane>>4, r = lane&15;
  int o0 = wv*48;
  bf16x8 bw[3][6];
  #pragma unroll
  for (int jo=0;jo<3;++jo)
    #pragma unroll
    for (int ks=0;ks<6;++ks)
      bw[jo][ks] = *(const bf16x8*)(wb + (size_t)(o0+jo*16+r)*NC + ks*32 + 8*g);
  float bv[3];
  #pragma unroll
  for (int jo=0;jo<3;++jo) bv[jo] = bias[o0+jo*16+r];

  const bf16* ib = inT + (size_t)b*NN*NC;
  #pragma unroll
  for (int t=0;t<4;++t){
    int px = px0 + t*16;
    bf16x8 a[6];
    #pragma unroll
    for (int ks=0;ks<6;++ks) a[ks] = *(const bf16x8*)(ib + (size_t)(px+r)*NC + ks*32 + 8*g);
    f32x4 acc[3];
    #pragma unroll
    for (int jo=0;jo<3;++jo){ acc[jo][0]=0.f; acc[jo][1]=0.f; acc[jo][2]=0.f; acc[jo][3]=0.f; }
    #pragma unroll
    for (int ks=0;ks<6;++ks)
      #pragma unroll
      for (int jo=0;jo<3;++jo)
        acc[jo] = __builtin_amdgcn_mfma_f32_16x16x32_bf16(a[ks], bw[jo][ks], acc[jo], 0,0,0);
    float m0=1.f, m1=1.f, m2=1.f, m3=1.f;
    if (flag){
      int pix = px + 4*g;
      int4 f4 = *(const int4*)(flag + (size_t)b*NN + pix);
      float4 s4 = *(const float4*)(sa + (size_t)b*NN + pix);
      m0 = f4.x ? 1.f : s4.x;
      m1 = f4.y ? 1.f : s4.y;
      m2 = f4.z ? 1.f : s4.z;
      m3 = f4.w ? 1.f : s4.w;
    }
    #pragma unroll
    for (int jo=0;jo<3;++jo){
      float4 rv;
      rv.x=(acc[jo][0]+bv[jo])*m0; rv.y=(acc[jo][1]+bv[jo])*m1;
      rv.z=(acc[jo][2]+bv[jo])*m2; rv.w=(acc[jo][3]+bv[jo])*m3;
      *(float4*)(outp + ((size_t)b*NC + o0+jo*16+r)*NN + px + 4*g) = rv;
    }
  }
}

// ---------------- token GEMM via MFMA: out[b][s][o] bf16 --------------------
__global__ __launch_bounds__(256) void k_gemm_mfma(const bf16* __restrict__ in, const bf16* __restrict__ wb,
                                                   const float* __restrict__ bias, bf16* __restrict__ outp){
  int b = blockIdx.y;
  int s0 = blockIdx.x*32;
  int wv = threadIdx.x>>6, lane = threadIdx.x&63, g = lane>>4, r = lane&15;
  int o0 = wv*48;
  bf16x8 bw[3][6];
  #pragma unroll
  for (int jo=0;jo<3;++jo)
    #pragma unroll
    for (int ks=0;ks<6;++ks)
      bw[jo][ks] = *(const bf16x8*)(wb + (size_t)(o0+jo*16+r)*NC + ks*32 + 8*g);
  float bv[3];
  #pragma unroll
  for (int jo=0;jo<3;++jo) bv[jo] = bias[o0+jo*16+r];

  const bf16* ib = in + (size_t)b*NKEEP*NC;
  bf16* ob = outp + (size_t)b*NKEEP*NC;
  #pragma unroll
  for (int t=0;t<2;++t){
    int s = s0 + t*16;
    bf16x8 a[6];
    #pragma unroll
    for (int ks=0;ks<6;++ks) a[ks] = *(const bf16x8*)(ib + (size_t)(s+r)*NC + ks*32 + 8*g);
    f32x4 acc[3];
    #pragma unroll
    for (int jo=0;jo<3;++jo){ acc[jo][0]=0.f; acc[jo][1]=0.f; acc[jo][2]=0.f; acc[jo][3]=0.f; }
    #pragma unroll
    for (int ks=0;ks<6;++ks)
      #pragma unroll
      for (int jo=0;jo<3;++jo)
        acc[jo] = __builtin_amdgcn_mfma_f32_16x16x32_bf16(a[ks], bw[jo][ks], acc[jo], 0,0,0);
    #pragma unroll
    for (int jo=0;jo<3;++jo)
      #pragma unroll
      for (int i=0;i<4;++i)
        ob[(size_t)(s+4*g+i)*NC + o0+jo*16+r] = __float2bfloat16(acc[jo][i]+bv[jo]);
  }
}

// ---------------- warp params per selected token ----------------------------
__global__ __launch_bounds__(256) void k_warp_params(const int* __restrict__ idx1, const float* __restrict__ offs,
                                                     float4* __restrict__ wpar, int4* __restrict__ ipar){
  int gid = blockIdx.x*256 + threadIdx.x;  // B*KEEP
  int b = gid >> 11;
  int p = idx1[gid];
  int ph = p >> 6, pwx = p & 63;
  float fx = offs[((size_t)b*2+0)*NN + p];
  float fy = offs[((size_t)b*2+1)*NN + p];
  float sx = (float)pwx + fx, sy = (float)ph + fy;
  float x0f = floorf(sx), y0f = floorf(sy);
  float wx = sx - x0f, wy = sy - y0f;
  int x0 = (int)x0f, y0 = (int)y0f;
  bool vx0 = (x0f >= 0.f) && (x0f <= 63.f);
  bool vx1 = (x0f+1.f >= 0.f) && (x0f+1.f <= 63.f);
  bool vy0 = (y0f >= 0.f) && (y0f <= 63.f);
  bool vy1 = (y0f+1.f >= 0.f) && (y0f+1.f <= 63.f);
  int cx0 = min(max(x0,0),63), cx1 = min(max(x0+1,0),63);
  int cy0 = min(max(y0,0),63), cy1 = min(max(y0+1,0),63);
  float4 w4;
  w4.x = (vx0&&vy0) ? (1.f-wx)*(1.f-wy) : 0.f;
  w4.y = (vx1&&vy0) ? wx*(1.f-wy)       : 0.f;
  w4.z = (vx0&&vy1) ? (1.f-wx)*wy       : 0.f;
  w4.w = (vx1&&vy1) ? wx*wy             : 0.f;
  int4 i4;
  i4.x = cy0*64+cx0; i4.y = cy0*64+cx1; i4.z = cy1*64+cx0; i4.w = cy1*64+cx1;
  wpar[gid]=w4; ipar[gid]=i4;
}

// ---------------- gathers from xT (token rows, vectorized) ------------------
__global__ __launch_bounds__(256) void k_gather_qT(const bf16* __restrict__ xT, const int* __restrict__ idx1,
                                                   bf16* __restrict__ qin){
  int gid = blockIdx.x*256 + threadIdx.x;   // B*KEEP*24
  int j = gid % 24;
  int bs = gid / 24;
  int b = bs >> 11;
  int p = idx1[bs];
  *(bf16x8*)(qin + (size_t)bs*NC + j*8) = *(const bf16x8*)(xT + ((size_t)b*NN + p)*NC + j*8);
}

__global__ __launch_bounds__(256) void k_gather_kT(const bf16* __restrict__ xT, const int* __restrict__ idx1,
                                                   const float4* __restrict__ wpar, const int4* __restrict__ ipar,
                                                   bf16* __restrict__ kin){
  int gid = blockIdx.x*256 + threadIdx.x;   // B*KEEP*24
  int j = gid % 24;
  int bs = gid / 24;
  int b = bs >> 11;
  int p = idx1[bs];
  float4 w4 = wpar[bs]; int4 i4 = ipar[bs];
  const bf16* xb = xT + (size_t)b*NN*NC + j*8;
  bf16x8 v0 = *(const bf16x8*)(xb + (size_t)p*NC);
  bf16x8 v1 = *(const bf16x8*)(xb + (size_t)i4.x*NC);
  bf16x8 v2 = *(const bf16x8*)(xb + (size_t)i4.y*NC);
  bf16x8 v3 = *(const bf16x8*)(xb + (size_t)i4.z*NC);
  bf16x8 v4 = *(const bf16x8*)(xb + (size_t)i4.w*NC);
  bf16x8 o;
  #pragma unroll
  for (int k=0;k<8;++k){
    float vv = b2f(v0[k]) + w4.x*b2f(v1[k]) + w4.y*b2f(v2[k]) + w4.z*b2f(v3[k]) + w4.w*b2f(v4[k]);
    bf16 h = __float2bfloat16(vv);
    o[k] = *(short*)&h;
  }
  *(bf16x8*)(kin + (size_t)bs*NC + j*8) = o;
}

__global__ __launch_bounds__(256) void k_gather_vT(const float* __restrict__ v, const int* __restrict__ idx1,
                                                   bf16* __restrict__ v1T){
  int gid = blockIdx.x*256 + threadIdx.x;
  int s = gid & (NKEEP-1);
  int bc = gid >> 11;
  int b = bc/NC;
  v1T[gid] = __float2bfloat16(v[(size_t)bc*NN + idx1[b*NKEEP+s]]);
}

// ---------------- flash attention: LDS-staged K/V, K-split x2, XCD-swizzled --
// Octet LDS layouts (conflict-free reads, bank = 4r):
//   K: [oct=ch/8][row=key][16B]  (24*32*16 = 12288 B)
//   V: [oct=key/8][ch][16B]      ( 4*192*16 = 12288 B)
// grid 1D = 512; b = id&7 pins each batch to one XCD (Q,K,V = 2.3 MB < L2).
__global__ __launch_bounds__(256) void k_attn(const bf16* __restrict__ q1, const bf16* __restrict__ k1,
                                              const bf16* __restrict__ v1T,
                                              bf16* __restrict__ pacc, float* __restrict__ pl)
{
  int id = blockIdx.x;
  int b  = id & 7;
  int t2 = id >> 3;
  int sp = t2 & (NSPLIT-1);
  int qb = t2 >> 1;               // 0..31
  int tid = threadIdx.x;
  int wv = tid >> 6;
  int lane = tid & 63;
  int g = lane >> 4, r = lane & 15;
  int q0 = qb*64 + wv*16;

  const bf16* qbp = q1 + (size_t)b*NKEEP*NC;
  const char* kgb = (const char*)(k1 + (size_t)b*NKEEP*NC);
  const char* vgb = (const char*)(v1T + (size_t)b*NC*NKEEP);

  __shared__ __align__(1024) char kl[12288];        // K tile, oct layout
  __shared__ __align__(1024) char vl[2][12288];     // V tile, oct layout, dbuf
  __shared__ __align__(16) bf16 plds[4][16][40];    // per-wave P transpose
  bf16 (* __restrict__ pw)[40] = plds[wv];
  char* klc = kl;

  int ksrc[3], vsrc[3];
  #pragma unroll
  for (int i=0;i<3;++i){
    int o = (wv*3 + i)*1024 + lane*16;
    int koct = o >> 9;                 // ch-octet 0..23
    int krow = (o >> 4) & 31;          // key row
    ksrc[i] = krow*384 + koct*16;      // + k0*384 at stage
    int voct = o / 3072;               // key-octet 0..3
    int vch  = (o - voct*3072) >> 4;   // channel 0..191
    vsrc[i] = vch*(NKEEP*2) + voct*16; // + k0*2 at stage
  }

  const int kbase = sp*KPS;
  auto stage = [&](int k0, int vb){
    char* vlc = vl[vb];
    #pragma unroll
    for (int i=0;i<3;++i){
      int j = wv*3 + i;
      __builtin_amdgcn_global_load_lds(
        (const __attribute__((address_space(1))) void*)(kgb + (size_t)k0*384 + ksrc[i]),
        (__attribute__((address_space(3))) void*)(klc + j*1024), 16, 0, 0);
      __builtin_amdgcn_global_load_lds(
        (const __attribute__((address_space(1))) void*)(vgb + (size_t)k0*2 + vsrc[i]),
        (__attribute__((address_space(3))) void*)(vlc + j*1024), 16, 0, 0);
    }
  };

  bf16x8 aq[6];
  #pragma unroll
  for (int ks=0;ks<6;++ks)
    aq[ks] = *(const bf16x8*)(qbp + (size_t)(q0+r)*NC + 32*ks + 8*g);

  f32x4 acc[12];
  #pragma unroll
  for (int i=0;i<12;++i){ acc[i][0]=0.f; acc[i][1]=0.f; acc[i][2]=0.f; acc[i][3]=0.f; }
  float l[4]={0.f,0.f,0.f,0.f};

  const float scale = 0.07216878364870323f;        // 192^-0.5
  const float shift = 20.f;                        // uniform; cancels in v/l

  stage(kbase, 0);
  __syncthreads();

  int vb = 0;
  for (int t16=0;t16<NT;++t16) {
    f32x4 s0v, s1v;
    s0v[0]=s0v[1]=s0v[2]=s0v[3]=0.f;
    s1v[0]=s1v[1]=s1v[2]=s1v[3]=0.f;
    #pragma unroll
    for (int ks=0;ks<6;++ks) {
      const char* kp = klc + (size_t)(4*ks+g)*512 + r*16;
      bf16x8 bk0 = *(const bf16x8*)(kp);
      bf16x8 bk1 = *(const bf16x8*)(kp + 256);
      s0v = __builtin_amdgcn_mfma_f32_16x16x32_bf16(aq[ks], bk0, s0v, 0,0,0);
      s1v = __builtin_amdgcn_mfma_f32_16x16x32_bf16(aq[ks], bk1, s1v, 0,0,0);
    }
    #pragma unroll
    for (int i=0;i<4;++i) {
      float e0 = __expf(s0v[i]*scale - shift);
      float e1 = __expf(s1v[i]*scale - shift);
      l[i] += e0 + e1;
      pw[4*g+i][r]    = __float2bfloat16(e0);
      pw[4*g+i][16+r] = __float2bfloat16(e1);
    }
    bf16x8 pa = *(const bf16x8*)(&pw[r][8*g]);

    __syncthreads();
    if (t16+1 < NT) stage(kbase + (t16+1)*32, vb^1);

    const char* vlc = vl[vb];
    #pragma unroll
    for (int ct=0;ct<12;++ct) {
      bf16x8 bvv = *(const bf16x8*)(vlc + g*3072 + (16*ct + r)*16);
      acc[ct] = __builtin_amdgcn_mfma_f32_16x16x32_bf16(pa, bvv, acc[ct], 0,0,0);
    }
    __syncthreads();
    vb ^= 1;
  }

  #pragma unroll
  for (int i=0;i<4;++i){
    #pragma unroll
    for (int o=1;o<16;o<<=1) l[i] += __shfl_xor(l[i],o);
  }
  size_t pbase = (((size_t)(b*32+qb)*NSPLIT + sp)*64);
  if (r==0){
    #pragma unroll
    for (int i=0;i<4;++i) pl[pbase + wv*16 + 4*g + i] = l[i];
  }
  #pragma unroll
  for (int ct=0;ct<12;++ct)
    #pragma unroll
    for (int i=0;i<4;++i)
      pacc[(pbase + wv*16 + 4*g + i)*NC + 16*ct + r] = __float2bfloat16(acc[ct][i]);
}

// ---------------- merge the NSPLIT attention partials + scatter -------------
__global__ __launch_bounds__(256) void k_merge(const bf16* __restrict__ pacc,
                                               const float* __restrict__ pl, const int* __restrict__ idx1,
                                               float* __restrict__ out_img)
{
  int gid = blockIdx.x*256 + threadIdx.x;   // B*KEEP*NC, c fastest
  int c = gid % NC;
  int bs = gid / NC;
  int s = bs & (NKEEP-1);
  int b = bs >> 11;
  int qb = s >> 6, ql = s & 63;
  size_t base = ((size_t)(b*32+qb)*NSPLIT)*64 + ql;
  float l = pl[base] + pl[base+64];
  size_t pb = base*NC + c;
  float v = __bfloat162float(pacc[pb])
          + __bfloat162float(pacc[pb + (size_t)64*NC]);
  out_img[((size_t)b*NC + c)*NN + idx1[b*NKEEP + s]] = v / l;
}

// ---------------- depthwise 3x3 + gelu*ca + residual, LDS-staged ------------
__global__ __launch_bounds__(256) void k_dwgelu(const float* __restrict__ vin, const float* __restrict__ ca,
                                                const float* __restrict__ cw, const float* __restrict__ cb,
                                                float* __restrict__ out2){
  int bc = blockIdx.x;           // b*NC + c
  int c = bc % NC, b = bc / NC;
  __shared__ float tl[66][66];   // 17424 B, zero halo
  int t = threadIdx.x;

  if (t < 66){ tl[0][t] = 0.f; tl[65][t] = 0.f; }
  if (t < 64){ tl[t+1][0] = 0.f; tl[t+1][65] = 0.f; }
  const float* ip = vin + (size_t)bc*NN;
  #pragma unroll
  for (int k=0;k<4;++k){
    int p4 = (t + k*256)*4;
    int hh = p4 >> 6, ww = p4 & 63;
    float4 v4 = *(const float4*)(ip + p4);
    tl[1+hh][1+ww  ] = v4.x;
    tl[1+hh][1+ww+1] = v4.y;
    tl[1+hh][1+ww+2] = v4.z;
    tl[1+hh][1+ww+3] = v4.w;
  }
  float wr[9];
  #pragma unroll
  for (int i=0;i<9;++i) wr[i] = cw[c*9+i];
  float cbv = cb[c];
  float cav = ca[b*NC+c];
  __syncthreads();

  float* op = out2 + (size_t)bc*NN;
  #pragma unroll
  for (int k=0;k<16;++k){
    int p = t + k*256;
    int hh = p >> 6, ww = p & 63;
    float a = cbv;
    #pragma unroll
    for (int dy=0;dy<3;++dy){
      a += tl[hh+dy][ww  ]*wr[dy*3+0];
      a += tl[hh+dy][ww+1]*wr[dy*3+1];
      a += tl[hh+dy][ww+2]*wr[dy*3+2];
    }
    float gl = 0.5f*a*(1.f+tanhf(0.79788456080286536f*(a+0.044715f*a*a*a)));
    op[p] = gl*cav + tl[1+hh][1+ww];
  }
}

// ============================================================================
extern "C" void kernel_launch(void* const* d_in, const int* in_sizes, int n_in,
                              void* d_out, int out_size, void* d_ws, size_t ws_size,
                              hipStream_t stream)
{
  const float* x       = (const float*)d_in[0];
  const float* p_in_w  = (const float*)d_in[1];
  const float* p_in_b  = (const float*)d_in[2];
  const float* p_ln_w  = (const float*)d_in[3];
  const float* p_ln_b  = (const float*)d_in[4];
  const float* p_off_w1= (const float*)d_in[5];
  const float* p_off_b1= (const float*)d_in[6];
  const float* p_off_w2= (const float*)d_in[7];
  const float* p_off_b2= (const float*)d_in[8];
  const float* p_ca_w  = (const float*)d_in[9];
  const float* p_ca_b  = (const float*)d_in[10];
  const float* p_sa_w  = (const float*)d_in[11];
  const float* p_sa_b  = (const float*)d_in[12];
  const float* p_mask_w1=(const float*)d_in[13];
  const float* p_mask_b1=(const float*)d_in[14];
  const float* p_mask_w2=(const float*)d_in[15];
  const float* p_mask_b2=(const float*)d_in[16];
  const float* v_w     = (const float*)d_in[17];
  const float* v_b     = (const float*)d_in[18];
  const float* q_w     = (const float*)d_in[19];
  const float* q_b     = (const float*)d_in[20];
  const float* k_w     = (const float*)d_in[21];
  const float* k_b     = (const float*)d_in[22];
  const float* cs_w    = (const float*)d_in[23];
  const float* cs_b    = (const float*)d_in[24];
  const float* out_w   = (const float*)d_in[25];
  const float* out_b   = (const float*)d_in[26];
  float* out = (float*)d_out;
  (void)in_sizes; (void)n_in; (void)out_size;

  char* wsp = (char*)d_ws;
  size_t off = 0;
  auto alloc = [&](size_t bytes)->char*{ char* p = wsp + off; off += (bytes + 255) & ~(size_t)255; return p; };
  float* f     = (float*)alloc((size_t)NB*NC4*NN*4);
  float* score = (float*)alloc((size_t)NB*NN*4);
  int*   idx1  = (int*)  alloc((size_t)NB*NKEEP*4);
  int*   flag  = (int*)  alloc((size_t)NB*NN*4);
  float* offs  = (float*)alloc((size_t)NB*2*NN*4);
  float* sa    = (float*)alloc((size_t)NB*NN*4);
  float* fmean = (float*)alloc((size_t)NB*NC4*4);
  float* ca    = (float*)alloc((size_t)NB*NC*4);
  float* vbuf  = (float*)alloc((size_t)NB*NC*NN*4);     // v(*sa), later out_img (in place)
  bf16*  q1bf  = (bf16*) alloc((size_t)NB*NKEEP*NC*2);
  bf16*  k1bf  = (bf16*) alloc((size_t)NB*NKEEP*NC*2);
  bf16*  v1T   = (bf16*) alloc((size_t)NB*NC*NKEEP*2);
  float4* wpar = (float4*)alloc((size_t)NB*NKEEP*16);
  int4*   ipar = (int4*) alloc((size_t)NB*NKEEP*16);
  float* out2  = (float*)alloc((size_t)NB*NC*NN*4);
  float* pl    = (float*)alloc((size_t)NB*32*NSPLIT*64*4);
  bf16*  xT    = (bf16*) alloc((size_t)NB*NN*NC*2);     // x tokens; later out2T
  bf16*  wqb   = (bf16*) alloc((size_t)NC*NC*2);
  bf16*  wkb   = (bf16*) alloc((size_t)NC*NC*2);
  bf16*  wvb   = (bf16*) alloc((size_t)NC*NC*2);
  bf16*  wob   = (bf16*) alloc((size_t)NC*NC*2);
  if (off > ws_size) return;
  // aliases inside out2 (sequentially dead):
  //   qin/kin (gathers+gemms) -> pacc (attn+merge) -> out2 fp32 (dwgelu+transpose)
  bf16* qin  = (bf16*)out2;
  bf16* kin  = qin + (size_t)NB*NKEEP*NC;
  bf16* pacc = (bf16*)out2;
  bf16* out2T = xT;   // xT dead after gather_kT

  k_w2bf<<<(NC*NC+255)/256, 256, 0, stream>>>(q_w, k_w, v_w, out_w, wqb, wkb, wvb, wob);
  k_transpose<<<dim3(NN/32, NC/32, NB), 256, 0, stream>>>(x, xT);
  k_f_score<<<NB*NN/128, 128, 0, stream>>>(x, p_in_w, p_in_b, p_ln_w, p_ln_b,
      p_mask_w1, p_mask_b1, p_mask_w2, p_mask_b2, f, score);
  k_topk<<<NB, 1024, 0, stream>>>(score, idx1, flag);
  k_offsets<<<NB*NN/256, 256, 0, stream>>>(f, p_off_w1, p_off_b1, p_off_w2, p_off_b2, offs);
  k_fmean<<<NB*NC4, 256, 0, stream>>>(f, fmean);
  k_ca<<<NB, NC, 0, stream>>>(fmean, p_ca_w, p_ca_b, ca);
  k_sa<<<dim3(NH, NB), 256, 0, stream>>>(f, p_sa_w, p_sa_b, sa);
  k_conv_mfma<<<dim3(NN/64, NB), 256, 0, stream>>>(xT, wvb, v_b, vbuf, flag, sa);
  k_warp_params<<<NB*NKEEP/256, 256, 0, stream>>>(idx1, offs, wpar, ipar);
  k_gather_qT<<<NB*NKEEP*24/256, 256, 0, stream>>>(xT, idx1, qin);
  k_gather_kT<<<NB*NKEEP*24/256, 256, 0, stream>>>(xT, idx1, wpar, ipar, kin);
  k_gemm_mfma<<<dim3(NKEEP/32, NB), 256, 0, stream>>>(qin, wqb, q_b, q1bf);
  k_gemm_mfma<<<dim3(NKEEP/32, NB), 256, 0, stream>>>(kin, wkb, k_b, k1bf);
  k_gather_vT<<<NB*NC*NKEEP/256, 256, 0, stream>>>(vbuf, idx1, v1T);
  k_attn<<<NB*NSPLIT*32, 256, 0, stream>>>(q1bf, k1bf, v1T, pacc, pl);
  k_merge<<<NB*NKEEP*NC/256, 256, 0, stream>>>(pacc, pl, idx1, vbuf);
  k_dwgelu<<<NB*NC, 256, 0, stream>>>(vbuf, ca, cs_w, cs_b, out2);
  k_transpose<<<dim3(NN/32, NC/32, NB), 256, 0, stream>>>(out2, out2T);
  k_conv_mfma<<<dim3(NN/64, NB), 256, 0, stream>>>(out2T, wob, out_b, out, nullptr, nullptr);
}

// Round 10
// 420.695 us; speedup vs baseline: 3.3270x; 1.0144x over previous
//
#include <hip/hip_runtime.h>
#include <hip/hip_bf16.h>

#define NB   8
#define NC   192
#define NH   64
#define NW   64
#define NN   4096        // H*W
#define NCD  194         // C+2
#define NC4  48          // (C+2)/4
#define NKEEP 2048       // N*RATIO
#define NSPLIT 4         // attention K-splits
#define KPS   (NKEEP/NSPLIT)   // 512 keys per split
#define NT    (KPS/32)         // 16 key-tiles per split

typedef __attribute__((ext_vector_type(8))) short bf16x8;  // 8 bf16 (4 VGPRs)
typedef __attribute__((ext_vector_type(4))) float f32x4;
typedef __hip_bfloat16 bf16;

__device__ __forceinline__ float dsigmoid(float x){ return 1.f/(1.f+__expf(-x)); }
__device__ __forceinline__ float dlrelu(float x){ return x>0.f ? x : 0.1f*x; }
__device__ __forceinline__ float b2f(short s){ return __uint_as_float(((unsigned)(unsigned short)s)<<16); }

// ---------------- K0: f = lrelu(LN(conv1x1(cond))), plus score ----------------
__global__ __launch_bounds__(128) void k_f_score(
    const float* __restrict__ x, const float* __restrict__ w_in, const float* __restrict__ b_in,
    const float* __restrict__ ln_w, const float* __restrict__ ln_b,
    const float* __restrict__ mw1, const float* __restrict__ mb1,
    const float* __restrict__ mw2, const float* __restrict__ mb2,
    float* __restrict__ f, float* __restrict__ score)
{
  __shared__ float wT[NCD][NC4];   // transposed weights; reads are broadcast
  int t = threadIdx.x;
  for (int i=t; i<NCD*NC4; i+=128){ int o = i/NCD, c = i - o*NCD; wT[c][o] = w_in[i]; }
  __syncthreads();

  int gid = blockIdx.x*128 + t;
  int p = gid & (NN-1), b = gid >> 12;
  int hh = p>>6, ww = p&63;

  f32x4 a4[12];
  #pragma unroll
  for (int j=0;j<12;++j) a4[j] = *(const f32x4*)(b_in + 4*j);

  const float* xb = x + (size_t)b*NC*NN + p;
  for (int c=0;c<NC;++c){
    float xv = xb[(size_t)c*NN];
    #pragma unroll
    for (int j=0;j<12;++j){ f32x4 wv = *(const f32x4*)&wT[c][4*j]; a4[j] += wv*xv; }
  }
  { float gx = -1.f + (2.f/63.f)*(float)ww;
    #pragma unroll
    for (int j=0;j<12;++j){ f32x4 wv = *(const f32x4*)&wT[192][4*j]; a4[j] += wv*gx; }
    float gy = -1.f + (2.f/63.f)*(float)hh;
    #pragma unroll
    for (int j=0;j<12;++j){ f32x4 wv = *(const f32x4*)&wT[193][4*j]; a4[j] += wv*gy; }
  }
  float s1=0.f, s2=0.f;
  #pragma unroll
  for (int j=0;j<12;++j){
    #pragma unroll
    for (int k=0;k<4;++k){ float v=a4[j][k]; s1+=v; s2+=v*v; }
  }
  float mean = s1*(1.f/NC4);
  float var  = s2*(1.f/NC4) - mean*mean;
  float rstd = rsqrtf(var + 1e-6f);
  float tsum = 0.f;
  #pragma unroll
  for (int j=0;j<12;++j){
    f32x4 lw = *(const f32x4*)(ln_w + 4*j);
    f32x4 lb = *(const f32x4*)(ln_b + 4*j);
    #pragma unroll
    for (int k=0;k<4;++k){
      float z = lw[k]*((a4[j][k]-mean)*rstd) + lb[k];
      float fv = z>0.f ? z : 0.1f*z;
      tsum += fv;
      f[((size_t)b*NC4 + 4*j+k)*NN + p] = fv;
    }
  }
  float tm = tsum*(1.f/NC4);
  float sv = dlrelu(tm*mw1[0] + mb1[0]);
  float d  = sv*(mw2[0]-mw2[1]) + (mb2[0]-mb2[1]);
  score[b*NN + p] = dsigmoid(d);
}

// ---------------- K1: per-batch top-2048 via 64-bit radix select -----------
__global__ __launch_bounds__(1024) void k_topk(const float* __restrict__ score,
                                               int* __restrict__ idx1, int* __restrict__ flag)
{
  int b = blockIdx.x;
  int t = threadIdx.x;
  __shared__ unsigned hist[256];
  __shared__ unsigned long long sP;
  __shared__ unsigned sR;
  __shared__ unsigned cnt;
  unsigned long long key[4];
  #pragma unroll
  for (int j=0;j<4;++j){
    int i = t + j*1024;
    unsigned u = __float_as_uint(score[b*NN+i]);
    unsigned a = (u & 0x80000000u) ? ~u : (u | 0x80000000u); // ascending orderable
    unsigned d = ~a;                                          // descending score
    key[j] = ((unsigned long long)d << 32) | (unsigned)i;
  }
  if (t==0){ sP=0ull; sR=NKEEP-1; cnt=0u; }
  #pragma unroll 1
  for (int pass=0; pass<8; ++pass){
    int shift = 56 - pass*8;
    if (t<256) hist[t]=0u;
    __syncthreads();
    unsigned long long P = sP;
    #pragma unroll
    for (int j=0;j<4;++j){
      bool ok = (pass==0) || ((key[j] >> (shift+8)) == (P >> (shift+8)));
      if (ok) atomicAdd(&hist[(unsigned)((key[j]>>shift)&255ull)], 1u);
    }
    __syncthreads();
    if (t < 64){
      unsigned s[4]; unsigned lsum=0u;
      #pragma unroll
      for (int j=0;j<4;++j){ s[j]=hist[4*t+j]; lsum+=s[j]; }
      unsigned incl = lsum;
      #pragma unroll
      for (int d2=1; d2<64; d2<<=1){
        unsigned v = __shfl_up(incl, d2);
        if (t >= d2) incl += v;
      }
      unsigned before = incl - lsum;
      unsigned R = sR;
      if (R >= before && R < incl){
        unsigned c = before;
        #pragma unroll
        for (int j=0;j<4;++j){
          if (R < c + s[j]){
            sP = sP | ((unsigned long long)(4u*(unsigned)t + (unsigned)j) << shift);
            sR = R - c;
            break;
          }
          c += s[j];
        }
      }
    }
    __syncthreads();
  }
  unsigned long long P = sP;
  #pragma unroll
  for (int j=0;j<4;++j){
    int i = t + j*1024;
    bool sel = (key[j] <= P);
    flag[b*NN+i] = sel ? 1 : 0;
    if (sel){
      unsigned pos = atomicAdd(&cnt, 1u);
      idx1[b*NKEEP + pos] = i;
    }
  }
}

// ---------------- K2: offsets = tanh(conv1x1(lrelu(conv1x1(f))))*8 ----------
__global__ __launch_bounds__(256) void k_offsets(
    const float* __restrict__ f, const float* __restrict__ w1, const float* __restrict__ b1,
    const float* __restrict__ w2, const float* __restrict__ b2, float* __restrict__ offs)
{
  int gid = blockIdx.x*256 + threadIdx.x;
  int p = gid & (NN-1);
  int b = gid >> 12;
  const float* fb = f + (size_t)b*NC4*NN + p;
  float fl[NC4];
  #pragma unroll 8
  for (int c=0;c<NC4;++c) fl[c] = fb[(size_t)c*NN];
  float h1[24];
  for (int o=0;o<24;++o){
    const float* wr = w1 + o*NC4;
    float a = b1[o];
    #pragma unroll 8
    for (int c=0;c<NC4;++c) a += wr[c]*fl[c];
    h1[o] = dlrelu(a);
  }
  #pragma unroll
  for (int o=0;o<2;++o){
    const float* wr = w2 + o*24;
    float a = b2[o];
    #pragma unroll
    for (int c=0;c<24;++c) a += wr[c]*h1[c];
    offs[((size_t)b*2+o)*NN + p] = tanhf(a)*8.f;
  }
}

// ---------------- K3: f spatial mean, then ca = sigmoid(fc) -----------------
__global__ __launch_bounds__(256) void k_fmean(const float* __restrict__ f, float* __restrict__ fmean){
  int bc = blockIdx.x;
  const float* p = f + (size_t)bc*NN;
  float s = 0.f;
  for (int i=threadIdx.x;i<NN;i+=256) s += p[i];
  for (int o=32;o;o>>=1) s += __shfl_xor(s,o);
  __shared__ float r[4];
  if ((threadIdx.x&63)==0) r[threadIdx.x>>6] = s;
  __syncthreads();
  if (threadIdx.x==0) fmean[bc] = (r[0]+r[1]+r[2]+r[3])*(1.f/NN);
}

__global__ void k_ca(const float* __restrict__ fmean, const float* __restrict__ w,
                     const float* __restrict__ bias, float* __restrict__ ca){
  int b = blockIdx.x, o = threadIdx.x;
  const float* fm = fmean + b*NC4;
  float a = bias[o];
  #pragma unroll 8
  for (int c=0;c<NC4;++c) a += w[o*NC4+c]*fm[c];
  ca[b*NC+o] = dsigmoid(a);
}

// ---------------- K4: sa = sigmoid(conv3x3(f, 48->1)), LDS-staged -----------
__global__ __launch_bounds__(256) void k_sa(const float* __restrict__ f, const float* __restrict__ w,
                                            const float* __restrict__ bias, float* __restrict__ sa){
  int hh = blockIdx.x;
  int b  = blockIdx.y;
  __shared__ float fl[3][NC4][66];   // 38016 B
  __shared__ float wl[NC4*9];        // 1728 B
  __shared__ float ps[4][64];        // 1024 B
  int t = threadIdx.x;

  for (int i=t; i<3*NC4*64; i+=256){
    int col = i & 63;
    int rc  = i >> 6;            // 0..143
    int cc  = rc % NC4;
    int rr  = rc / NC4;          // 0..2
    int yy  = hh + rr - 1;
    float v = (yy>=0 && yy<=63) ? f[((size_t)b*NC4+cc)*NN + yy*64 + col] : 0.f;
    fl[rr][cc][1+col] = v;
  }
  if (t < 3*NC4){ int rr=t/NC4, cc=t%NC4; fl[rr][cc][0]=0.f; fl[rr][cc][65]=0.f; }
  for (int i=t; i<NC4*9; i+=256) wl[i] = w[i];
  __syncthreads();

  int ww = t & 63, gq = t >> 6;
  float acc = 0.f;
  #pragma unroll
  for (int j=0;j<12;++j){
    int cc = gq*12 + j;
    const float* wc = &wl[cc*9];
    #pragma unroll
    for (int dy=0;dy<3;++dy){
      acc += fl[dy][cc][ww  ]*wc[dy*3+0];
      acc += fl[dy][cc][ww+1]*wc[dy*3+1];
      acc += fl[dy][cc][ww+2]*wc[dy*3+2];
    }
  }
  ps[gq][ww] = acc;
  __syncthreads();
  if (t < 64){
    float s = ps[0][t]+ps[1][t]+ps[2][t]+ps[3][t] + bias[0];
    sa[(size_t)b*NN + hh*64 + t] = dsigmoid(s);
  }
}

// ---------------- weights fp32 -> bf16 (4 matrices of 192x192) --------------
__global__ __launch_bounds__(256) void k_w2bf(const float* __restrict__ a, const float* __restrict__ b,
                                              const float* __restrict__ c, const float* __restrict__ d,
                                              bf16* __restrict__ oa, bf16* __restrict__ ob,
                                              bf16* __restrict__ oc, bf16* __restrict__ od){
  int i = blockIdx.x*256 + threadIdx.x;
  if (i < NC*NC){
    oa[i] = __float2bfloat16(a[i]);
    ob[i] = __float2bfloat16(b[i]);
    oc[i] = __float2bfloat16(c[i]);
    od[i] = __float2bfloat16(d[i]);
  }
}

// ---------------- transpose [b][c][p] fp32 -> [b][p][c] bf16 ----------------
__global__ __launch_bounds__(256) void k_transpose(const float* __restrict__ in, bf16* __restrict__ outT){
  int b = blockIdx.z;
  int c0 = blockIdx.y*32, p0 = blockIdx.x*32;
  __shared__ float tile[32][33];
  int col = threadIdx.x & 31, row8 = threadIdx.x >> 5;
  #pragma unroll
  for (int ph=0;ph<4;++ph){
    int c = c0 + ph*8 + row8;
    tile[ph*8+row8][col] = in[((size_t)b*NC + c)*NN + p0 + col];
  }
  __syncthreads();
  #pragma unroll
  for (int ph=0;ph<4;++ph){
    int p = p0 + ph*8 + row8;
    outT[((size_t)b*NN + p)*NC + c0 + col] = __float2bfloat16(tile[col][ph*8+row8]);
  }
}

// ---------------- conv1x1 via MFMA; optional fused (flag ? 1 : sa) gate -----
__global__ __launch_bounds__(256) void k_conv_mfma(const bf16* __restrict__ inT, const bf16* __restrict__ wb,
                                                   const float* __restrict__ bias, float* __restrict__ outp,
                                                   const int* __restrict__ flag, const float* __restrict__ sa){
  int b = blockIdx.y;
  int px0 = blockIdx.x*64;
  int wv = threadIdx.x>>6, lane = threadIdx.x&63, g = lane>>4, r = lane&15;
  int o0 = wv*48;
  bf16x8 bw[3][6];
  #pragma unroll
  for (int jo=0;jo<3;++jo)
    #pragma unroll
    for (int ks=0;ks<6;++ks)
      bw[jo][ks] = *(const bf16x8*)(wb + (size_t)(o0+jo*16+r)*NC + ks*32 + 8*g);
  float bv[3];
  #pragma unroll
  for (int jo=0;jo<3;++jo) bv[jo] = bias[o0+jo*16+r];

  const bf16* ib = inT + (size_t)b*NN*NC;
  #pragma unroll
  for (int t=0;t<4;++t){
    int px = px0 + t*16;
    bf16x8 a[6];
    #pragma unroll
    for (int ks=0;ks<6;++ks) a[ks] = *(const bf16x8*)(ib + (size_t)(px+r)*NC + ks*32 + 8*g);
    f32x4 acc[3];
    #pragma unroll
    for (int jo=0;jo<3;++jo){ acc[jo][0]=0.f; acc[jo][1]=0.f; acc[jo][2]=0.f; acc[jo][3]=0.f; }
    #pragma unroll
    for (int ks=0;ks<6;++ks)
      #pragma unroll
      for (int jo=0;jo<3;++jo)
        acc[jo] = __builtin_amdgcn_mfma_f32_16x16x32_bf16(a[ks], bw[jo][ks], acc[jo], 0,0,0);
    float m0=1.f, m1=1.f, m2=1.f, m3=1.f;
    if (flag){
      int pix = px + 4*g;
      int4 f4 = *(const int4*)(flag + (size_t)b*NN + pix);
      float4 s4 = *(const float4*)(sa + (size_t)b*NN + pix);
      m0 = f4.x ? 1.f : s4.x;
      m1 = f4.y ? 1.f : s4.y;
      m2 = f4.z ? 1.f : s4.z;
      m3 = f4.w ? 1.f : s4.w;
    }
    #pragma unroll
    for (int jo=0;jo<3;++jo){
      float4 rv;
      rv.x=(acc[jo][0]+bv[jo])*m0; rv.y=(acc[jo][1]+bv[jo])*m1;
      rv.z=(acc[jo][2]+bv[jo])*m2; rv.w=(acc[jo][3]+bv[jo])*m3;
      *(float4*)(outp + ((size_t)b*NC + o0+jo*16+r)*NN + px + 4*g) = rv;
    }
  }
}

// ---------------- token GEMM via MFMA: out[b][s][o] bf16 --------------------
__global__ __launch_bounds__(256) void k_gemm_mfma(const bf16* __restrict__ in, const bf16* __restrict__ wb,
                                                   const float* __restrict__ bias, bf16* __restrict__ outp){
  int b = blockIdx.y;
  int s0 = blockIdx.x*32;
  int wv = threadIdx.x>>6, lane = threadIdx.x&63, g = lane>>4, r = lane&15;
  int o0 = wv*48;
  bf16x8 bw[3][6];
  #pragma unroll
  for (int jo=0;jo<3;++jo)
    #pragma unroll
    for (int ks=0;ks<6;++ks)
      bw[jo][ks] = *(const bf16x8*)(wb + (size_t)(o0+jo*16+r)*NC + ks*32 + 8*g);
  float bv[3];
  #pragma unroll
  for (int jo=0;jo<3;++jo) bv[jo] = bias[o0+jo*16+r];

  const bf16* ib = in + (size_t)b*NKEEP*NC;
  bf16* ob = outp + (size_t)b*NKEEP*NC;
  #pragma unroll
  for (int t=0;t<2;++t){
    int s = s0 + t*16;
    bf16x8 a[6];
    #pragma unroll
    for (int ks=0;ks<6;++ks) a[ks] = *(const bf16x8*)(ib + (size_t)(s+r)*NC + ks*32 + 8*g);
    f32x4 acc[3];
    #pragma unroll
    for (int jo=0;jo<3;++jo){ acc[jo][0]=0.f; acc[jo][1]=0.f; acc[jo][2]=0.f; acc[jo][3]=0.f; }
    #pragma unroll
    for (int ks=0;ks<6;++ks)
      #pragma unroll
      for (int jo=0;jo<3;++jo)
        acc[jo] = __builtin_amdgcn_mfma_f32_16x16x32_bf16(a[ks], bw[jo][ks], acc[jo], 0,0,0);
    #pragma unroll
    for (int jo=0;jo<3;++jo)
      #pragma unroll
      for (int i=0;i<4;++i)
        ob[(size_t)(s+4*g+i)*NC + o0+jo*16+r] = __float2bfloat16(acc[jo][i]+bv[jo]);
  }
}

// ---------------- warp params per selected token ----------------------------
__global__ __launch_bounds__(256) void k_warp_params(const int* __restrict__ idx1, const float* __restrict__ offs,
                                                     float4* __restrict__ wpar, int4* __restrict__ ipar){
  int gid = blockIdx.x*256 + threadIdx.x;  // B*KEEP
  int b = gid >> 11;
  int p = idx1[gid];
  int ph = p >> 6, pwx = p & 63;
  float fx = offs[((size_t)b*2+0)*NN + p];
  float fy = offs[((size_t)b*2+1)*NN + p];
  float sx = (float)pwx + fx, sy = (float)ph + fy;
  float x0f = floorf(sx), y0f = floorf(sy);
  float wx = sx - x0f, wy = sy - y0f;
  int x0 = (int)x0f, y0 = (int)y0f;
  bool vx0 = (x0f >= 0.f) && (x0f <= 63.f);
  bool vx1 = (x0f+1.f >= 0.f) && (x0f+1.f <= 63.f);
  bool vy0 = (y0f >= 0.f) && (y0f <= 63.f);
  bool vy1 = (y0f+1.f >= 0.f) && (y0f+1.f <= 63.f);
  int cx0 = min(max(x0,0),63), cx1 = min(max(x0+1,0),63);
  int cy0 = min(max(y0,0),63), cy1 = min(max(y0+1,0),63);
  float4 w4;
  w4.x = (vx0&&vy0) ? (1.f-wx)*(1.f-wy) : 0.f;
  w4.y = (vx1&&vy0) ? wx*(1.f-wy)       : 0.f;
  w4.z = (vx0&&vy1) ? (1.f-wx)*wy       : 0.f;
  w4.w = (vx1&&vy1) ? wx*wy             : 0.f;
  int4 i4;
  i4.x = cy0*64+cx0; i4.y = cy0*64+cx1; i4.z = cy1*64+cx0; i4.w = cy1*64+cx1;
  wpar[gid]=w4; ipar[gid]=i4;
}

// ---------------- gathers from xT (token rows, vectorized) ------------------
__global__ __launch_bounds__(256) void k_gather_qT(const bf16* __restrict__ xT, const int* __restrict__ idx1,
                                                   bf16* __restrict__ qin){
  int gid = blockIdx.x*256 + threadIdx.x;   // B*KEEP*24
  int j = gid % 24;
  int bs = gid / 24;
  int b = bs >> 11;
  int p = idx1[bs];
  *(bf16x8*)(qin + (size_t)bs*NC + j*8) = *(const bf16x8*)(xT + ((size_t)b*NN + p)*NC + j*8);
}

__global__ __launch_bounds__(256) void k_gather_kT(const bf16* __restrict__ xT, const int* __restrict__ idx1,
                                                   const float4* __restrict__ wpar, const int4* __restrict__ ipar,
                                                   bf16* __restrict__ kin){
  int gid = blockIdx.x*256 + threadIdx.x;   // B*KEEP*24
  int j = gid % 24;
  int bs = gid / 24;
  int b = bs >> 11;
  int p = idx1[bs];
  float4 w4 = wpar[bs]; int4 i4 = ipar[bs];
  const bf16* xb = xT + (size_t)b*NN*NC + j*8;
  bf16x8 v0 = *(const bf16x8*)(xb + (size_t)p*NC);
  bf16x8 v1 = *(const bf16x8*)(xb + (size_t)i4.x*NC);
  bf16x8 v2 = *(const bf16x8*)(xb + (size_t)i4.y*NC);
  bf16x8 v3 = *(const bf16x8*)(xb + (size_t)i4.z*NC);
  bf16x8 v4 = *(const bf16x8*)(xb + (size_t)i4.w*NC);
  bf16x8 o;
  #pragma unroll
  for (int k=0;k<8;++k){
    float vv = b2f(v0[k]) + w4.x*b2f(v1[k]) + w4.y*b2f(v2[k]) + w4.z*b2f(v3[k]) + w4.w*b2f(v4[k]);
    bf16 h = __float2bfloat16(vv);
    o[k] = *(short*)&h;
  }
  *(bf16x8*)(kin + (size_t)bs*NC + j*8) = o;
}

__global__ __launch_bounds__(256) void k_gather_vT(const float* __restrict__ v, const int* __restrict__ idx1,
                                                   bf16* __restrict__ v1T){
  int gid = blockIdx.x*256 + threadIdx.x;
  int s = gid & (NKEEP-1);
  int bc = gid >> 11;
  int b = bc/NC;
  v1T[gid] = __float2bfloat16(v[(size_t)bc*NN + idx1[b*NKEEP+s]]);
}

// ---------------- flash attention: single-buffer K/V rotating stage ---------
// Octet LDS layouts (conflict-free reads, bank = 4r):
//   K: [oct=ch/8][row=key][16B]  (24*32*16 = 12288 B)
//   V: [oct=key/8][ch][16B]      ( 4*192*16 = 12288 B)
// Schedule per tile: QK(kl) -> exp/P -> bar1 -> stageK(t+1) -> PV(vl) ->
// bar2 -> stageV(t+1).  stageK hidden by PV, stageV hidden by next QK+exp;
// each drained by the next barrier's vmcnt(0).  LDS 29.7 KB -> 5 blocks/CU;
// grid 1024 (XCD-pinned, 4/CU resident, 16 waves/CU).
__global__ __launch_bounds__(256) void k_attn(const bf16* __restrict__ q1, const bf16* __restrict__ k1,
                                              const bf16* __restrict__ v1T,
                                              bf16* __restrict__ pacc, float* __restrict__ pl)
{
  int id = blockIdx.x;
  int b  = id & 7;                // pin batch -> XCD (Q,K,V ~2.3 MB < 4 MB L2)
  int t2 = id >> 3;               // 0..127
  int sp = t2 & (NSPLIT-1);       // 0..3
  int qb = t2 >> 2;               // 0..31
  int tid = threadIdx.x;
  int wv = tid >> 6;
  int lane = tid & 63;
  int g = lane >> 4, r = lane & 15;
  int q0 = qb*64 + wv*16;

  const bf16* qbp = q1 + (size_t)b*NKEEP*NC;
  const char* kgb = (const char*)(k1 + (size_t)b*NKEEP*NC);
  const char* vgb = (const char*)(v1T + (size_t)b*NC*NKEEP);

  __shared__ __align__(1024) char kl[12288];        // K tile, oct layout
  __shared__ __align__(1024) char vl[12288];        // V tile, oct layout
  __shared__ __align__(16) bf16 plds[4][16][40];    // per-wave P transpose
  bf16 (* __restrict__ pw)[40] = plds[wv];

  int ksrc[3], vsrc[3];
  #pragma unroll
  for (int i=0;i<3;++i){
    int o = (wv*3 + i)*1024 + lane*16;
    int koct = o >> 9;                 // ch-octet 0..23
    int krow = (o >> 4) & 31;          // key row
    ksrc[i] = krow*384 + koct*16;      // + k0*384 at stage
    int voct = o / 3072;               // key-octet 0..3
    int vch  = (o - voct*3072) >> 4;   // channel 0..191
    vsrc[i] = vch*(NKEEP*2) + voct*16; // + k0*2 at stage
  }

  const int kbase = sp*KPS;
  auto stageK = [&](int k0){
    #pragma unroll
    for (int i=0;i<3;++i){
      int j = wv*3 + i;
      __builtin_amdgcn_global_load_lds(
        (const __attribute__((address_space(1))) void*)(kgb + (size_t)k0*384 + ksrc[i]),
        (__attribute__((address_space(3))) void*)(kl + j*1024), 16, 0, 0);
    }
  };
  auto stageV = [&](int k0){
    #pragma unroll
    for (int i=0;i<3;++i){
      int j = wv*3 + i;
      __builtin_amdgcn_global_load_lds(
        (const __attribute__((address_space(1))) void*)(vgb + (size_t)k0*2 + vsrc[i]),
        (__attribute__((address_space(3))) void*)(vl + j*1024), 16, 0, 0);
    }
  };

  bf16x8 aq[6];
  #pragma unroll
  for (int ks=0;ks<6;++ks)
    aq[ks] = *(const bf16x8*)(qbp + (size_t)(q0+r)*NC + 32*ks + 8*g);

  f32x4 acc[12];
  #pragma unroll
  for (int i=0;i<12;++i){ acc[i][0]=0.f; acc[i][1]=0.f; acc[i][2]=0.f; acc[i][3]=0.f; }
  float l[4]={0.f,0.f,0.f,0.f};

  const float scale = 0.07216878364870323f;        // 192^-0.5
  const float shift = 20.f;                        // uniform; cancels in v/l

  stageK(kbase);
  stageV(kbase);
  __syncthreads();

  for (int t16=0;t16<NT;++t16) {
    // ---- QK^T from kl: 4 independent 3-MFMA chains ----
    f32x4 s0a, s0b, s1a, s1b;
    s0a[0]=s0a[1]=s0a[2]=s0a[3]=0.f; s0b=s0a; s1a=s0a; s1b=s0a;
    #pragma unroll
    for (int ks=0;ks<3;++ks) {
      const char* kp = kl + (size_t)(4*ks+g)*512 + r*16;
      bf16x8 bk0 = *(const bf16x8*)(kp);
      bf16x8 bk1 = *(const bf16x8*)(kp + 256);
      s0a = __builtin_amdgcn_mfma_f32_16x16x32_bf16(aq[ks], bk0, s0a, 0,0,0);
      s1a = __builtin_amdgcn_mfma_f32_16x16x32_bf16(aq[ks], bk1, s1a, 0,0,0);
    }
    #pragma unroll
    for (int ks=3;ks<6;++ks) {
      const char* kp = kl + (size_t)(4*ks+g)*512 + r*16;
      bf16x8 bk0 = *(const bf16x8*)(kp);
      bf16x8 bk1 = *(const bf16x8*)(kp + 256);
      s0b = __builtin_amdgcn_mfma_f32_16x16x32_bf16(aq[ks], bk0, s0b, 0,0,0);
      s1b = __builtin_amdgcn_mfma_f32_16x16x32_bf16(aq[ks], bk1, s1b, 0,0,0);
    }
    f32x4 s0v = s0a + s0b, s1v = s1a + s1b;
    #pragma unroll
    for (int i=0;i<4;++i) {
      float e0 = __expf(s0v[i]*scale - shift);
      float e1 = __expf(s1v[i]*scale - shift);
      l[i] += e0 + e1;
      pw[4*g+i][r]    = __float2bfloat16(e0);
      pw[4*g+i][16+r] = __float2bfloat16(e1);
    }
    bf16x8 pa = *(const bf16x8*)(&pw[r][8*g]);

    __syncthreads();                    // waves done with kl; drains stageV(t)
    if (t16+1 < NT) stageK(kbase + (t16+1)*32);   // hidden by PV

    #pragma unroll
    for (int ct=0;ct<12;++ct) {
      bf16x8 bvv = *(const bf16x8*)(vl + g*3072 + (16*ct + r)*16);
      acc[ct] = __builtin_amdgcn_mfma_f32_16x16x32_bf16(pa, bvv, acc[ct], 0,0,0);
    }
    __syncthreads();                    // waves done with vl; drains stageK(t+1)
    if (t16+1 < NT) stageV(kbase + (t16+1)*32);   // hidden by next QK+exp
  }

  #pragma unroll
  for (int i=0;i<4;++i){
    #pragma unroll
    for (int o=1;o<16;o<<=1) l[i] += __shfl_xor(l[i],o);
  }
  size_t pbase = (((size_t)(b*32+qb)*NSPLIT + sp)*64);
  if (r==0){
    #pragma unroll
    for (int i=0;i<4;++i) pl[pbase + wv*16 + 4*g + i] = l[i];
  }
  #pragma unroll
  for (int ct=0;ct<12;++ct)
    #pragma unroll
    for (int i=0;i<4;++i)
      pacc[(pbase + wv*16 + 4*g + i)*NC + 16*ct + r] = __float2bfloat16(acc[ct][i]);
}

// ---------------- merge the NSPLIT attention partials + scatter -------------
__global__ __launch_bounds__(256) void k_merge(const bf16* __restrict__ pacc,
                                               const float* __restrict__ pl, const int* __restrict__ idx1,
                                               float* __restrict__ out_img)
{
  int gid = blockIdx.x*256 + threadIdx.x;   // B*KEEP*NC, c fastest
  int c = gid % NC;
  int bs = gid / NC;
  int s = bs & (NKEEP-1);
  int b = bs >> 11;
  int qb = s >> 6, ql = s & 63;
  size_t base = ((size_t)(b*32+qb)*NSPLIT)*64 + ql;
  float l = pl[base] + pl[base+64] + pl[base+128] + pl[base+192];
  size_t pb = base*NC + c;
  float v = __bfloat162float(pacc[pb])
          + __bfloat162float(pacc[pb + (size_t)64*NC])
          + __bfloat162float(pacc[pb + (size_t)128*NC])
          + __bfloat162float(pacc[pb + (size_t)192*NC]);
  out_img[((size_t)b*NC + c)*NN + idx1[b*NKEEP + s]] = v / l;
}

// ---------------- depthwise 3x3 + gelu*ca + residual, LDS-staged ------------
__global__ __launch_bounds__(256) void k_dwgelu(const float* __restrict__ vin, const float* __restrict__ ca,
                                                const float* __restrict__ cw, const float* __restrict__ cb,
                                                float* __restrict__ out2){
  int bc = blockIdx.x;           // b*NC + c
  int c = bc % NC, b = bc / NC;
  __shared__ float tl[66][66];   // 17424 B, zero halo
  int t = threadIdx.x;

  if (t < 66){ tl[0][t] = 0.f; tl[65][t] = 0.f; }
  if (t < 64){ tl[t+1][0] = 0.f; tl[t+1][65] = 0.f; }
  const float* ip = vin + (size_t)bc*NN;
  #pragma unroll
  for (int k=0;k<4;++k){
    int p4 = (t + k*256)*4;
    int hh = p4 >> 6, ww = p4 & 63;
    float4 v4 = *(const float4*)(ip + p4);
    tl[1+hh][1+ww  ] = v4.x;
    tl[1+hh][1+ww+1] = v4.y;
    tl[1+hh][1+ww+2] = v4.z;
    tl[1+hh][1+ww+3] = v4.w;
  }
  float wr[9];
  #pragma unroll
  for (int i=0;i<9;++i) wr[i] = cw[c*9+i];
  float cbv = cb[c];
  float cav = ca[b*NC+c];
  __syncthreads();

  float* op = out2 + (size_t)bc*NN;
  #pragma unroll
  for (int k=0;k<16;++k){
    int p = t + k*256;
    int hh = p >> 6, ww = p & 63;
    float a = cbv;
    #pragma unroll
    for (int dy=0;dy<3;++dy){
      a += tl[hh+dy][ww  ]*wr[dy*3+0];
      a += tl[hh+dy][ww+1]*wr[dy*3+1];
      a += tl[hh+dy][ww+2]*wr[dy*3+2];
    }
    float gl = 0.5f*a*(1.f+tanhf(0.79788456080286536f*(a+0.044715f*a*a*a)));
    op[p] = gl*cav + tl[1+hh][1+ww];
  }
}

// ============================================================================
extern "C" void kernel_launch(void* const* d_in, const int* in_sizes, int n_in,
                              void* d_out, int out_size, void* d_ws, size_t ws_size,
                              hipStream_t stream)
{
  const float* x       = (const float*)d_in[0];
  const float* p_in_w  = (const float*)d_in[1];
  const float* p_in_b  = (const float*)d_in[2];
  const float* p_ln_w  = (const float*)d_in[3];
  const float* p_ln_b  = (const float*)d_in[4];
  const float* p_off_w1= (const float*)d_in[5];
  const float* p_off_b1= (const float*)d_in[6];
  const float* p_off_w2= (const float*)d_in[7];
  const float* p_off_b2= (const float*)d_in[8];
  const float* p_ca_w  = (const float*)d_in[9];
  const float* p_ca_b  = (const float*)d_in[10];
  const float* p_sa_w  = (const float*)d_in[11];
  const float* p_sa_b  = (const float*)d_in[12];
  const float* p_mask_w1=(const float*)d_in[13];
  const float* p_mask_b1=(const float*)d_in[14];
  const float* p_mask_w2=(const float*)d_in[15];
  const float* p_mask_b2=(const float*)d_in[16];
  const float* v_w     = (const float*)d_in[17];
  const float* v_b     = (const float*)d_in[18];
  const float* q_w     = (const float*)d_in[19];
  const float* q_b     = (const float*)d_in[20];
  const float* k_w     = (const float*)d_in[21];
  const float* k_b     = (const float*)d_in[22];
  const float* cs_w    = (const float*)d_in[23];
  const float* cs_b    = (const float*)d_in[24];
  const float* out_w   = (const float*)d_in[25];
  const float* out_b   = (const float*)d_in[26];
  float* out = (float*)d_out;
  (void)in_sizes; (void)n_in; (void)out_size;

  char* wsp = (char*)d_ws;
  size_t off = 0;
  auto alloc = [&](size_t bytes)->char*{ char* p = wsp + off; off += (bytes + 255) & ~(size_t)255; return p; };
  float* f     = (float*)alloc((size_t)NB*NC4*NN*4);
  float* score = (float*)alloc((size_t)NB*NN*4);
  int*   idx1  = (int*)  alloc((size_t)NB*NKEEP*4);
  int*   flag  = (int*)  alloc((size_t)NB*NN*4);
  float* offs  = (float*)alloc((size_t)NB*2*NN*4);
  float* sa    = (float*)alloc((size_t)NB*NN*4);
  float* fmean = (float*)alloc((size_t)NB*NC4*4);
  float* ca    = (float*)alloc((size_t)NB*NC*4);
  float* vbuf  = (float*)alloc((size_t)NB*NC*NN*4);     // v(*sa), later out_img (in place)
  bf16*  q1bf  = (bf16*) alloc((size_t)NB*NKEEP*NC*2);
  bf16*  k1bf  = (bf16*) alloc((size_t)NB*NKEEP*NC*2);
  bf16*  v1T   = (bf16*) alloc((size_t)NB*NC*NKEEP*2);
  float4* wpar = (float4*)alloc((size_t)NB*NKEEP*16);
  int4*   ipar = (int4*) alloc((size_t)NB*NKEEP*16);
  float* out2  = (float*)alloc((size_t)NB*NC*NN*4);
  float* pl    = (float*)alloc((size_t)NB*32*NSPLIT*64*4);
  bf16*  xT    = (bf16*) alloc((size_t)NB*NN*NC*2);     // x tokens; later out2T
  bf16*  wqb   = (bf16*) alloc((size_t)NC*NC*2);
  bf16*  wkb   = (bf16*) alloc((size_t)NC*NC*2);
  bf16*  wvb   = (bf16*) alloc((size_t)NC*NC*2);
  bf16*  wob   = (bf16*) alloc((size_t)NC*NC*2);
  if (off > ws_size) return;
  // aliases inside out2 (sequentially dead):
  //   qin/kin (gathers+gemms) -> pacc (attn+merge) -> out2 fp32 (dwgelu+transpose)
  bf16* qin  = (bf16*)out2;
  bf16* kin  = qin + (size_t)NB*NKEEP*NC;
  bf16* pacc = (bf16*)out2;
  bf16* out2T = xT;   // xT dead after gather_kT

  k_w2bf<<<(NC*NC+255)/256, 256, 0, stream>>>(q_w, k_w, v_w, out_w, wqb, wkb, wvb, wob);
  k_transpose<<<dim3(NN/32, NC/32, NB), 256, 0, stream>>>(x, xT);
  k_f_score<<<NB*NN/128, 128, 0, stream>>>(x, p_in_w, p_in_b, p_ln_w, p_ln_b,
      p_mask_w1, p_mask_b1, p_mask_w2, p_mask_b2, f, score);
  k_topk<<<NB, 1024, 0, stream>>>(score, idx1, flag);
  k_offsets<<<NB*NN/256, 256, 0, stream>>>(f, p_off_w1, p_off_b1, p_off_w2, p_off_b2, offs);
  k_fmean<<<NB*NC4, 256, 0, stream>>>(f, fmean);
  k_ca<<<NB, NC, 0, stream>>>(fmean, p_ca_w, p_ca_b, ca);
  k_sa<<<dim3(NH, NB), 256, 0, stream>>>(f, p_sa_w, p_sa_b, sa);
  k_conv_mfma<<<dim3(NN/64, NB), 256, 0, stream>>>(xT, wvb, v_b, vbuf, flag, sa);
  k_warp_params<<<NB*NKEEP/256, 256, 0, stream>>>(idx1, offs, wpar, ipar);
  k_gather_qT<<<NB*NKEEP*24/256, 256, 0, stream>>>(xT, idx1, qin);
  k_gather_kT<<<NB*NKEEP*24/256, 256, 0, stream>>>(xT, idx1, wpar, ipar, kin);
  k_gemm_mfma<<<dim3(NKEEP/32, NB), 256, 0, stream>>>(qin, wqb, q_b, q1bf);
  k_gemm_mfma<<<dim3(NKEEP/32, NB), 256, 0, stream>>>(kin, wkb, k_b, k1bf);
  k_gather_vT<<<NB*NC*NKEEP/256, 256, 0, stream>>>(vbuf, idx1, v1T);
  k_attn<<<NB*NSPLIT*32, 256, 0, stream>>>(q1bf, k1bf, v1T, pacc, pl);
  k_merge<<<NB*NKEEP*NC/256, 256, 0, stream>>>(pacc, pl, idx1, vbuf);
  k_dwgelu<<<NB*NC, 256, 0, stream>>>(vbuf, ca, cs_w, cs_b, out2);
  k_transpose<<<dim3(NN/32, NC/32, NB), 256, 0, stream>>>(out2, out2T);
  k_conv_mfma<<<dim3(NN/64, NB), 256, 0, stream>>>(out2T, wob, out_b, out, nullptr, nullptr);
}